// Round 6
// baseline (931.990 us; speedup 1.0000x reference)
//
#include <hip/hip_runtime.h>
#include <hip/hip_bf16.h>
#include <math.h>

#define N_TOKENS 16
#define TOK_DIM 64
#define NODE_DIM 64
#define HID 128
#define FC 128
#define NUM_GRAPHS 1024
#define SCAN_B 256

// ---------------- embed + token-mean + Wp projection -> node64[N,64] ----------------
// 256 threads = 4 nodes/block, one wave per node
__global__ void embed_project_kernel(const int* __restrict__ tok,
                                     const float* __restrict__ emb,
                                     const float* __restrict__ Wp,
                                     const float* __restrict__ bp,
                                     float* __restrict__ node64, int N) {
    __shared__ float smean[4][64];
    int t = threadIdx.x;
    int w = t >> 6, j = t & 63;
    int i = blockIdx.x * 4 + w;
    if (i < N) {
        int vt = tok[i * N_TOKENS + (j & 15)];  // lanes 0..15 hold the 16 token ids
        float s = 0.f;
#pragma unroll
        for (int tt = 0; tt < N_TOKENS; tt++) {
            int v = __shfl(vt, tt, 64);
            s += emb[v * TOK_DIM + j];
        }
        smean[w][j] = s * (1.0f / (float)N_TOKENS);
    }
    __syncthreads();
    if (i < N) {
        float acc = bp[j];
#pragma unroll
        for (int k = 0; k < TOK_DIM; k++) acc += smean[w][k] * Wp[k * NODE_DIM + j];
        node64[(size_t)i * 64 + j] = acc;
    }
}

// ---------------- degree histogram ----------------
__global__ void hist_kernel(const int* __restrict__ dst, int* __restrict__ hist, int E) {
    int e = blockIdx.x * blockDim.x + threadIdx.x;
    if (e < E) atomicAdd(&hist[dst[e]], 1);
}

// ---------------- scan local + dis + cursor reset (fused) ----------------
__global__ void scan_local_kernel(int* __restrict__ hist, int* __restrict__ row_start,
                                  int* __restrict__ bsums, float* __restrict__ dis, int N) {
    __shared__ int s[SCAN_B];
    int tid = threadIdx.x;
    int i = blockIdx.x * SCAN_B + tid;
    int v = (i < N) ? hist[i] : 0;
    s[tid] = v;
    __syncthreads();
    for (int off = 1; off < SCAN_B; off <<= 1) {
        int add = (tid >= off) ? s[tid - off] : 0;
        __syncthreads();
        s[tid] += add;
        __syncthreads();
    }
    if (i < N) {
        row_start[i] = s[tid] - v;                 // exclusive (block-local)
        dis[i] = rsqrtf(1.0f + (float)v);          // +1 self loop
        hist[i] = 0;                               // reset: hist doubles as cursor
    }
    if (tid == SCAN_B - 1) bsums[blockIdx.x] = s[SCAN_B - 1];
}

// single block, 512 threads; nb <= 512
__global__ void scan_bsums_kernel(int* __restrict__ bsums, int nb) {
    __shared__ int s[512];
    int tid = threadIdx.x;
    int v = (tid < nb) ? bsums[tid] : 0;
    s[tid] = v;
    __syncthreads();
    for (int off = 1; off < 512; off <<= 1) {
        int add = (tid >= off) ? s[tid - off] : 0;
        __syncthreads();
        s[tid] += add;
        __syncthreads();
    }
    if (tid < nb) bsums[tid] = s[tid] - v;  // exclusive
    if (tid == 511) bsums[nb] = s[511];     // total
}

__global__ void scan_add_kernel(int* __restrict__ row_start, const int* __restrict__ bsums,
                                int N, int nb) {
    int i = blockIdx.x * blockDim.x + threadIdx.x;
    if (i < N) row_start[i] += bsums[i >> 8];
    else if (i == N) row_start[N] = bsums[nb];
}

// ---------------- CSR fill, packed (src, weight) int2 ----------------
__global__ void fill_csr_kernel(const int* __restrict__ src, const int* __restrict__ dst,
                                const int* __restrict__ row_start, int* __restrict__ cursor,
                                const float* __restrict__ dis,
                                int2* __restrict__ csr, int E) {
    int e = blockIdx.x * blockDim.x + threadIdx.x;
    if (e < E) {
        int d = dst[e];
        int s = src[e];
        int pos = atomicAdd(&cursor[d], 1);
        int o = row_start[d] + pos;
        csr[o] = make_int2(s, __float_as_int(dis[s] * dis[d]));
    }
}

// ---------------- layer 1 fused: agg64 (int4 CSR loads, 8 gathers in flight) + W1 + b1 + ReLU + W2 ----------------
// 256 threads = 4 nodes/block, one wave per node (lane j = feature 0..63)
__global__ void gcn_layer1_kernel(const float* __restrict__ node64,
                                  const int* __restrict__ row_start,
                                  const int2* __restrict__ csr,
                                  const float* __restrict__ dis,
                                  const float* __restrict__ W1,
                                  const float* __restrict__ b1,
                                  const float* __restrict__ W2,
                                  float* __restrict__ y, int N) {
    __shared__ float sagg[4][64];
    __shared__ float sx1[4][128];
    int t = threadIdx.x;
    int w = t >> 6, j = t & 63;
    int node = blockIdx.x * 4 + w;
    if (node < N) {
        int beg = row_start[node];
        int end = row_start[node + 1];
        float d = dis[node];
        float acc = node64[(size_t)node * 64 + j] * d * d;
        int k = beg;
        if (k < end && (k & 1)) {  // peel to 16B-align int4 loads
            int2 e = csr[k];
            acc += node64[(size_t)e.x * 64 + j] * __int_as_float(e.y);
            k++;
        }
        const int4* csr4 = (const int4*)csr;  // pair p covers edges 2p, 2p+1
        for (; k + 8 <= end; k += 8) {
            int p = k >> 1;
            int4 e0 = csr4[p], e1 = csr4[p + 1], e2 = csr4[p + 2], e3 = csr4[p + 3];
            float v0 = node64[(size_t)e0.x * 64 + j];
            float v1 = node64[(size_t)e0.z * 64 + j];
            float v2 = node64[(size_t)e1.x * 64 + j];
            float v3 = node64[(size_t)e1.z * 64 + j];
            float v4 = node64[(size_t)e2.x * 64 + j];
            float v5 = node64[(size_t)e2.z * 64 + j];
            float v6 = node64[(size_t)e3.x * 64 + j];
            float v7 = node64[(size_t)e3.z * 64 + j];
            acc += v0 * __int_as_float(e0.y);
            acc += v1 * __int_as_float(e0.w);
            acc += v2 * __int_as_float(e1.y);
            acc += v3 * __int_as_float(e1.w);
            acc += v4 * __int_as_float(e2.y);
            acc += v5 * __int_as_float(e2.w);
            acc += v6 * __int_as_float(e3.y);
            acc += v7 * __int_as_float(e3.w);
        }
        for (; k < end; k++) {
            int2 e = csr[k];
            acc += node64[(size_t)e.x * 64 + j] * __int_as_float(e.y);
        }
        sagg[w][j] = acc;
    }
    __syncthreads();
    if (node < N) {
        float o0 = b1[j], o1 = b1[j + 64];
#pragma unroll
        for (int k = 0; k < 64; k++) {
            float a = sagg[w][k];
            o0 += a * W1[k * 128 + j];
            o1 += a * W1[k * 128 + j + 64];
        }
        sx1[w][j] = fmaxf(o0, 0.f);
        sx1[w][j + 64] = fmaxf(o1, 0.f);
    }
    __syncthreads();
    if (node < N) {
        const float2* W2v = (const float2*)W2;  // row k, col pair j => W2v[k*64+j]
        float2 yy = make_float2(0.f, 0.f);
#pragma unroll 8
        for (int k = 0; k < 128; k++) {
            float a = sx1[w][k];
            float2 wk = W2v[k * 64 + j];
            yy.x += a * wk.x;
            yy.y += a * wk.y;
        }
        ((float2*)y)[(size_t)node * 64 + j] = yy;  // y = relu(aggW1+b1) @ W2 (bias/relu deferred)
    }
}

// ---------------- layer 2: 128-dim gather (float2, int4 CSR loads, 8 in flight) + b2 + ReLU ----------------
// 256 threads = 4 nodes/block, one wave per node, lane j = dims (2j, 2j+1)
__global__ void gcn_layer2_kernel(const float* __restrict__ y,
                                  const int* __restrict__ row_start,
                                  const int2* __restrict__ csr,
                                  const float* __restrict__ dis,
                                  const float* __restrict__ b2,
                                  float* __restrict__ outx, int N) {
    int t = threadIdx.x;
    int w = t >> 6, j = t & 63;
    int node = blockIdx.x * 4 + w;
    if (node >= N) return;
    const float2* y2 = (const float2*)y;
    int beg = row_start[node];
    int end = row_start[node + 1];
    float d = dis[node];
    float2 self = y2[(size_t)node * 64 + j];
    float2 acc = make_float2(self.x * d * d, self.y * d * d);
    int k = beg;
    if (k < end && (k & 1)) {
        int2 e = csr[k];
        float2 v = y2[(size_t)e.x * 64 + j];
        float ww = __int_as_float(e.y);
        acc.x += v.x * ww; acc.y += v.y * ww;
        k++;
    }
    const int4* csr4 = (const int4*)csr;
    for (; k + 8 <= end; k += 8) {
        int p = k >> 1;
        int4 e0 = csr4[p], e1 = csr4[p + 1], e2 = csr4[p + 2], e3 = csr4[p + 3];
        float2 v0 = y2[(size_t)e0.x * 64 + j];
        float2 v1 = y2[(size_t)e0.z * 64 + j];
        float2 v2 = y2[(size_t)e1.x * 64 + j];
        float2 v3 = y2[(size_t)e1.z * 64 + j];
        float2 v4 = y2[(size_t)e2.x * 64 + j];
        float2 v5 = y2[(size_t)e2.z * 64 + j];
        float2 v6 = y2[(size_t)e3.x * 64 + j];
        float2 v7 = y2[(size_t)e3.z * 64 + j];
        float w0 = __int_as_float(e0.y), w1 = __int_as_float(e0.w);
        float w2 = __int_as_float(e1.y), w3 = __int_as_float(e1.w);
        float w4 = __int_as_float(e2.y), w5 = __int_as_float(e2.w);
        float w6 = __int_as_float(e3.y), w7 = __int_as_float(e3.w);
        acc.x += v0.x * w0; acc.y += v0.y * w0;
        acc.x += v1.x * w1; acc.y += v1.y * w1;
        acc.x += v2.x * w2; acc.y += v2.y * w2;
        acc.x += v3.x * w3; acc.y += v3.y * w3;
        acc.x += v4.x * w4; acc.y += v4.y * w4;
        acc.x += v5.x * w5; acc.y += v5.y * w5;
        acc.x += v6.x * w6; acc.y += v6.y * w6;
        acc.x += v7.x * w7; acc.y += v7.y * w7;
    }
    for (; k < end; k++) {
        int2 e = csr[k];
        float2 v = y2[(size_t)e.x * 64 + j];
        float ww = __int_as_float(e.y);
        acc.x += v.x * ww; acc.y += v.y * ww;
    }
    const float2* b22 = (const float2*)b2;
    float2 bb = b22[j];
    float2 o = make_float2(fmaxf(acc.x + bb.x, 0.f), fmaxf(acc.y + bb.y, 0.f));
    ((float2*)outx)[(size_t)node * 64 + j] = o;
}

// ---------------- atomic-free global mean pool (batch sorted), float2 ----------------
__device__ __forceinline__ int lower_bound_i(const int* __restrict__ a, int n, int val) {
    int lo = 0, hi = n;
    while (lo < hi) {
        int mid = (lo + hi) >> 1;
        if (a[mid] < val) lo = mid + 1; else hi = mid;
    }
    return lo;
}

// 256 threads = 4 graphs/block, one wave per graph
__global__ void pool_mean_kernel(const float* __restrict__ x,
                                 const int* __restrict__ batch,
                                 float* __restrict__ g, int N) {
    int t = threadIdx.x;
    int w = t >> 6, j = t & 63;
    int gr = blockIdx.x * 4 + w;
    if (gr >= NUM_GRAPHS) return;
    int beg = lower_bound_i(batch, N, gr);
    int end = lower_bound_i(batch, N, gr + 1);
    const float2* x2 = (const float2*)x;
    float2 acc = make_float2(0.f, 0.f);
    int i = beg;
    for (; i + 4 <= end; i += 4) {
        float2 a0 = x2[(size_t)i * 64 + j];
        float2 a1 = x2[(size_t)(i + 1) * 64 + j];
        float2 a2 = x2[(size_t)(i + 2) * 64 + j];
        float2 a3 = x2[(size_t)(i + 3) * 64 + j];
        acc.x += a0.x + a1.x + a2.x + a3.x;
        acc.y += a0.y + a1.y + a2.y + a3.y;
    }
    for (; i < end; i++) {
        float2 a = x2[(size_t)i * 64 + j];
        acc.x += a.x; acc.y += a.y;
    }
    float inv = 1.0f / fmaxf((float)(end - beg), 1.0f);
    ((float2*)g)[(size_t)gr * 64 + j] = make_float2(acc.x * inv, acc.y * inv);
}

// ---------------- head ----------------
__global__ void head_kernel(const float* __restrict__ g,
                            const float* __restrict__ Wfc,
                            const float* __restrict__ bfc,
                            const float* __restrict__ Wout,
                            const float* __restrict__ bout,
                            float* __restrict__ out) {
    int gr = blockIdx.x;
    int j = threadIdx.x;  // 0..127
    __shared__ float sg[128];
    __shared__ float sred[128];
    sg[j] = g[gr * 128 + j];
    __syncthreads();
    float acc = bfc[j];
#pragma unroll
    for (int k = 0; k < 128; k++) acc += sg[k] * Wfc[k * 128 + j];
    float f = fmaxf(acc, 0.f);
    sred[j] = f * Wout[j];
    __syncthreads();
    if (j < 64) sred[j] += sred[j + 64];
    __syncthreads();
    if (j < 64) {
        float v = sred[j];
#pragma unroll
        for (int off = 32; off > 0; off >>= 1) v += __shfl_down(v, off);
        if (j == 0) {
            float logit = v + bout[0];
            out[gr] = 1.0f / (1.0f + expf(-logit));
            out[NUM_GRAPHS + gr] = logit;
        }
    }
}

extern "C" void kernel_launch(void* const* d_in, const int* in_sizes, int n_in,
                              void* d_out, int out_size, void* d_ws, size_t ws_size,
                              hipStream_t stream) {
    const int* tok   = (const int*)d_in[0];
    const int* eidx  = (const int*)d_in[1];
    const int* batch = (const int*)d_in[2];
    const float* emb = (const float*)d_in[3];
    const float* Wp  = (const float*)d_in[4];
    const float* bp  = (const float*)d_in[5];
    const float* W1  = (const float*)d_in[6];
    const float* b1  = (const float*)d_in[7];
    const float* W2  = (const float*)d_in[8];
    const float* b2  = (const float*)d_in[9];
    const float* Wfc = (const float*)d_in[10];
    const float* bfc = (const float*)d_in[11];
    const float* Wout= (const float*)d_in[12];
    const float* bout= (const float*)d_in[13];
    float* out = (float*)d_out;

    const int N = in_sizes[2];
    const int E = in_sizes[1] / 2;
    const int* src = eidx;
    const int* dst = eidx + E;
    const int nb_scan = (N + SCAN_B - 1) / SCAN_B;
    const int Np = (N + 3) & ~3;

    // workspace layout (floats); bsums padded to 1028 so csr lands 16B-aligned
    float* ws = (float*)d_ws;
    float* dis    = ws;                            // Np
    float* node64 = dis + Np;                      // Np*64
    float* ybuf   = node64 + (size_t)Np * 64;      // Np*128  (x1 @ W2)
    float* xfin   = ybuf + (size_t)Np * 128;       // Np*128  (layer-2 output)
    float* g      = xfin + (size_t)Np * 128;       // 1024*128
    int* row_start = (int*)(g + NUM_GRAPHS * 128); // Np+4
    int* hist      = row_start + Np + 4;           // Np (doubles as cursor)
    int* bsums     = hist + Np;                    // 1028 (padded for csr alignment)
    int2* csr      = (int2*)(bsums + 1028);        // E int2, 16B-aligned

    // --- degree histogram ---
    hipMemsetAsync(hist, 0, N * sizeof(int), stream);
    hist_kernel<<<(E + 255) / 256, 256, 0, stream>>>(dst, hist, E);

    // --- scan (fused: dis + cursor reset) ---
    scan_local_kernel<<<nb_scan, SCAN_B, 0, stream>>>(hist, row_start, bsums, dis, N);
    scan_bsums_kernel<<<1, 512, 0, stream>>>(bsums, nb_scan);
    scan_add_kernel<<<(N + 1 + 255) / 256, 256, 0, stream>>>(row_start, bsums, N, nb_scan);

    // --- CSR fill (hist is the zeroed cursor) ---
    fill_csr_kernel<<<(E + 255) / 256, 256, 0, stream>>>(src, dst, row_start, hist, dis,
                                                         csr, E);

    // --- embed + mean + Wp -> node64 ---
    embed_project_kernel<<<(N + 3) / 4, 256, 0, stream>>>(tok, emb, Wp, bp, node64, N);

    // --- layer 1: agg64 + W1 + b1 + ReLU + W2 -> y ---
    gcn_layer1_kernel<<<(N + 3) / 4, 256, 0, stream>>>(node64, row_start, csr, dis,
                                                       W1, b1, W2, ybuf, N);

    // --- layer 2: gather y + b2 + ReLU -> xfin ---
    gcn_layer2_kernel<<<(N + 3) / 4, 256, 0, stream>>>(ybuf, row_start, csr, dis, b2,
                                                       xfin, N);

    // --- global mean pool + head ---
    pool_mean_kernel<<<(NUM_GRAPHS + 3) / 4, 256, 0, stream>>>(xfin, batch, g, N);
    head_kernel<<<NUM_GRAPHS, 128, 0, stream>>>(g, Wfc, bfc, Wout, bout, out);
}

// Round 7
// 670.614 us; speedup vs baseline: 1.3898x; 1.3898x over previous
//
#include <hip/hip_runtime.h>
#include <hip/hip_bf16.h>
#include <math.h>

#define N_TOKENS 16
#define TOK_DIM 64
#define NODE_DIM 64
#define HID 128
#define FC 128
#define NUM_GRAPHS 1024
#define SCAN_B 256

// ---------------- embed + token-mean + Wp projection -> node64[N,64] ----------------
// 256 threads = 4 nodes/block, one wave per node
__global__ void embed_project_kernel(const int* __restrict__ tok,
                                     const float* __restrict__ emb,
                                     const float* __restrict__ Wp,
                                     const float* __restrict__ bp,
                                     float* __restrict__ node64, int N) {
    __shared__ float smean[4][64];
    int t = threadIdx.x;
    int w = t >> 6, j = t & 63;
    int i = blockIdx.x * 4 + w;
    if (i < N) {
        int vt = tok[i * N_TOKENS + (j & 15)];  // lanes 0..15 hold the 16 token ids
        float s = 0.f;
#pragma unroll
        for (int tt = 0; tt < N_TOKENS; tt++) {
            int v = __shfl(vt, tt, 64);
            s += emb[v * TOK_DIM + j];
        }
        smean[w][j] = s * (1.0f / (float)N_TOKENS);
    }
    __syncthreads();
    if (i < N) {
        float acc = bp[j];
#pragma unroll
        for (int k = 0; k < TOK_DIM; k++) acc += smean[w][k] * Wp[k * NODE_DIM + j];
        node64[(size_t)i * 64 + j] = acc;
    }
}

// ---------------- degree histogram ----------------
__global__ void hist_kernel(const int* __restrict__ dst, int* __restrict__ hist, int E) {
    int e = blockIdx.x * blockDim.x + threadIdx.x;
    if (e < E) atomicAdd(&hist[dst[e]], 1);
}

// ---------------- scan local + dis + cursor reset (fused) ----------------
__global__ void scan_local_kernel(int* __restrict__ hist, int* __restrict__ row_start,
                                  int* __restrict__ bsums, float* __restrict__ dis, int N) {
    __shared__ int s[SCAN_B];
    int tid = threadIdx.x;
    int i = blockIdx.x * SCAN_B + tid;
    int v = (i < N) ? hist[i] : 0;
    s[tid] = v;
    __syncthreads();
    for (int off = 1; off < SCAN_B; off <<= 1) {
        int add = (tid >= off) ? s[tid - off] : 0;
        __syncthreads();
        s[tid] += add;
        __syncthreads();
    }
    if (i < N) {
        row_start[i] = s[tid] - v;                 // exclusive (block-local)
        dis[i] = rsqrtf(1.0f + (float)v);          // +1 self loop
        hist[i] = 0;                               // reset: hist doubles as cursor
    }
    if (tid == SCAN_B - 1) bsums[blockIdx.x] = s[SCAN_B - 1];
}

// single block, 512 threads; nb <= 512
__global__ void scan_bsums_kernel(int* __restrict__ bsums, int nb) {
    __shared__ int s[512];
    int tid = threadIdx.x;
    int v = (tid < nb) ? bsums[tid] : 0;
    s[tid] = v;
    __syncthreads();
    for (int off = 1; off < 512; off <<= 1) {
        int add = (tid >= off) ? s[tid - off] : 0;
        __syncthreads();
        s[tid] += add;
        __syncthreads();
    }
    if (tid < nb) bsums[tid] = s[tid] - v;  // exclusive
    if (tid == 511) bsums[nb] = s[511];     // total
}

__global__ void scan_add_kernel(int* __restrict__ row_start, const int* __restrict__ bsums,
                                int N, int nb) {
    int i = blockIdx.x * blockDim.x + threadIdx.x;
    if (i < N) row_start[i] += bsums[i >> 8];
    else if (i == N) row_start[N] = bsums[nb];
}

// ---------------- CSR fill, packed (src, weight) int2 ----------------
__global__ void fill_csr_kernel(const int* __restrict__ src, const int* __restrict__ dst,
                                const int* __restrict__ row_start, int* __restrict__ cursor,
                                const float* __restrict__ dis,
                                int2* __restrict__ csr, int E) {
    int e = blockIdx.x * blockDim.x + threadIdx.x;
    if (e < E) {
        int d = dst[e];
        int s = src[e];
        int pos = atomicAdd(&cursor[d], 1);
        int o = row_start[d] + pos;
        csr[o] = make_int2(s, __float_as_int(dis[s] * dis[d]));
    }
}

// ---------------- layer 1: agg64 (8 gathers in flight) + W1 + b1 + ReLU -> x1[N,128] ----------------
// 256 threads = 4 nodes/block, one wave per node (lane j = feature 0..63)
__global__ __launch_bounds__(256, 6)
void gcn_agg64_linear_kernel(const float* __restrict__ node64,
                             const int* __restrict__ row_start,
                             const int2* __restrict__ csr,
                             const float* __restrict__ dis,
                             const float* __restrict__ W1,
                             const float* __restrict__ b1,
                             float* __restrict__ x1, int N) {
    __shared__ float sagg[4][64];
    int t = threadIdx.x;
    int w = t >> 6, j = t & 63;
    int node = blockIdx.x * 4 + w;
    if (node < N) {
        int beg = row_start[node];
        int end = row_start[node + 1];
        float d = dis[node];
        float acc = node64[(size_t)node * 64 + j] * d * d;
        int k = beg;
        for (; k + 8 <= end; k += 8) {
            int2 e0 = csr[k], e1 = csr[k + 1], e2 = csr[k + 2], e3 = csr[k + 3];
            int2 e4 = csr[k + 4], e5 = csr[k + 5], e6 = csr[k + 6], e7 = csr[k + 7];
            float v0 = node64[(size_t)e0.x * 64 + j];
            float v1 = node64[(size_t)e1.x * 64 + j];
            float v2 = node64[(size_t)e2.x * 64 + j];
            float v3 = node64[(size_t)e3.x * 64 + j];
            float v4 = node64[(size_t)e4.x * 64 + j];
            float v5 = node64[(size_t)e5.x * 64 + j];
            float v6 = node64[(size_t)e6.x * 64 + j];
            float v7 = node64[(size_t)e7.x * 64 + j];
            acc += v0 * __int_as_float(e0.y);
            acc += v1 * __int_as_float(e1.y);
            acc += v2 * __int_as_float(e2.y);
            acc += v3 * __int_as_float(e3.y);
            acc += v4 * __int_as_float(e4.y);
            acc += v5 * __int_as_float(e5.y);
            acc += v6 * __int_as_float(e6.y);
            acc += v7 * __int_as_float(e7.y);
        }
        for (; k < end; k++) {
            int2 e = csr[k];
            acc += node64[(size_t)e.x * 64 + j] * __int_as_float(e.y);
        }
        sagg[w][j] = acc;
    }
    __syncthreads();
    if (node < N) {
        float o0 = b1[j], o1 = b1[j + 64];
#pragma unroll
        for (int k = 0; k < 64; k++) {
            float a = sagg[w][k];
            o0 += a * W1[k * 128 + j];
            o1 += a * W1[k * 128 + j + 64];
        }
        x1[(size_t)node * 128 + j] = fmaxf(o0, 0.f);
        x1[(size_t)node * 128 + j + 64] = fmaxf(o1, 0.f);
    }
}

// ---------------- in-place dense linear 128x128, 8 nodes per 128-thread block ----------------
__global__ void linear_128_128_inplace_kernel(float* __restrict__ x,
                                              const float* __restrict__ W, int N) {
    __shared__ float sx[8][128];
    int t = threadIdx.x;  // 0..127
    int nb = blockIdx.x * 8;
#pragma unroll
    for (int n = 0; n < 8; n++) {
        int gi = nb + n;
        sx[n][t] = (gi < N) ? x[(size_t)gi * 128 + t] : 0.f;
    }
    __syncthreads();
    float acc[8] = {0, 0, 0, 0, 0, 0, 0, 0};
#pragma unroll 8
    for (int k = 0; k < 128; k++) {
        float w = W[k * 128 + t];
#pragma unroll
        for (int n = 0; n < 8; n++) acc[n] += sx[n][k] * w;
    }
#pragma unroll
    for (int n = 0; n < 8; n++) {
        int gi = nb + n;
        if (gi < N) x[(size_t)gi * 128 + t] = acc[n];
    }
}

// ---------------- layer 2: 128-dim gather (float2, 8 in flight) + b2 + ReLU ----------------
// 256 threads = 4 nodes/block, one wave per node, lane j = dims (2j, 2j+1)
__global__ __launch_bounds__(256, 6)
void gcn_agg128_kernel(const float* __restrict__ h,
                       const int* __restrict__ row_start,
                       const int2* __restrict__ csr,
                       const float* __restrict__ dis,
                       const float* __restrict__ b2,
                       float* __restrict__ outx, int N) {
    int t = threadIdx.x;
    int w = t >> 6, j = t & 63;
    int node = blockIdx.x * 4 + w;
    if (node >= N) return;
    const float2* h2 = (const float2*)h;
    int beg = row_start[node];
    int end = row_start[node + 1];
    float d = dis[node];
    float2 self = h2[(size_t)node * 64 + j];
    float2 acc = make_float2(self.x * d * d, self.y * d * d);
    int k = beg;
    for (; k + 8 <= end; k += 8) {
        int2 e0 = csr[k], e1 = csr[k + 1], e2 = csr[k + 2], e3 = csr[k + 3];
        int2 e4 = csr[k + 4], e5 = csr[k + 5], e6 = csr[k + 6], e7 = csr[k + 7];
        float2 v0 = h2[(size_t)e0.x * 64 + j];
        float2 v1 = h2[(size_t)e1.x * 64 + j];
        float2 v2 = h2[(size_t)e2.x * 64 + j];
        float2 v3 = h2[(size_t)e3.x * 64 + j];
        float2 v4 = h2[(size_t)e4.x * 64 + j];
        float2 v5 = h2[(size_t)e5.x * 64 + j];
        float2 v6 = h2[(size_t)e6.x * 64 + j];
        float2 v7 = h2[(size_t)e7.x * 64 + j];
        float w0 = __int_as_float(e0.y), w1 = __int_as_float(e1.y);
        float w2 = __int_as_float(e2.y), w3 = __int_as_float(e3.y);
        float w4 = __int_as_float(e4.y), w5 = __int_as_float(e5.y);
        float w6 = __int_as_float(e6.y), w7 = __int_as_float(e7.y);
        acc.x += v0.x * w0; acc.y += v0.y * w0;
        acc.x += v1.x * w1; acc.y += v1.y * w1;
        acc.x += v2.x * w2; acc.y += v2.y * w2;
        acc.x += v3.x * w3; acc.y += v3.y * w3;
        acc.x += v4.x * w4; acc.y += v4.y * w4;
        acc.x += v5.x * w5; acc.y += v5.y * w5;
        acc.x += v6.x * w6; acc.y += v6.y * w6;
        acc.x += v7.x * w7; acc.y += v7.y * w7;
    }
    for (; k < end; k++) {
        int2 e = csr[k];
        float2 v = h2[(size_t)e.x * 64 + j];
        float ww = __int_as_float(e.y);
        acc.x += v.x * ww; acc.y += v.y * ww;
    }
    const float2* b22 = (const float2*)b2;
    float2 bb = b22[j];
    float2 o = make_float2(fmaxf(acc.x + bb.x, 0.f), fmaxf(acc.y + bb.y, 0.f));
    ((float2*)outx)[(size_t)node * 64 + j] = o;
}

// ---------------- atomic-free global mean pool (batch sorted), float2 ----------------
__device__ __forceinline__ int lower_bound_i(const int* __restrict__ a, int n, int val) {
    int lo = 0, hi = n;
    while (lo < hi) {
        int mid = (lo + hi) >> 1;
        if (a[mid] < val) lo = mid + 1; else hi = mid;
    }
    return lo;
}

// 256 threads = 4 graphs/block, one wave per graph
__global__ void pool_mean_kernel(const float* __restrict__ x,
                                 const int* __restrict__ batch,
                                 float* __restrict__ g, int N) {
    int t = threadIdx.x;
    int w = t >> 6, j = t & 63;
    int gr = blockIdx.x * 4 + w;
    if (gr >= NUM_GRAPHS) return;
    int beg = lower_bound_i(batch, N, gr);
    int end = lower_bound_i(batch, N, gr + 1);
    const float2* x2 = (const float2*)x;
    float2 acc = make_float2(0.f, 0.f);
    int i = beg;
    for (; i + 4 <= end; i += 4) {
        float2 a0 = x2[(size_t)i * 64 + j];
        float2 a1 = x2[(size_t)(i + 1) * 64 + j];
        float2 a2 = x2[(size_t)(i + 2) * 64 + j];
        float2 a3 = x2[(size_t)(i + 3) * 64 + j];
        acc.x += a0.x + a1.x + a2.x + a3.x;
        acc.y += a0.y + a1.y + a2.y + a3.y;
    }
    for (; i < end; i++) {
        float2 a = x2[(size_t)i * 64 + j];
        acc.x += a.x; acc.y += a.y;
    }
    float inv = 1.0f / fmaxf((float)(end - beg), 1.0f);
    ((float2*)g)[(size_t)gr * 64 + j] = make_float2(acc.x * inv, acc.y * inv);
}

// ---------------- head ----------------
__global__ void head_kernel(const float* __restrict__ g,
                            const float* __restrict__ Wfc,
                            const float* __restrict__ bfc,
                            const float* __restrict__ Wout,
                            const float* __restrict__ bout,
                            float* __restrict__ out) {
    int gr = blockIdx.x;
    int j = threadIdx.x;  // 0..127
    __shared__ float sg[128];
    __shared__ float sred[128];
    sg[j] = g[gr * 128 + j];
    __syncthreads();
    float acc = bfc[j];
#pragma unroll
    for (int k = 0; k < 128; k++) acc += sg[k] * Wfc[k * 128 + j];
    float f = fmaxf(acc, 0.f);
    sred[j] = f * Wout[j];
    __syncthreads();
    if (j < 64) sred[j] += sred[j + 64];
    __syncthreads();
    if (j < 64) {
        float v = sred[j];
#pragma unroll
        for (int off = 32; off > 0; off >>= 1) v += __shfl_down(v, off);
        if (j == 0) {
            float logit = v + bout[0];
            out[gr] = 1.0f / (1.0f + expf(-logit));
            out[NUM_GRAPHS + gr] = logit;
        }
    }
}

extern "C" void kernel_launch(void* const* d_in, const int* in_sizes, int n_in,
                              void* d_out, int out_size, void* d_ws, size_t ws_size,
                              hipStream_t stream) {
    const int* tok   = (const int*)d_in[0];
    const int* eidx  = (const int*)d_in[1];
    const int* batch = (const int*)d_in[2];
    const float* emb = (const float*)d_in[3];
    const float* Wp  = (const float*)d_in[4];
    const float* bp  = (const float*)d_in[5];
    const float* W1  = (const float*)d_in[6];
    const float* b1  = (const float*)d_in[7];
    const float* W2  = (const float*)d_in[8];
    const float* b2  = (const float*)d_in[9];
    const float* Wfc = (const float*)d_in[10];
    const float* bfc = (const float*)d_in[11];
    const float* Wout= (const float*)d_in[12];
    const float* bout= (const float*)d_in[13];
    float* out = (float*)d_out;

    const int N = in_sizes[2];
    const int E = in_sizes[1] / 2;
    const int* src = eidx;
    const int* dst = eidx + E;
    const int nb_scan = (N + SCAN_B - 1) / SCAN_B;
    const int Np = (N + 3) & ~3;

    // workspace layout (floats)
    float* ws = (float*)d_ws;
    float* dis    = ws;                            // Np
    float* node64 = dis + Np;                      // Np*64
    float* x1buf  = node64 + (size_t)Np * 64;      // Np*128  (layer-1 out, then @=W2)
    float* xfin   = x1buf + (size_t)Np * 128;      // Np*128  (layer-2 output)
    float* g      = xfin + (size_t)Np * 128;       // 1024*128
    int* row_start = (int*)(g + NUM_GRAPHS * 128); // Np+4
    int* hist      = row_start + Np + 4;           // Np (doubles as cursor)
    int* bsums     = hist + Np;                    // 1028 (padded for csr alignment)
    int2* csr      = (int2*)(bsums + 1028);        // E int2, 16B-aligned

    // --- degree histogram ---
    hipMemsetAsync(hist, 0, N * sizeof(int), stream);
    hist_kernel<<<(E + 255) / 256, 256, 0, stream>>>(dst, hist, E);

    // --- scan (fused: dis + cursor reset) ---
    scan_local_kernel<<<nb_scan, SCAN_B, 0, stream>>>(hist, row_start, bsums, dis, N);
    scan_bsums_kernel<<<1, 512, 0, stream>>>(bsums, nb_scan);
    scan_add_kernel<<<(N + 1 + 255) / 256, 256, 0, stream>>>(row_start, bsums, N, nb_scan);

    // --- CSR fill (hist is the zeroed cursor) ---
    fill_csr_kernel<<<(E + 255) / 256, 256, 0, stream>>>(src, dst, row_start, hist, dis,
                                                         csr, E);

    // --- embed + mean + Wp -> node64 ---
    embed_project_kernel<<<(N + 3) / 4, 256, 0, stream>>>(tok, emb, Wp, bp, node64, N);

    // --- layer 1: agg64 + W1 + b1 + ReLU -> x1 ---
    gcn_agg64_linear_kernel<<<(N + 3) / 4, 256, 0, stream>>>(node64, row_start, csr, dis,
                                                             W1, b1, x1buf, N);

    // --- layer 2: x1 @= W2 (in place), then aggregate + b2 + ReLU -> xfin ---
    linear_128_128_inplace_kernel<<<(N + 7) / 8, 128, 0, stream>>>(x1buf, W2, N);
    gcn_agg128_kernel<<<(N + 3) / 4, 256, 0, stream>>>(x1buf, row_start, csr, dis, b2,
                                                       xfin, N);

    // --- global mean pool + head ---
    pool_mean_kernel<<<(NUM_GRAPHS + 3) / 4, 256, 0, stream>>>(xfin, batch, g, N);
    head_kernel<<<NUM_GRAPHS, 128, 0, stream>>>(g, Wfc, bfc, Wout, bout, out);
}

// Round 8
// 643.272 us; speedup vs baseline: 1.4488x; 1.0425x over previous
//
#include <hip/hip_runtime.h>
#include <hip/hip_bf16.h>
#include <math.h>

#define N_TOKENS 16
#define TOK_DIM 64
#define NODE_DIM 64
#define HID 128
#define FC 128
#define NUM_GRAPHS 1024
#define SCAN_B 256

// ---------------- embed + token-mean + Wp projection -> node64[N,64] ----------------
// 256 threads = 4 nodes/block, one wave per node.
// Gather packing: lane (q,l), q=j>>4, l=j&15 — 4 emb rows per float4 gather instr.
__global__ void embed_project_kernel(const int* __restrict__ tok,
                                     const float* __restrict__ emb,
                                     const float* __restrict__ Wp,
                                     const float* __restrict__ bp,
                                     float* __restrict__ node64, int N) {
    __shared__ float smean[4][64];
    int t = threadIdx.x;
    int w = t >> 6, j = t & 63;
    int q = j >> 4, l = j & 15;
    int i = blockIdx.x * 4 + w;
    if (i < N) {
        const float4* e4 = (const float4*)emb;  // row = 16 float4
        int t0 = tok[i * 16 + q];
        int t1 = tok[i * 16 + q + 4];
        int t2 = tok[i * 16 + q + 8];
        int t3 = tok[i * 16 + q + 12];
        float4 v0 = e4[(size_t)t0 * 16 + l];
        float4 v1 = e4[(size_t)t1 * 16 + l];
        float4 v2 = e4[(size_t)t2 * 16 + l];
        float4 v3 = e4[(size_t)t3 * 16 + l];
        float4 s;
        s.x = v0.x + v1.x + v2.x + v3.x;
        s.y = v0.y + v1.y + v2.y + v3.y;
        s.z = v0.z + v1.z + v2.z + v3.z;
        s.w = v0.w + v1.w + v2.w + v3.w;
        s.x += __shfl_xor(s.x, 16); s.y += __shfl_xor(s.y, 16);
        s.z += __shfl_xor(s.z, 16); s.w += __shfl_xor(s.w, 16);
        s.x += __shfl_xor(s.x, 32); s.y += __shfl_xor(s.y, 32);
        s.z += __shfl_xor(s.z, 32); s.w += __shfl_xor(s.w, 32);
        if (q == 0) {
            const float inv = 1.0f / 16.0f;
            float4 m = make_float4(s.x * inv, s.y * inv, s.z * inv, s.w * inv);
            ((float4*)smean[w])[l] = m;
        }
    }
    __syncthreads();
    if (i < N) {
        float acc = bp[j];
#pragma unroll
        for (int k = 0; k < TOK_DIM; k++) acc += smean[w][k] * Wp[k * NODE_DIM + j];
        node64[(size_t)i * 64 + j] = acc;
    }
}

// ---------------- degree histogram ----------------
__global__ void hist_kernel(const int* __restrict__ dst, int* __restrict__ hist, int E) {
    int e = blockIdx.x * blockDim.x + threadIdx.x;
    if (e < E) atomicAdd(&hist[dst[e]], 1);
}

// ---------------- scan local + dis + cursor reset (fused) ----------------
__global__ void scan_local_kernel(int* __restrict__ hist, int* __restrict__ row_start,
                                  int* __restrict__ bsums, float* __restrict__ dis, int N) {
    __shared__ int s[SCAN_B];
    int tid = threadIdx.x;
    int i = blockIdx.x * SCAN_B + tid;
    int v = (i < N) ? hist[i] : 0;
    s[tid] = v;
    __syncthreads();
    for (int off = 1; off < SCAN_B; off <<= 1) {
        int add = (tid >= off) ? s[tid - off] : 0;
        __syncthreads();
        s[tid] += add;
        __syncthreads();
    }
    if (i < N) {
        row_start[i] = s[tid] - v;                 // exclusive (block-local)
        dis[i] = rsqrtf(1.0f + (float)v);          // +1 self loop
        hist[i] = 0;                               // reset: hist doubles as cursor
    }
    if (tid == SCAN_B - 1) bsums[blockIdx.x] = s[SCAN_B - 1];
}

// single block, 512 threads; nb <= 512
__global__ void scan_bsums_kernel(int* __restrict__ bsums, int nb) {
    __shared__ int s[512];
    int tid = threadIdx.x;
    int v = (tid < nb) ? bsums[tid] : 0;
    s[tid] = v;
    __syncthreads();
    for (int off = 1; off < 512; off <<= 1) {
        int add = (tid >= off) ? s[tid - off] : 0;
        __syncthreads();
        s[tid] += add;
        __syncthreads();
    }
    if (tid < nb) bsums[tid] = s[tid] - v;  // exclusive
    if (tid == 511) bsums[nb] = s[511];     // total
}

__global__ void scan_add_kernel(int* __restrict__ row_start, const int* __restrict__ bsums,
                                int N, int nb) {
    int i = blockIdx.x * blockDim.x + threadIdx.x;
    if (i < N) row_start[i] += bsums[i >> 8];
    else if (i == N) row_start[N] = bsums[nb];
}

// ---------------- CSR fill, packed (src, weight) int2 ----------------
__global__ void fill_csr_kernel(const int* __restrict__ src, const int* __restrict__ dst,
                                const int* __restrict__ row_start, int* __restrict__ cursor,
                                const float* __restrict__ dis,
                                int2* __restrict__ csr, int E) {
    int e = blockIdx.x * blockDim.x + threadIdx.x;
    if (e < E) {
        int d = dst[e];
        int s = src[e];
        int pos = atomicAdd(&cursor[d], 1);
        int o = row_start[d] + pos;
        csr[o] = make_int2(s, __float_as_int(dis[s] * dis[d]));
    }
}

// ---------------- layer 1: agg64 (4 rows per gather instr) + W1 + b1 + ReLU -> x1 ----------------
// one wave per node; lane (q,l): q=j>>4 edge slot, l=j&15 feature block (float4)
__global__ __launch_bounds__(256, 6)
void gcn_agg64_linear_kernel(const float* __restrict__ node64,
                             const int* __restrict__ row_start,
                             const int2* __restrict__ csr,
                             const float* __restrict__ dis,
                             const float* __restrict__ W1,
                             const float* __restrict__ b1,
                             float* __restrict__ x1, int N) {
    __shared__ float sagg[4][64];
    int t = threadIdx.x;
    int w = t >> 6, j = t & 63;
    int q = j >> 4, l = j & 15;
    int node = blockIdx.x * 4 + w;
    if (node < N) {
        int beg = row_start[node];
        int end = row_start[node + 1];
        float d = dis[node];
        const float4* n4 = (const float4*)node64;  // row = 16 float4
        float4 self = n4[(size_t)node * 16 + l];
        float d2 = d * d * ((q == 0) ? 1.f : 0.f);
        float4 acc = make_float4(self.x * d2, self.y * d2, self.z * d2, self.w * d2);
        for (int k = beg; k < end; k += 16) {
            int k0 = k + q, k1 = k + 4 + q, k2 = k + 8 + q, k3 = k + 12 + q;
            int2 e0 = (k0 < end) ? csr[k0] : make_int2(0, 0);
            int2 e1 = (k1 < end) ? csr[k1] : make_int2(0, 0);
            int2 e2 = (k2 < end) ? csr[k2] : make_int2(0, 0);
            int2 e3 = (k3 < end) ? csr[k3] : make_int2(0, 0);
            float4 v0 = n4[(size_t)e0.x * 16 + l];
            float4 v1 = n4[(size_t)e1.x * 16 + l];
            float4 v2 = n4[(size_t)e2.x * 16 + l];
            float4 v3 = n4[(size_t)e3.x * 16 + l];
            float w0 = __int_as_float(e0.y), w1 = __int_as_float(e1.y);
            float w2 = __int_as_float(e2.y), w3 = __int_as_float(e3.y);
            acc.x += v0.x * w0 + v1.x * w1 + v2.x * w2 + v3.x * w3;
            acc.y += v0.y * w0 + v1.y * w1 + v2.y * w2 + v3.y * w3;
            acc.z += v0.z * w0 + v1.z * w1 + v2.z * w2 + v3.z * w3;
            acc.w += v0.w * w0 + v1.w * w1 + v2.w * w2 + v3.w * w3;
        }
        // fold quads: lanes differing in bits 4,5 hold partial sums of same features
        acc.x += __shfl_xor(acc.x, 16); acc.y += __shfl_xor(acc.y, 16);
        acc.z += __shfl_xor(acc.z, 16); acc.w += __shfl_xor(acc.w, 16);
        acc.x += __shfl_xor(acc.x, 32); acc.y += __shfl_xor(acc.y, 32);
        acc.z += __shfl_xor(acc.z, 32); acc.w += __shfl_xor(acc.w, 32);
        if (q == 0) ((float4*)sagg[w])[l] = acc;
    }
    __syncthreads();
    if (node < N) {
        float o0 = b1[j], o1 = b1[j + 64];
#pragma unroll
        for (int k = 0; k < 64; k++) {
            float a = sagg[w][k];
            o0 += a * W1[k * 128 + j];
            o1 += a * W1[k * 128 + j + 64];
        }
        x1[(size_t)node * 128 + j] = fmaxf(o0, 0.f);
        x1[(size_t)node * 128 + j + 64] = fmaxf(o1, 0.f);
    }
}

// ---------------- in-place dense linear 128x128, 8 nodes per 128-thread block ----------------
__global__ void linear_128_128_inplace_kernel(float* __restrict__ x,
                                              const float* __restrict__ W, int N) {
    __shared__ float sx[8][128];
    int t = threadIdx.x;  // 0..127
    int nb = blockIdx.x * 8;
#pragma unroll
    for (int n = 0; n < 8; n++) {
        int gi = nb + n;
        sx[n][t] = (gi < N) ? x[(size_t)gi * 128 + t] : 0.f;
    }
    __syncthreads();
    float acc[8] = {0, 0, 0, 0, 0, 0, 0, 0};
#pragma unroll 8
    for (int k = 0; k < 128; k++) {
        float w = W[k * 128 + t];
#pragma unroll
        for (int n = 0; n < 8; n++) acc[n] += sx[n][k] * w;
    }
#pragma unroll
    for (int n = 0; n < 8; n++) {
        int gi = nb + n;
        if (gi < N) x[(size_t)gi * 128 + t] = acc[n];
    }
}

// ---------------- layer 2: agg128 (2 rows per gather instr) + b2 + ReLU ----------------
// one wave per node; lane (h,l): h=j>>5 edge slot, l=j&31 feature block (float4)
__global__ __launch_bounds__(256, 6)
void gcn_agg128_kernel(const float* __restrict__ hsrc,
                       const int* __restrict__ row_start,
                       const int2* __restrict__ csr,
                       const float* __restrict__ dis,
                       const float* __restrict__ b2,
                       float* __restrict__ outx, int N) {
    int t = threadIdx.x;
    int w = t >> 6, j = t & 63;
    int hh = j >> 5, l = j & 31;
    int node = blockIdx.x * 4 + w;
    if (node >= N) return;
    const float4* h4 = (const float4*)hsrc;  // row = 32 float4
    int beg = row_start[node];
    int end = row_start[node + 1];
    float d = dis[node];
    float4 self = h4[(size_t)node * 32 + l];
    float d2 = d * d * ((hh == 0) ? 1.f : 0.f);
    float4 acc = make_float4(self.x * d2, self.y * d2, self.z * d2, self.w * d2);
    for (int k = beg; k < end; k += 8) {
        int k0 = k + hh, k1 = k + 2 + hh, k2 = k + 4 + hh, k3 = k + 6 + hh;
        int2 e0 = (k0 < end) ? csr[k0] : make_int2(0, 0);
        int2 e1 = (k1 < end) ? csr[k1] : make_int2(0, 0);
        int2 e2 = (k2 < end) ? csr[k2] : make_int2(0, 0);
        int2 e3 = (k3 < end) ? csr[k3] : make_int2(0, 0);
        float4 v0 = h4[(size_t)e0.x * 32 + l];
        float4 v1 = h4[(size_t)e1.x * 32 + l];
        float4 v2 = h4[(size_t)e2.x * 32 + l];
        float4 v3 = h4[(size_t)e3.x * 32 + l];
        float w0 = __int_as_float(e0.y), w1 = __int_as_float(e1.y);
        float w2 = __int_as_float(e2.y), w3 = __int_as_float(e3.y);
        acc.x += v0.x * w0 + v1.x * w1 + v2.x * w2 + v3.x * w3;
        acc.y += v0.y * w0 + v1.y * w1 + v2.y * w2 + v3.y * w3;
        acc.z += v0.z * w0 + v1.z * w1 + v2.z * w2 + v3.z * w3;
        acc.w += v0.w * w0 + v1.w * w1 + v2.w * w2 + v3.w * w3;
    }
    acc.x += __shfl_xor(acc.x, 32); acc.y += __shfl_xor(acc.y, 32);
    acc.z += __shfl_xor(acc.z, 32); acc.w += __shfl_xor(acc.w, 32);
    if (hh == 0) {
        const float4* b4 = (const float4*)b2;
        float4 bb = b4[l];
        float4 o;
        o.x = fmaxf(acc.x + bb.x, 0.f);
        o.y = fmaxf(acc.y + bb.y, 0.f);
        o.z = fmaxf(acc.z + bb.z, 0.f);
        o.w = fmaxf(acc.w + bb.w, 0.f);
        ((float4*)outx)[(size_t)node * 32 + l] = o;
    }
}

// ---------------- atomic-free global mean pool (batch sorted), float2 ----------------
__device__ __forceinline__ int lower_bound_i(const int* __restrict__ a, int n, int val) {
    int lo = 0, hi = n;
    while (lo < hi) {
        int mid = (lo + hi) >> 1;
        if (a[mid] < val) lo = mid + 1; else hi = mid;
    }
    return lo;
}

// 256 threads = 4 graphs/block, one wave per graph
__global__ void pool_mean_kernel(const float* __restrict__ x,
                                 const int* __restrict__ batch,
                                 float* __restrict__ g, int N) {
    int t = threadIdx.x;
    int w = t >> 6, j = t & 63;
    int gr = blockIdx.x * 4 + w;
    if (gr >= NUM_GRAPHS) return;
    int beg = lower_bound_i(batch, N, gr);
    int end = lower_bound_i(batch, N, gr + 1);
    const float2* x2 = (const float2*)x;
    float2 acc = make_float2(0.f, 0.f);
    int i = beg;
    for (; i + 4 <= end; i += 4) {
        float2 a0 = x2[(size_t)i * 64 + j];
        float2 a1 = x2[(size_t)(i + 1) * 64 + j];
        float2 a2 = x2[(size_t)(i + 2) * 64 + j];
        float2 a3 = x2[(size_t)(i + 3) * 64 + j];
        acc.x += a0.x + a1.x + a2.x + a3.x;
        acc.y += a0.y + a1.y + a2.y + a3.y;
    }
    for (; i < end; i++) {
        float2 a = x2[(size_t)i * 64 + j];
        acc.x += a.x; acc.y += a.y;
    }
    float inv = 1.0f / fmaxf((float)(end - beg), 1.0f);
    ((float2*)g)[(size_t)gr * 64 + j] = make_float2(acc.x * inv, acc.y * inv);
}

// ---------------- head ----------------
__global__ void head_kernel(const float* __restrict__ g,
                            const float* __restrict__ Wfc,
                            const float* __restrict__ bfc,
                            const float* __restrict__ Wout,
                            const float* __restrict__ bout,
                            float* __restrict__ out) {
    int gr = blockIdx.x;
    int j = threadIdx.x;  // 0..127
    __shared__ float sg[128];
    __shared__ float sred[128];
    sg[j] = g[gr * 128 + j];
    __syncthreads();
    float acc = bfc[j];
#pragma unroll
    for (int k = 0; k < 128; k++) acc += sg[k] * Wfc[k * 128 + j];
    float f = fmaxf(acc, 0.f);
    sred[j] = f * Wout[j];
    __syncthreads();
    if (j < 64) sred[j] += sred[j + 64];
    __syncthreads();
    if (j < 64) {
        float v = sred[j];
#pragma unroll
        for (int off = 32; off > 0; off >>= 1) v += __shfl_down(v, off);
        if (j == 0) {
            float logit = v + bout[0];
            out[gr] = 1.0f / (1.0f + expf(-logit));
            out[NUM_GRAPHS + gr] = logit;
        }
    }
}

extern "C" void kernel_launch(void* const* d_in, const int* in_sizes, int n_in,
                              void* d_out, int out_size, void* d_ws, size_t ws_size,
                              hipStream_t stream) {
    const int* tok   = (const int*)d_in[0];
    const int* eidx  = (const int*)d_in[1];
    const int* batch = (const int*)d_in[2];
    const float* emb = (const float*)d_in[3];
    const float* Wp  = (const float*)d_in[4];
    const float* bp  = (const float*)d_in[5];
    const float* W1  = (const float*)d_in[6];
    const float* b1  = (const float*)d_in[7];
    const float* W2  = (const float*)d_in[8];
    const float* b2  = (const float*)d_in[9];
    const float* Wfc = (const float*)d_in[10];
    const float* bfc = (const float*)d_in[11];
    const float* Wout= (const float*)d_in[12];
    const float* bout= (const float*)d_in[13];
    float* out = (float*)d_out;

    const int N = in_sizes[2];
    const int E = in_sizes[1] / 2;
    const int* src = eidx;
    const int* dst = eidx + E;
    const int nb_scan = (N + SCAN_B - 1) / SCAN_B;
    const int Np = (N + 3) & ~3;

    // workspace layout (floats)
    float* ws = (float*)d_ws;
    float* dis    = ws;                            // Np
    float* node64 = dis + Np;                      // Np*64
    float* x1buf  = node64 + (size_t)Np * 64;      // Np*128  (layer-1 out, then @=W2)
    float* xfin   = x1buf + (size_t)Np * 128;      // Np*128  (layer-2 output)
    float* g      = xfin + (size_t)Np * 128;       // 1024*128
    int* row_start = (int*)(g + NUM_GRAPHS * 128); // Np+4
    int* hist      = row_start + Np + 4;           // Np (doubles as cursor)
    int* bsums     = hist + Np;                    // 1028 (padded for csr alignment)
    int2* csr      = (int2*)(bsums + 1028);        // E int2, 16B-aligned

    // --- degree histogram ---
    hipMemsetAsync(hist, 0, N * sizeof(int), stream);
    hist_kernel<<<(E + 255) / 256, 256, 0, stream>>>(dst, hist, E);

    // --- scan (fused: dis + cursor reset) ---
    scan_local_kernel<<<nb_scan, SCAN_B, 0, stream>>>(hist, row_start, bsums, dis, N);
    scan_bsums_kernel<<<1, 512, 0, stream>>>(bsums, nb_scan);
    scan_add_kernel<<<(N + 1 + 255) / 256, 256, 0, stream>>>(row_start, bsums, N, nb_scan);

    // --- CSR fill (hist is the zeroed cursor) ---
    fill_csr_kernel<<<(E + 255) / 256, 256, 0, stream>>>(src, dst, row_start, hist, dis,
                                                         csr, E);

    // --- embed + mean + Wp -> node64 ---
    embed_project_kernel<<<(N + 3) / 4, 256, 0, stream>>>(tok, emb, Wp, bp, node64, N);

    // --- layer 1: agg64 + W1 + b1 + ReLU -> x1 ---
    gcn_agg64_linear_kernel<<<(N + 3) / 4, 256, 0, stream>>>(node64, row_start, csr, dis,
                                                             W1, b1, x1buf, N);

    // --- layer 2: x1 @= W2 (in place), then aggregate + b2 + ReLU -> xfin ---
    linear_128_128_inplace_kernel<<<(N + 7) / 8, 128, 0, stream>>>(x1buf, W2, N);
    gcn_agg128_kernel<<<(N + 3) / 4, 256, 0, stream>>>(x1buf, row_start, csr, dis, b2,
                                                       xfin, N);

    // --- global mean pool + head ---
    pool_mean_kernel<<<(NUM_GRAPHS + 3) / 4, 256, 0, stream>>>(xfin, batch, g, N);
    head_kernel<<<NUM_GRAPHS, 128, 0, stream>>>(g, Wfc, bfc, Wout, bout, out);
}

// Round 9
// 596.120 us; speedup vs baseline: 1.5634x; 1.0791x over previous
//
#include <hip/hip_runtime.h>
#include <hip/hip_bf16.h>
#include <math.h>

#define N_TOKENS 16
#define TOK_DIM 64
#define NODE_DIM 64
#define HID 128
#define FC 128
#define NUM_GRAPHS 1024
#define SCAN_B 256

// ---------------- fused-weight precompute: Wf = Wp @ W1 (64x128), bf = bp @ W1 ----------------
__global__ void fuse_w_kernel(const float* __restrict__ Wp, const float* __restrict__ W1,
                              float* __restrict__ Wf) {
    int m = blockIdx.x;      // 0..63
    int j = threadIdx.x;     // 0..127
    float acc = 0.f;
#pragma unroll
    for (int d = 0; d < 64; d++) acc += Wp[m * 64 + d] * W1[d * 128 + j];
    Wf[m * 128 + j] = acc;
}

__global__ void fuse_b_kernel(const float* __restrict__ bp, const float* __restrict__ W1,
                              float* __restrict__ bf) {
    int j = threadIdx.x;     // 0..127
    float acc = 0.f;
#pragma unroll
    for (int d = 0; d < 64; d++) acc += bp[d] * W1[d * 128 + j];
    bf[j] = acc;
}

// ---------------- embed + token-mean -> mean[N,64] (no projection; Wp folded downstream) ----------------
// 256 threads = 4 nodes/block, one wave per node; lane (q,l): 4 emb rows per gather instr
__global__ void embed_mean_kernel(const int* __restrict__ tok,
                                  const float* __restrict__ emb,
                                  float* __restrict__ mean64, int N) {
    int t = threadIdx.x;
    int w = t >> 6, j = t & 63;
    int q = j >> 4, l = j & 15;
    int i = blockIdx.x * 4 + w;
    if (i >= N) return;
    const float4* e4 = (const float4*)emb;  // row = 16 float4
    int t0 = tok[i * 16 + q];
    int t1 = tok[i * 16 + q + 4];
    int t2 = tok[i * 16 + q + 8];
    int t3 = tok[i * 16 + q + 12];
    float4 v0 = e4[(size_t)t0 * 16 + l];
    float4 v1 = e4[(size_t)t1 * 16 + l];
    float4 v2 = e4[(size_t)t2 * 16 + l];
    float4 v3 = e4[(size_t)t3 * 16 + l];
    float4 s;
    s.x = v0.x + v1.x + v2.x + v3.x;
    s.y = v0.y + v1.y + v2.y + v3.y;
    s.z = v0.z + v1.z + v2.z + v3.z;
    s.w = v0.w + v1.w + v2.w + v3.w;
    s.x += __shfl_xor(s.x, 16); s.y += __shfl_xor(s.y, 16);
    s.z += __shfl_xor(s.z, 16); s.w += __shfl_xor(s.w, 16);
    s.x += __shfl_xor(s.x, 32); s.y += __shfl_xor(s.y, 32);
    s.z += __shfl_xor(s.z, 32); s.w += __shfl_xor(s.w, 32);
    if (q == 0) {
        const float inv = 1.0f / 16.0f;
        ((float4*)mean64)[(size_t)i * 16 + l] =
            make_float4(s.x * inv, s.y * inv, s.z * inv, s.w * inv);
    }
}

// ---------------- degree histogram ----------------
__global__ void hist_kernel(const int* __restrict__ dst, int* __restrict__ hist, int E) {
    int e = blockIdx.x * blockDim.x + threadIdx.x;
    if (e < E) atomicAdd(&hist[dst[e]], 1);
}

// ---------------- scan local + dis + cursor reset (fused) ----------------
__global__ void scan_local_kernel(int* __restrict__ hist, int* __restrict__ row_start,
                                  int* __restrict__ bsums, float* __restrict__ dis, int N) {
    __shared__ int s[SCAN_B];
    int tid = threadIdx.x;
    int i = blockIdx.x * SCAN_B + tid;
    int v = (i < N) ? hist[i] : 0;
    s[tid] = v;
    __syncthreads();
    for (int off = 1; off < SCAN_B; off <<= 1) {
        int add = (tid >= off) ? s[tid - off] : 0;
        __syncthreads();
        s[tid] += add;
        __syncthreads();
    }
    if (i < N) {
        row_start[i] = s[tid] - v;
        dis[i] = rsqrtf(1.0f + (float)v);  // +1 self loop
        hist[i] = 0;                       // hist doubles as cursor
    }
    if (tid == SCAN_B - 1) bsums[blockIdx.x] = s[SCAN_B - 1];
}

__global__ void scan_bsums_kernel(int* __restrict__ bsums, int nb) {
    __shared__ int s[512];
    int tid = threadIdx.x;
    int v = (tid < nb) ? bsums[tid] : 0;
    s[tid] = v;
    __syncthreads();
    for (int off = 1; off < 512; off <<= 1) {
        int add = (tid >= off) ? s[tid - off] : 0;
        __syncthreads();
        s[tid] += add;
        __syncthreads();
    }
    if (tid < nb) bsums[tid] = s[tid] - v;
    if (tid == 511) bsums[nb] = s[511];
}

__global__ void scan_add_kernel(int* __restrict__ row_start, const int* __restrict__ bsums,
                                int N, int nb) {
    int i = blockIdx.x * blockDim.x + threadIdx.x;
    if (i < N) row_start[i] += bsums[i >> 8];
    else if (i == N) row_start[N] = bsums[nb];
}

// ---------------- CSR fill, packed (src, weight) int2 ----------------
__global__ void fill_csr_kernel(const int* __restrict__ src, const int* __restrict__ dst,
                                const int* __restrict__ row_start, int* __restrict__ cursor,
                                const float* __restrict__ dis,
                                int2* __restrict__ csr, int E) {
    int e = blockIdx.x * blockDim.x + threadIdx.x;
    if (e < E) {
        int d = dst[e];
        int s = src[e];
        int pos = atomicAdd(&cursor[d], 1);
        int o = row_start[d] + pos;
        csr[o] = make_int2(s, __float_as_int(dis[s] * dis[d]));
    }
}

// ---------------- pure agg64 + rowsum: one wave per node, 8 gathers in flight ----------------
// lane (q,l): q=j>>4 edge slot, l=j&15 feature block (float4)
__global__ __launch_bounds__(256, 5)
void agg64_kernel(const float* __restrict__ mean64,
                  const int* __restrict__ row_start,
                  const int2* __restrict__ csr,
                  const float* __restrict__ dis,
                  float* __restrict__ agg,
                  float* __restrict__ rowsum, int N) {
    int t = threadIdx.x;
    int w = t >> 6, j = t & 63;
    int q = j >> 4, l = j & 15;
    int node = blockIdx.x * 4 + w;
    (void)w;
    if (node >= N) return;
    int beg = row_start[node];
    int end = row_start[node + 1];
    float d = dis[node];
    const float4* n4 = (const float4*)mean64;  // row = 16 float4
    float4 self = n4[(size_t)node * 16 + l];
    float d2 = d * d * ((q == 0) ? 1.f : 0.f);
    float4 acc = make_float4(self.x * d2, self.y * d2, self.z * d2, self.w * d2);
    float rs = 0.f;
    for (int k = beg; k < end; k += 32) {
        int2 e[8];
        float4 v[8];
#pragma unroll
        for (int m = 0; m < 8; m++) {
            int kk = k + 4 * m + q;
            e[m] = (kk < end) ? csr[kk] : make_int2(0, 0);
        }
#pragma unroll
        for (int m = 0; m < 8; m++) v[m] = n4[(size_t)e[m].x * 16 + l];
#pragma unroll
        for (int m = 0; m < 8; m++) {
            float wm = __int_as_float(e[m].y);
            acc.x += v[m].x * wm; acc.y += v[m].y * wm;
            acc.z += v[m].z * wm; acc.w += v[m].w * wm;
            rs += wm;
        }
    }
    // fold across q (bits 4,5 of lane id)
    acc.x += __shfl_xor(acc.x, 16); acc.y += __shfl_xor(acc.y, 16);
    acc.z += __shfl_xor(acc.z, 16); acc.w += __shfl_xor(acc.w, 16);
    acc.x += __shfl_xor(acc.x, 32); acc.y += __shfl_xor(acc.y, 32);
    acc.z += __shfl_xor(acc.z, 32); acc.w += __shfl_xor(acc.w, 32);
    rs += __shfl_xor(rs, 16);
    rs += __shfl_xor(rs, 32);
    if (q == 0) ((float4*)agg)[(size_t)node * 16 + l] = acc;
    if (j == 0) rowsum[node] = rs + d * d;
}

// ---------------- dense chain: h2 = relu(agg @ Wf + rowsum*bf + b1) @ W2 ----------------
// 256 threads, 32 nodes/block; thread t: col j=t&127, node group g=t>>7 (16 nodes each)
#define NB 32
__global__ void dense_chain_kernel(const float* __restrict__ agg,
                                   const float* __restrict__ rowsum,
                                   const float* __restrict__ Wf,
                                   const float* __restrict__ bf,
                                   const float* __restrict__ b1,
                                   const float* __restrict__ W2,
                                   float* __restrict__ h2, int N) {
    __shared__ float sa[NB][64];
    __shared__ float srs[NB];
    __shared__ float sx1[NB][128];
    int t = threadIdx.x;
    int nb0 = blockIdx.x * NB;
    const float4* a4 = (const float4*)agg;
#pragma unroll
    for (int r = 0; r < 2; r++) {
        int idx = r * 256 + t;  // 0..511
        int n = idx >> 4, l = idx & 15;
        int gi = nb0 + n;
        float4 v = (gi < N) ? a4[(size_t)gi * 16 + l] : make_float4(0, 0, 0, 0);
        ((float4*)sa[n])[l] = v;
    }
    if (t < NB) srs[t] = (nb0 + t < N) ? rowsum[nb0 + t] : 0.f;
    __syncthreads();
    int j = t & 127, g = t >> 7;  // g in {0,1}
    float bfj = bf[j], b1j = b1[j];
    float acc[16];
#pragma unroll
    for (int n = 0; n < 16; n++) acc[n] = 0.f;
#pragma unroll 4
    for (int k = 0; k < 64; k++) {
        float wv = Wf[k * 128 + j];
#pragma unroll
        for (int n = 0; n < 16; n++) acc[n] += sa[g * 16 + n][k] * wv;
    }
#pragma unroll
    for (int n = 0; n < 16; n++) {
        float z = acc[n] + srs[g * 16 + n] * bfj + b1j;
        sx1[g * 16 + n][j] = fmaxf(z, 0.f);
    }
    __syncthreads();
#pragma unroll
    for (int n = 0; n < 16; n++) acc[n] = 0.f;
#pragma unroll 4
    for (int k = 0; k < 128; k++) {
        float wv = W2[k * 128 + j];
#pragma unroll
        for (int n = 0; n < 16; n++) acc[n] += sx1[g * 16 + n][k] * wv;
    }
#pragma unroll
    for (int n = 0; n < 16; n++) {
        int gi = nb0 + g * 16 + n;
        if (gi < N) h2[(size_t)gi * 128 + j] = acc[n];
    }
}

// ---------------- layer 2: agg128 (2 rows per gather, 8 gathers in flight) + b2 + ReLU ----------------
// one wave per node; lane (h,l): h=j>>5 edge slot, l=j&31 feature block (float4)
__global__ __launch_bounds__(256, 5)
void gcn_agg128_kernel(const float* __restrict__ hsrc,
                       const int* __restrict__ row_start,
                       const int2* __restrict__ csr,
                       const float* __restrict__ dis,
                       const float* __restrict__ b2,
                       float* __restrict__ outx, int N) {
    int t = threadIdx.x;
    int w = t >> 6, j = t & 63;
    int hh = j >> 5, l = j & 31;
    int node = blockIdx.x * 4 + w;
    (void)w;
    if (node >= N) return;
    const float4* h4 = (const float4*)hsrc;  // row = 32 float4
    int beg = row_start[node];
    int end = row_start[node + 1];
    float d = dis[node];
    float4 self = h4[(size_t)node * 32 + l];
    float d2 = d * d * ((hh == 0) ? 1.f : 0.f);
    float4 acc = make_float4(self.x * d2, self.y * d2, self.z * d2, self.w * d2);
    for (int k = beg; k < end; k += 16) {
        int2 e[8];
        float4 v[8];
#pragma unroll
        for (int m = 0; m < 8; m++) {
            int kk = k + 2 * m + hh;
            e[m] = (kk < end) ? csr[kk] : make_int2(0, 0);
        }
#pragma unroll
        for (int m = 0; m < 8; m++) v[m] = h4[(size_t)e[m].x * 32 + l];
#pragma unroll
        for (int m = 0; m < 8; m++) {
            float wm = __int_as_float(e[m].y);
            acc.x += v[m].x * wm; acc.y += v[m].y * wm;
            acc.z += v[m].z * wm; acc.w += v[m].w * wm;
        }
    }
    acc.x += __shfl_xor(acc.x, 32); acc.y += __shfl_xor(acc.y, 32);
    acc.z += __shfl_xor(acc.z, 32); acc.w += __shfl_xor(acc.w, 32);
    if (hh == 0) {
        const float4* b4 = (const float4*)b2;
        float4 bb = b4[l];
        float4 o;
        o.x = fmaxf(acc.x + bb.x, 0.f);
        o.y = fmaxf(acc.y + bb.y, 0.f);
        o.z = fmaxf(acc.z + bb.z, 0.f);
        o.w = fmaxf(acc.w + bb.w, 0.f);
        ((float4*)outx)[(size_t)node * 32 + l] = o;
    }
}

// ---------------- atomic-free global mean pool (batch sorted), float2 ----------------
__device__ __forceinline__ int lower_bound_i(const int* __restrict__ a, int n, int val) {
    int lo = 0, hi = n;
    while (lo < hi) {
        int mid = (lo + hi) >> 1;
        if (a[mid] < val) lo = mid + 1; else hi = mid;
    }
    return lo;
}

__global__ void pool_mean_kernel(const float* __restrict__ x,
                                 const int* __restrict__ batch,
                                 float* __restrict__ g, int N) {
    int t = threadIdx.x;
    int w = t >> 6, j = t & 63;
    int gr = blockIdx.x * 4 + w;
    if (gr >= NUM_GRAPHS) return;
    int beg = lower_bound_i(batch, N, gr);
    int end = lower_bound_i(batch, N, gr + 1);
    const float2* x2 = (const float2*)x;
    float2 acc = make_float2(0.f, 0.f);
    int i = beg;
    for (; i + 4 <= end; i += 4) {
        float2 a0 = x2[(size_t)i * 64 + j];
        float2 a1 = x2[(size_t)(i + 1) * 64 + j];
        float2 a2 = x2[(size_t)(i + 2) * 64 + j];
        float2 a3 = x2[(size_t)(i + 3) * 64 + j];
        acc.x += a0.x + a1.x + a2.x + a3.x;
        acc.y += a0.y + a1.y + a2.y + a3.y;
    }
    for (; i < end; i++) {
        float2 a = x2[(size_t)i * 64 + j];
        acc.x += a.x; acc.y += a.y;
    }
    float inv = 1.0f / fmaxf((float)(end - beg), 1.0f);
    ((float2*)g)[(size_t)gr * 64 + j] = make_float2(acc.x * inv, acc.y * inv);
}

// ---------------- head ----------------
__global__ void head_kernel(const float* __restrict__ g,
                            const float* __restrict__ Wfc,
                            const float* __restrict__ bfc,
                            const float* __restrict__ Wout,
                            const float* __restrict__ bout,
                            float* __restrict__ out) {
    int gr = blockIdx.x;
    int j = threadIdx.x;  // 0..127
    __shared__ float sg[128];
    __shared__ float sred[128];
    sg[j] = g[gr * 128 + j];
    __syncthreads();
    float acc = bfc[j];
#pragma unroll
    for (int k = 0; k < 128; k++) acc += sg[k] * Wfc[k * 128 + j];
    float f = fmaxf(acc, 0.f);
    sred[j] = f * Wout[j];
    __syncthreads();
    if (j < 64) sred[j] += sred[j + 64];
    __syncthreads();
    if (j < 64) {
        float v = sred[j];
#pragma unroll
        for (int off = 32; off > 0; off >>= 1) v += __shfl_down(v, off);
        if (j == 0) {
            float logit = v + bout[0];
            out[gr] = 1.0f / (1.0f + expf(-logit));
            out[NUM_GRAPHS + gr] = logit;
        }
    }
}

extern "C" void kernel_launch(void* const* d_in, const int* in_sizes, int n_in,
                              void* d_out, int out_size, void* d_ws, size_t ws_size,
                              hipStream_t stream) {
    const int* tok   = (const int*)d_in[0];
    const int* eidx  = (const int*)d_in[1];
    const int* batch = (const int*)d_in[2];
    const float* emb = (const float*)d_in[3];
    const float* Wp  = (const float*)d_in[4];
    const float* bp  = (const float*)d_in[5];
    const float* W1  = (const float*)d_in[6];
    const float* b1  = (const float*)d_in[7];
    const float* W2  = (const float*)d_in[8];
    const float* b2  = (const float*)d_in[9];
    const float* Wfc = (const float*)d_in[10];
    const float* bfc = (const float*)d_in[11];
    const float* Wout= (const float*)d_in[12];
    const float* bout= (const float*)d_in[13];
    float* out = (float*)d_out;

    const int N = in_sizes[2];
    const int E = in_sizes[1] / 2;
    const int* src = eidx;
    const int* dst = eidx + E;
    const int nb_scan = (N + SCAN_B - 1) / SCAN_B;
    const int Np = (N + 3) & ~3;

    // workspace layout (floats); A = mean (low half) then h2 (full, after mean is dead)
    float* ws = (float*)d_ws;
    float* dis    = ws;                            // Np
    float* Abuf   = dis + Np;                      // Np*128: mean64 in first Np*64, later h2
    float* mean64 = Abuf;
    float* h2buf  = Abuf;
    float* aggbuf = Abuf + (size_t)Np * 128;       // Np*64
    float* rowsum = aggbuf + (size_t)Np * 64;      // Np
    float* xfin   = rowsum + Np;                   // Np*128
    float* g      = xfin + (size_t)Np * 128;       // 1024*128
    float* Wf     = g + NUM_GRAPHS * 128;          // 64*128
    float* bf     = Wf + 64 * 128;                 // 128
    int* row_start = (int*)(bf + 128);             // Np+4
    int* hist      = row_start + Np + 4;           // Np (doubles as cursor)
    int* bsums     = hist + Np;                    // 1028 (pad for csr 16B alignment)
    int2* csr      = (int2*)(bsums + 1028);        // E int2

    // --- fused projection weights (tiny) ---
    fuse_w_kernel<<<64, 128, 0, stream>>>(Wp, W1, Wf);
    fuse_b_kernel<<<1, 128, 0, stream>>>(bp, W1, bf);

    // --- degree histogram ---
    hipMemsetAsync(hist, 0, N * sizeof(int), stream);
    hist_kernel<<<(E + 255) / 256, 256, 0, stream>>>(dst, hist, E);

    // --- scan (fused: dis + cursor reset) ---
    scan_local_kernel<<<nb_scan, SCAN_B, 0, stream>>>(hist, row_start, bsums, dis, N);
    scan_bsums_kernel<<<1, 512, 0, stream>>>(bsums, nb_scan);
    scan_add_kernel<<<(N + 1 + 255) / 256, 256, 0, stream>>>(row_start, bsums, N, nb_scan);

    // --- CSR fill ---
    fill_csr_kernel<<<(E + 255) / 256, 256, 0, stream>>>(src, dst, row_start, hist, dis,
                                                         csr, E);

    // --- embed + token-mean -> mean64 ---
    embed_mean_kernel<<<(N + 3) / 4, 256, 0, stream>>>(tok, emb, mean64, N);

    // --- pure 64-dim aggregate + rowsum ---
    agg64_kernel<<<(N + 3) / 4, 256, 0, stream>>>(mean64, row_start, csr, dis,
                                                  aggbuf, rowsum, N);

    // --- dense chain: h2 = relu(agg@Wf + rowsum*bf + b1) @ W2 (overwrites mean region) ---
    dense_chain_kernel<<<(N + NB - 1) / NB, 256, 0, stream>>>(aggbuf, rowsum, Wf, bf, b1,
                                                              W2, h2buf, N);

    // --- layer 2 aggregate + b2 + ReLU -> xfin ---
    gcn_agg128_kernel<<<(N + 3) / 4, 256, 0, stream>>>(h2buf, row_start, csr, dis, b2,
                                                       xfin, N);

    // --- global mean pool + head ---
    pool_mean_kernel<<<(NUM_GRAPHS + 3) / 4, 256, 0, stream>>>(xfin, batch, g, N);
    head_kernel<<<NUM_GRAPHS, 128, 0, stream>>>(g, Wfc, bfc, Wout, bout, out);
}

// Round 10
// 509.167 us; speedup vs baseline: 1.8304x; 1.1708x over previous
//
#include <hip/hip_runtime.h>
#include <hip/hip_bf16.h>
#include <hip/hip_fp16.h>
#include <math.h>

#define N_TOKENS 16
#define TOK_DIM 64
#define NODE_DIM 64
#define HID 128
#define FC 128
#define NUM_GRAPHS 1024
#define SCAN_B 256

// ---------------- fused-weight precompute: Wf = Wp @ W1 (64x128), bf = bp @ W1 ----------------
__global__ void fuse_w_kernel(const float* __restrict__ Wp, const float* __restrict__ W1,
                              float* __restrict__ Wf) {
    int m = blockIdx.x;      // 0..63
    int j = threadIdx.x;     // 0..127
    float acc = 0.f;
#pragma unroll
    for (int d = 0; d < 64; d++) acc += Wp[m * 64 + d] * W1[d * 128 + j];
    Wf[m * 128 + j] = acc;
}

__global__ void fuse_b_kernel(const float* __restrict__ bp, const float* __restrict__ W1,
                              float* __restrict__ bf) {
    int j = threadIdx.x;     // 0..127
    float acc = 0.f;
#pragma unroll
    for (int d = 0; d < 64; d++) acc += bp[d] * W1[d * 128 + j];
    bf[j] = acc;
}

// ---------------- embed + token-mean -> mean16[N,64] (fp16 storage) ----------------
// 256 threads = 4 nodes/block, one wave per node; lane (q,l): 4 emb rows per gather instr
__global__ void embed_mean_kernel(const int* __restrict__ tok,
                                  const float* __restrict__ emb,
                                  __half* __restrict__ mean16, int N) {
    int t = threadIdx.x;
    int w = t >> 6, j = t & 63;
    int q = j >> 4, l = j & 15;
    int i = blockIdx.x * 4 + w;
    if (i >= N) return;
    const float4* e4 = (const float4*)emb;  // row = 16 float4
    int t0 = tok[i * 16 + q];
    int t1 = tok[i * 16 + q + 4];
    int t2 = tok[i * 16 + q + 8];
    int t3 = tok[i * 16 + q + 12];
    float4 v0 = e4[(size_t)t0 * 16 + l];
    float4 v1 = e4[(size_t)t1 * 16 + l];
    float4 v2 = e4[(size_t)t2 * 16 + l];
    float4 v3 = e4[(size_t)t3 * 16 + l];
    float4 s;
    s.x = v0.x + v1.x + v2.x + v3.x;
    s.y = v0.y + v1.y + v2.y + v3.y;
    s.z = v0.z + v1.z + v2.z + v3.z;
    s.w = v0.w + v1.w + v2.w + v3.w;
    s.x += __shfl_xor(s.x, 16); s.y += __shfl_xor(s.y, 16);
    s.z += __shfl_xor(s.z, 16); s.w += __shfl_xor(s.w, 16);
    s.x += __shfl_xor(s.x, 32); s.y += __shfl_xor(s.y, 32);
    s.z += __shfl_xor(s.z, 32); s.w += __shfl_xor(s.w, 32);
    if (q == 0) {
        const float inv = 1.0f / 16.0f;
        __half2 h0 = __floats2half2_rn(s.x * inv, s.y * inv);
        __half2 h1 = __floats2half2_rn(s.z * inv, s.w * inv);
        float2 packed;
        ((__half2*)&packed)[0] = h0;
        ((__half2*)&packed)[1] = h1;
        ((float2*)mean16)[(size_t)i * 16 + l] = packed;  // features l*4..l*4+3
    }
}

// ---------------- degree histogram ----------------
__global__ void hist_kernel(const int* __restrict__ dst, int* __restrict__ hist, int E) {
    int e = blockIdx.x * blockDim.x + threadIdx.x;
    if (e < E) atomicAdd(&hist[dst[e]], 1);
}

// ---------------- scan local + dis + cursor reset (fused) ----------------
__global__ void scan_local_kernel(int* __restrict__ hist, int* __restrict__ row_start,
                                  int* __restrict__ bsums, float* __restrict__ dis, int N) {
    __shared__ int s[SCAN_B];
    int tid = threadIdx.x;
    int i = blockIdx.x * SCAN_B + tid;
    int v = (i < N) ? hist[i] : 0;
    s[tid] = v;
    __syncthreads();
    for (int off = 1; off < SCAN_B; off <<= 1) {
        int add = (tid >= off) ? s[tid - off] : 0;
        __syncthreads();
        s[tid] += add;
        __syncthreads();
    }
    if (i < N) {
        row_start[i] = s[tid] - v;
        dis[i] = rsqrtf(1.0f + (float)v);  // +1 self loop
        hist[i] = 0;                       // hist doubles as cursor
    }
    if (tid == SCAN_B - 1) bsums[blockIdx.x] = s[SCAN_B - 1];
}

__global__ void scan_bsums_kernel(int* __restrict__ bsums, int nb) {
    __shared__ int s[512];
    int tid = threadIdx.x;
    int v = (tid < nb) ? bsums[tid] : 0;
    s[tid] = v;
    __syncthreads();
    for (int off = 1; off < 512; off <<= 1) {
        int add = (tid >= off) ? s[tid - off] : 0;
        __syncthreads();
        s[tid] += add;
        __syncthreads();
    }
    if (tid < nb) bsums[tid] = s[tid] - v;
    if (tid == 511) bsums[nb] = s[511];
}

__global__ void scan_add_kernel(int* __restrict__ row_start, const int* __restrict__ bsums,
                                int N, int nb) {
    int i = blockIdx.x * blockDim.x + threadIdx.x;
    if (i < N) row_start[i] += bsums[i >> 8];
    else if (i == N) row_start[N] = bsums[nb];
}

// ---------------- CSR fill, packed (src, weight) int2 ----------------
__global__ void fill_csr_kernel(const int* __restrict__ src, const int* __restrict__ dst,
                                const int* __restrict__ row_start, int* __restrict__ cursor,
                                const float* __restrict__ dis,
                                int2* __restrict__ csr, int E) {
    int e = blockIdx.x * blockDim.x + threadIdx.x;
    if (e < E) {
        int d = dst[e];
        int s = src[e];
        int pos = atomicAdd(&cursor[d], 1);
        int o = row_start[d] + pos;
        csr[o] = make_int2(s, __float_as_int(dis[s] * dis[d]));
    }
}

// ---------------- pure agg64 (fp16 rows, 8 rows per gather instr) + rowsum ----------------
// lane (q,l): q=j>>3 edge slot (8), l=j&7 feature block (float4 = 8 halfs)
__global__ __launch_bounds__(256, 5)
void agg64_kernel(const __half* __restrict__ mean16,
                  const int* __restrict__ row_start,
                  const int2* __restrict__ csr,
                  const float* __restrict__ dis,
                  float* __restrict__ agg,
                  float* __restrict__ rowsum, int N) {
    int t = threadIdx.x;
    int w = t >> 6, j = t & 63;
    int q = j >> 3, l = j & 7;
    int node = blockIdx.x * 4 + w;
    if (node >= N) return;
    int beg = row_start[node];
    int end = row_start[node + 1];
    float d = dis[node];
    const float4* m4 = (const float4*)mean16;  // row = 8 float4 (64 halfs)
    float acc[8];
    {
        float4 raw = m4[(size_t)node * 8 + l];
        const __half2* hp = (const __half2*)&raw;
        float d2 = d * d * ((q == 0) ? 1.f : 0.f);
        float2 f0 = __half22float2(hp[0]);
        float2 f1 = __half22float2(hp[1]);
        float2 f2 = __half22float2(hp[2]);
        float2 f3 = __half22float2(hp[3]);
        acc[0] = f0.x * d2; acc[1] = f0.y * d2; acc[2] = f1.x * d2; acc[3] = f1.y * d2;
        acc[4] = f2.x * d2; acc[5] = f2.y * d2; acc[6] = f3.x * d2; acc[7] = f3.y * d2;
    }
    float rs = 0.f;
    for (int k = beg; k < end; k += 32) {  // 4 gathers x 8 rows = 32 edges/iter
        int2 e[4];
        float4 v[4];
#pragma unroll
        for (int m = 0; m < 4; m++) {
            int kk = k + 8 * m + q;
            e[m] = (kk < end) ? csr[kk] : make_int2(0, 0);
        }
#pragma unroll
        for (int m = 0; m < 4; m++) v[m] = m4[(size_t)e[m].x * 8 + l];
#pragma unroll
        for (int m = 0; m < 4; m++) {
            float wm = __int_as_float(e[m].y);
            const __half2* hp = (const __half2*)&v[m];
            float2 f0 = __half22float2(hp[0]);
            float2 f1 = __half22float2(hp[1]);
            float2 f2 = __half22float2(hp[2]);
            float2 f3 = __half22float2(hp[3]);
            acc[0] += f0.x * wm; acc[1] += f0.y * wm;
            acc[2] += f1.x * wm; acc[3] += f1.y * wm;
            acc[4] += f2.x * wm; acc[5] += f2.y * wm;
            acc[6] += f3.x * wm; acc[7] += f3.y * wm;
            rs += wm;
        }
    }
    // fold across q (lane bits 3,4,5)
#pragma unroll
    for (int i = 0; i < 8; i++) {
        acc[i] += __shfl_xor(acc[i], 8);
        acc[i] += __shfl_xor(acc[i], 16);
        acc[i] += __shfl_xor(acc[i], 32);
    }
    rs += __shfl_xor(rs, 8);
    rs += __shfl_xor(rs, 16);
    rs += __shfl_xor(rs, 32);
    if (q == 0) {
        ((float4*)agg)[(size_t)node * 16 + l * 2] = make_float4(acc[0], acc[1], acc[2], acc[3]);
        ((float4*)agg)[(size_t)node * 16 + l * 2 + 1] = make_float4(acc[4], acc[5], acc[6], acc[7]);
    }
    if (j == 0) rowsum[node] = rs + d * d;
}

// ---------------- dense chain: h2 = relu(agg @ Wf + rowsum*bf + b1) @ W2 -> fp16 ----------------
// 256 threads, 32 nodes/block; thread t: col j=t&127, node group g=t>>7 (16 nodes each)
#define NB 32
__global__ void dense_chain_kernel(const float* __restrict__ agg,
                                   const float* __restrict__ rowsum,
                                   const float* __restrict__ Wf,
                                   const float* __restrict__ bf,
                                   const float* __restrict__ b1,
                                   const float* __restrict__ W2,
                                   __half* __restrict__ h2, int N) {
    __shared__ float sa[NB][64];
    __shared__ float srs[NB];
    __shared__ float sx1[NB][128];
    int t = threadIdx.x;
    int nb0 = blockIdx.x * NB;
    const float4* a4 = (const float4*)agg;
#pragma unroll
    for (int r = 0; r < 2; r++) {
        int idx = r * 256 + t;  // 0..511
        int n = idx >> 4, l = idx & 15;
        int gi = nb0 + n;
        float4 v = (gi < N) ? a4[(size_t)gi * 16 + l] : make_float4(0, 0, 0, 0);
        ((float4*)sa[n])[l] = v;
    }
    if (t < NB) srs[t] = (nb0 + t < N) ? rowsum[nb0 + t] : 0.f;
    __syncthreads();
    int j = t & 127, g = t >> 7;  // g in {0,1}
    float bfj = bf[j], b1j = b1[j];
    float acc[16];
#pragma unroll
    for (int n = 0; n < 16; n++) acc[n] = 0.f;
#pragma unroll 4
    for (int k = 0; k < 64; k++) {
        float wv = Wf[k * 128 + j];
#pragma unroll
        for (int n = 0; n < 16; n++) acc[n] += sa[g * 16 + n][k] * wv;
    }
#pragma unroll
    for (int n = 0; n < 16; n++) {
        float z = acc[n] + srs[g * 16 + n] * bfj + b1j;
        sx1[g * 16 + n][j] = fmaxf(z, 0.f);
    }
    __syncthreads();
#pragma unroll
    for (int n = 0; n < 16; n++) acc[n] = 0.f;
#pragma unroll 4
    for (int k = 0; k < 128; k++) {
        float wv = W2[k * 128 + j];
#pragma unroll
        for (int n = 0; n < 16; n++) acc[n] += sx1[g * 16 + n][k] * wv;
    }
#pragma unroll
    for (int n = 0; n < 16; n++) {
        int gi = nb0 + g * 16 + n;
        if (gi < N) h2[(size_t)gi * 128 + j] = __float2half(acc[n]);
    }
}

// ---------------- layer 2: agg128 (fp16 rows, 4 rows per gather) + b2 + ReLU -> fp32 ----------------
// lane (q,l): q=j>>4 edge slot (4), l=j&15 feature block (float4 = 8 halfs)
__global__ __launch_bounds__(256, 5)
void gcn_agg128_kernel(const __half* __restrict__ hsrc,
                       const int* __restrict__ row_start,
                       const int2* __restrict__ csr,
                       const float* __restrict__ dis,
                       const float* __restrict__ b2,
                       float* __restrict__ outx, int N) {
    int t = threadIdx.x;
    int w = t >> 6, j = t & 63;
    int q = j >> 4, l = j & 15;
    int node = blockIdx.x * 4 + w;
    if (node >= N) return;
    const float4* h4 = (const float4*)hsrc;  // row = 16 float4 (128 halfs)
    int beg = row_start[node];
    int end = row_start[node + 1];
    float d = dis[node];
    float acc[8];
    {
        float4 raw = h4[(size_t)node * 16 + l];
        const __half2* hp = (const __half2*)&raw;
        float d2 = d * d * ((q == 0) ? 1.f : 0.f);
        float2 f0 = __half22float2(hp[0]);
        float2 f1 = __half22float2(hp[1]);
        float2 f2 = __half22float2(hp[2]);
        float2 f3 = __half22float2(hp[3]);
        acc[0] = f0.x * d2; acc[1] = f0.y * d2; acc[2] = f1.x * d2; acc[3] = f1.y * d2;
        acc[4] = f2.x * d2; acc[5] = f2.y * d2; acc[6] = f3.x * d2; acc[7] = f3.y * d2;
    }
    for (int k = beg; k < end; k += 32) {  // 8 gathers x 4 rows = 32 edges/iter
        int2 e[8];
        float4 v[8];
#pragma unroll
        for (int m = 0; m < 8; m++) {
            int kk = k + 4 * m + q;
            e[m] = (kk < end) ? csr[kk] : make_int2(0, 0);
        }
#pragma unroll
        for (int m = 0; m < 8; m++) v[m] = h4[(size_t)e[m].x * 16 + l];
#pragma unroll
        for (int m = 0; m < 8; m++) {
            float wm = __int_as_float(e[m].y);
            const __half2* hp = (const __half2*)&v[m];
            float2 f0 = __half22float2(hp[0]);
            float2 f1 = __half22float2(hp[1]);
            float2 f2 = __half22float2(hp[2]);
            float2 f3 = __half22float2(hp[3]);
            acc[0] += f0.x * wm; acc[1] += f0.y * wm;
            acc[2] += f1.x * wm; acc[3] += f1.y * wm;
            acc[4] += f2.x * wm; acc[5] += f2.y * wm;
            acc[6] += f3.x * wm; acc[7] += f3.y * wm;
        }
    }
#pragma unroll
    for (int i = 0; i < 8; i++) {
        acc[i] += __shfl_xor(acc[i], 16);
        acc[i] += __shfl_xor(acc[i], 32);
    }
    if (q == 0) {
        const float4* b4 = (const float4*)b2;
        float4 ba = b4[l * 2], bb = b4[l * 2 + 1];
        float4 o0, o1;
        o0.x = fmaxf(acc[0] + ba.x, 0.f);
        o0.y = fmaxf(acc[1] + ba.y, 0.f);
        o0.z = fmaxf(acc[2] + ba.z, 0.f);
        o0.w = fmaxf(acc[3] + ba.w, 0.f);
        o1.x = fmaxf(acc[4] + bb.x, 0.f);
        o1.y = fmaxf(acc[5] + bb.y, 0.f);
        o1.z = fmaxf(acc[6] + bb.z, 0.f);
        o1.w = fmaxf(acc[7] + bb.w, 0.f);
        ((float4*)outx)[(size_t)node * 32 + l * 2] = o0;
        ((float4*)outx)[(size_t)node * 32 + l * 2 + 1] = o1;
    }
}

// ---------------- atomic-free global mean pool (batch sorted), float2 ----------------
__device__ __forceinline__ int lower_bound_i(const int* __restrict__ a, int n, int val) {
    int lo = 0, hi = n;
    while (lo < hi) {
        int mid = (lo + hi) >> 1;
        if (a[mid] < val) lo = mid + 1; else hi = mid;
    }
    return lo;
}

__global__ void pool_mean_kernel(const float* __restrict__ x,
                                 const int* __restrict__ batch,
                                 float* __restrict__ g, int N) {
    int t = threadIdx.x;
    int w = t >> 6, j = t & 63;
    int gr = blockIdx.x * 4 + w;
    if (gr >= NUM_GRAPHS) return;
    int beg = lower_bound_i(batch, N, gr);
    int end = lower_bound_i(batch, N, gr + 1);
    const float2* x2 = (const float2*)x;
    float2 acc = make_float2(0.f, 0.f);
    int i = beg;
    for (; i + 4 <= end; i += 4) {
        float2 a0 = x2[(size_t)i * 64 + j];
        float2 a1 = x2[(size_t)(i + 1) * 64 + j];
        float2 a2 = x2[(size_t)(i + 2) * 64 + j];
        float2 a3 = x2[(size_t)(i + 3) * 64 + j];
        acc.x += a0.x + a1.x + a2.x + a3.x;
        acc.y += a0.y + a1.y + a2.y + a3.y;
    }
    for (; i < end; i++) {
        float2 a = x2[(size_t)i * 64 + j];
        acc.x += a.x; acc.y += a.y;
    }
    float inv = 1.0f / fmaxf((float)(end - beg), 1.0f);
    ((float2*)g)[(size_t)gr * 64 + j] = make_float2(acc.x * inv, acc.y * inv);
}

// ---------------- head ----------------
__global__ void head_kernel(const float* __restrict__ g,
                            const float* __restrict__ Wfc,
                            const float* __restrict__ bfc,
                            const float* __restrict__ Wout,
                            const float* __restrict__ bout,
                            float* __restrict__ out) {
    int gr = blockIdx.x;
    int j = threadIdx.x;  // 0..127
    __shared__ float sg[128];
    __shared__ float sred[128];
    sg[j] = g[gr * 128 + j];
    __syncthreads();
    float acc = bfc[j];
#pragma unroll
    for (int k = 0; k < 128; k++) acc += sg[k] * Wfc[k * 128 + j];
    float f = fmaxf(acc, 0.f);
    sred[j] = f * Wout[j];
    __syncthreads();
    if (j < 64) sred[j] += sred[j + 64];
    __syncthreads();
    if (j < 64) {
        float v = sred[j];
#pragma unroll
        for (int off = 32; off > 0; off >>= 1) v += __shfl_down(v, off);
        if (j == 0) {
            float logit = v + bout[0];
            out[gr] = 1.0f / (1.0f + expf(-logit));
            out[NUM_GRAPHS + gr] = logit;
        }
    }
}

extern "C" void kernel_launch(void* const* d_in, const int* in_sizes, int n_in,
                              void* d_out, int out_size, void* d_ws, size_t ws_size,
                              hipStream_t stream) {
    const int* tok   = (const int*)d_in[0];
    const int* eidx  = (const int*)d_in[1];
    const int* batch = (const int*)d_in[2];
    const float* emb = (const float*)d_in[3];
    const float* Wp  = (const float*)d_in[4];
    const float* bp  = (const float*)d_in[5];
    const float* W1  = (const float*)d_in[6];
    const float* b1  = (const float*)d_in[7];
    const float* W2  = (const float*)d_in[8];
    const float* b2  = (const float*)d_in[9];
    const float* Wfc = (const float*)d_in[10];
    const float* bfc = (const float*)d_in[11];
    const float* Wout= (const float*)d_in[12];
    const float* bout= (const float*)d_in[13];
    float* out = (float*)d_out;

    const int N = in_sizes[2];
    const int E = in_sizes[1] / 2;
    const int* src = eidx;
    const int* dst = eidx + E;
    const int nb_scan = (N + SCAN_B - 1) / SCAN_B;
    const int Np = (N + 3) & ~3;

    // workspace layout (floats); fp16 buffers sized in float units (halved)
    float* ws = (float*)d_ws;
    float* dis     = ws;                            // Np
    __half* mean16 = (__half*)(dis + Np);           // Np*64 halfs = Np*32 floats
    float* aggbuf  = dis + Np + (size_t)Np * 32;    // Np*64
    float* rowsum  = aggbuf + (size_t)Np * 64;      // Np
    __half* h2buf  = (__half*)(rowsum + Np);        // Np*128 halfs = Np*64 floats
    float* xfin    = rowsum + Np + (size_t)Np * 64; // Np*128
    float* g       = xfin + (size_t)Np * 128;       // 1024*128
    float* Wf      = g + NUM_GRAPHS * 128;          // 64*128
    float* bf      = Wf + 64 * 128;                 // 128
    int* row_start = (int*)(bf + 128);              // Np+4
    int* hist      = row_start + Np + 4;            // Np (doubles as cursor)
    int* bsums     = hist + Np;                     // 1028 (pad for csr 16B alignment)
    int2* csr      = (int2*)(bsums + 1028);         // E int2

    // --- fused projection weights (tiny) ---
    fuse_w_kernel<<<64, 128, 0, stream>>>(Wp, W1, Wf);
    fuse_b_kernel<<<1, 128, 0, stream>>>(bp, W1, bf);

    // --- degree histogram ---
    hipMemsetAsync(hist, 0, N * sizeof(int), stream);
    hist_kernel<<<(E + 255) / 256, 256, 0, stream>>>(dst, hist, E);

    // --- scan (fused: dis + cursor reset) ---
    scan_local_kernel<<<nb_scan, SCAN_B, 0, stream>>>(hist, row_start, bsums, dis, N);
    scan_bsums_kernel<<<1, 512, 0, stream>>>(bsums, nb_scan);
    scan_add_kernel<<<(N + 1 + 255) / 256, 256, 0, stream>>>(row_start, bsums, N, nb_scan);

    // --- CSR fill ---
    fill_csr_kernel<<<(E + 255) / 256, 256, 0, stream>>>(src, dst, row_start, hist, dis,
                                                         csr, E);

    // --- embed + token-mean -> mean16 (fp16) ---
    embed_mean_kernel<<<(N + 3) / 4, 256, 0, stream>>>(tok, emb, mean16, N);

    // --- pure 64-dim aggregate + rowsum ---
    agg64_kernel<<<(N + 3) / 4, 256, 0, stream>>>(mean16, row_start, csr, dis,
                                                  aggbuf, rowsum, N);

    // --- dense chain: h2 = relu(agg@Wf + rowsum*bf + b1) @ W2 -> fp16 ---
    dense_chain_kernel<<<(N + NB - 1) / NB, 256, 0, stream>>>(aggbuf, rowsum, Wf, bf, b1,
                                                              W2, h2buf, N);

    // --- layer 2 aggregate + b2 + ReLU -> xfin (fp32) ---
    gcn_agg128_kernel<<<(N + 3) / 4, 256, 0, stream>>>(h2buf, row_start, csr, dis, b2,
                                                       xfin, N);

    // --- global mean pool + head ---
    pool_mean_kernel<<<(NUM_GRAPHS + 3) / 4, 256, 0, stream>>>(xfin, batch, g, N);
    head_kernel<<<NUM_GRAPHS, 128, 0, stream>>>(g, Wfc, bfc, Wout, bout, out);
}

// Round 11
// 458.827 us; speedup vs baseline: 2.0312x; 1.1097x over previous
//
#include <hip/hip_runtime.h>
#include <hip/hip_bf16.h>
#include <hip/hip_fp16.h>
#include <math.h>

#define N_TOKENS 16
#define TOK_DIM 64
#define NODE_DIM 64
#define HID 128
#define FC 128
#define NUM_GRAPHS 1024
#define SCAN_B 256

typedef _Float16 f16x8 __attribute__((ext_vector_type(8)));
typedef float f32x4 __attribute__((ext_vector_type(4)));

// ---------------- fused fp16 transposed weights: Wf16t[n][k] = (Wp@W1)^T, bf = bp@W1 ----------------
__global__ void fuse_wt_kernel(const float* __restrict__ Wp, const float* __restrict__ W1,
                               _Float16* __restrict__ Wf16t) {
    int n = blockIdx.x;      // 0..127
    int m = threadIdx.x;     // 0..63
    float acc = 0.f;
#pragma unroll
    for (int d = 0; d < 64; d++) acc += Wp[m * 64 + d] * W1[d * 128 + n];
    Wf16t[(size_t)n * 64 + m] = (_Float16)acc;
}

__global__ void fuse_b_kernel(const float* __restrict__ bp, const float* __restrict__ W1,
                              float* __restrict__ bf) {
    int j = threadIdx.x;     // 0..127
    float acc = 0.f;
#pragma unroll
    for (int d = 0; d < 64; d++) acc += bp[d] * W1[d * 128 + j];
    bf[j] = acc;
}

__global__ void convert_w2t_kernel(const float* __restrict__ W2, _Float16* __restrict__ W2t) {
    int n = blockIdx.x;      // 0..127
    int k = threadIdx.x;     // 0..127
    W2t[(size_t)n * 128 + k] = (_Float16)W2[(size_t)k * 128 + n];
}

// ---------------- embed + token-mean -> mean16[N,64] (fp16 storage) ----------------
__global__ void embed_mean_kernel(const int* __restrict__ tok,
                                  const float* __restrict__ emb,
                                  __half* __restrict__ mean16, int N) {
    int t = threadIdx.x;
    int w = t >> 6, j = t & 63;
    int q = j >> 4, l = j & 15;
    int i = blockIdx.x * 4 + w;
    if (i >= N) return;
    const float4* e4 = (const float4*)emb;  // row = 16 float4
    int t0 = tok[i * 16 + q];
    int t1 = tok[i * 16 + q + 4];
    int t2 = tok[i * 16 + q + 8];
    int t3 = tok[i * 16 + q + 12];
    float4 v0 = e4[(size_t)t0 * 16 + l];
    float4 v1 = e4[(size_t)t1 * 16 + l];
    float4 v2 = e4[(size_t)t2 * 16 + l];
    float4 v3 = e4[(size_t)t3 * 16 + l];
    float4 s;
    s.x = v0.x + v1.x + v2.x + v3.x;
    s.y = v0.y + v1.y + v2.y + v3.y;
    s.z = v0.z + v1.z + v2.z + v3.z;
    s.w = v0.w + v1.w + v2.w + v3.w;
    s.x += __shfl_xor(s.x, 16); s.y += __shfl_xor(s.y, 16);
    s.z += __shfl_xor(s.z, 16); s.w += __shfl_xor(s.w, 16);
    s.x += __shfl_xor(s.x, 32); s.y += __shfl_xor(s.y, 32);
    s.z += __shfl_xor(s.z, 32); s.w += __shfl_xor(s.w, 32);
    if (q == 0) {
        const float inv = 1.0f / 16.0f;
        __half2 h0 = __floats2half2_rn(s.x * inv, s.y * inv);
        __half2 h1 = __floats2half2_rn(s.z * inv, s.w * inv);
        float2 packed;
        ((__half2*)&packed)[0] = h0;
        ((__half2*)&packed)[1] = h1;
        ((float2*)mean16)[(size_t)i * 16 + l] = packed;
    }
}

// ---------------- degree histogram ----------------
__global__ void hist_kernel(const int* __restrict__ dst, int* __restrict__ hist, int E) {
    int e = blockIdx.x * blockDim.x + threadIdx.x;
    if (e < E) atomicAdd(&hist[dst[e]], 1);
}

// ---------------- scan local + dis + cursor reset (fused) ----------------
__global__ void scan_local_kernel(int* __restrict__ hist, int* __restrict__ row_start,
                                  int* __restrict__ bsums, float* __restrict__ dis, int N) {
    __shared__ int s[SCAN_B];
    int tid = threadIdx.x;
    int i = blockIdx.x * SCAN_B + tid;
    int v = (i < N) ? hist[i] : 0;
    s[tid] = v;
    __syncthreads();
    for (int off = 1; off < SCAN_B; off <<= 1) {
        int add = (tid >= off) ? s[tid - off] : 0;
        __syncthreads();
        s[tid] += add;
        __syncthreads();
    }
    if (i < N) {
        row_start[i] = s[tid] - v;
        dis[i] = rsqrtf(1.0f + (float)v);  // +1 self loop
        hist[i] = 0;                       // hist doubles as cursor
    }
    if (tid == SCAN_B - 1) bsums[blockIdx.x] = s[SCAN_B - 1];
}

__global__ void scan_bsums_kernel(int* __restrict__ bsums, int nb) {
    __shared__ int s[512];
    int tid = threadIdx.x;
    int v = (tid < nb) ? bsums[tid] : 0;
    s[tid] = v;
    __syncthreads();
    for (int off = 1; off < 512; off <<= 1) {
        int add = (tid >= off) ? s[tid - off] : 0;
        __syncthreads();
        s[tid] += add;
        __syncthreads();
    }
    if (tid < nb) bsums[tid] = s[tid] - v;
    if (tid == 511) bsums[nb] = s[511];
}

__global__ void scan_add_kernel(int* __restrict__ row_start, const int* __restrict__ bsums,
                                int N, int nb) {
    int i = blockIdx.x * blockDim.x + threadIdx.x;
    if (i < N) row_start[i] += bsums[i >> 8];
    else if (i == N) row_start[N] = bsums[nb];
}

// ---------------- CSR fill, packed (src, weight) int2 ----------------
__global__ void fill_csr_kernel(const int* __restrict__ src, const int* __restrict__ dst,
                                const int* __restrict__ row_start, int* __restrict__ cursor,
                                const float* __restrict__ dis,
                                int2* __restrict__ csr, int E) {
    int e = blockIdx.x * blockDim.x + threadIdx.x;
    if (e < E) {
        int d = dst[e];
        int s = src[e];
        int pos = atomicAdd(&cursor[d], 1);
        int o = row_start[d] + pos;
        csr[o] = make_int2(s, __float_as_int(dis[s] * dis[d]));
    }
}

// ---------------- pure agg64 (fp16 rows, 8 rows per gather instr) -> fp16 agg + rowsum ----------------
// lane (q,l): q=j>>3 edge slot (8), l=j&7 feature block (float4 = 8 halfs)
__global__ __launch_bounds__(256, 5)
void agg64_kernel(const __half* __restrict__ mean16,
                  const int* __restrict__ row_start,
                  const int2* __restrict__ csr,
                  const float* __restrict__ dis,
                  __half* __restrict__ agg16,
                  float* __restrict__ rowsum, int N) {
    int t = threadIdx.x;
    int w = t >> 6, j = t & 63;
    int q = j >> 3, l = j & 7;
    int node = blockIdx.x * 4 + w;
    if (node >= N) return;
    int beg = row_start[node];
    int end = row_start[node + 1];
    float d = dis[node];
    const float4* m4 = (const float4*)mean16;  // row = 8 float4 (64 halfs)
    float acc[8];
    {
        float4 raw = m4[(size_t)node * 8 + l];
        const __half2* hp = (const __half2*)&raw;
        float d2 = d * d * ((q == 0) ? 1.f : 0.f);
        float2 f0 = __half22float2(hp[0]);
        float2 f1 = __half22float2(hp[1]);
        float2 f2 = __half22float2(hp[2]);
        float2 f3 = __half22float2(hp[3]);
        acc[0] = f0.x * d2; acc[1] = f0.y * d2; acc[2] = f1.x * d2; acc[3] = f1.y * d2;
        acc[4] = f2.x * d2; acc[5] = f2.y * d2; acc[6] = f3.x * d2; acc[7] = f3.y * d2;
    }
    float rs = 0.f;
    for (int k = beg; k < end; k += 32) {  // 4 gathers x 8 rows = 32 edges/iter
        int2 e[4];
        float4 v[4];
#pragma unroll
        for (int m = 0; m < 4; m++) {
            int kk = k + 8 * m + q;
            e[m] = (kk < end) ? csr[kk] : make_int2(0, 0);
        }
#pragma unroll
        for (int m = 0; m < 4; m++) v[m] = m4[(size_t)e[m].x * 8 + l];
#pragma unroll
        for (int m = 0; m < 4; m++) {
            float wm = __int_as_float(e[m].y);
            const __half2* hp = (const __half2*)&v[m];
            float2 f0 = __half22float2(hp[0]);
            float2 f1 = __half22float2(hp[1]);
            float2 f2 = __half22float2(hp[2]);
            float2 f3 = __half22float2(hp[3]);
            acc[0] += f0.x * wm; acc[1] += f0.y * wm;
            acc[2] += f1.x * wm; acc[3] += f1.y * wm;
            acc[4] += f2.x * wm; acc[5] += f2.y * wm;
            acc[6] += f3.x * wm; acc[7] += f3.y * wm;
            rs += wm;
        }
    }
    // fold across q (lane bits 3,4,5)
#pragma unroll
    for (int i = 0; i < 8; i++) {
        acc[i] += __shfl_xor(acc[i], 8);
        acc[i] += __shfl_xor(acc[i], 16);
        acc[i] += __shfl_xor(acc[i], 32);
    }
    rs += __shfl_xor(rs, 8);
    rs += __shfl_xor(rs, 16);
    rs += __shfl_xor(rs, 32);
    if (q == 0) {  // write fp16 row: features l*8 .. l*8+7
        __half2 p0 = __floats2half2_rn(acc[0], acc[1]);
        __half2 p1 = __floats2half2_rn(acc[2], acc[3]);
        __half2 p2 = __floats2half2_rn(acc[4], acc[5]);
        __half2 p3 = __floats2half2_rn(acc[6], acc[7]);
        float4 packed;
        ((__half2*)&packed)[0] = p0;
        ((__half2*)&packed)[1] = p1;
        ((__half2*)&packed)[2] = p2;
        ((__half2*)&packed)[3] = p3;
        ((float4*)agg16)[(size_t)node * 8 + l] = packed;
    }
    if (j == 0) rowsum[node] = rs + d * d;
}

// ---------------- MFMA dense chain: h2 = relu(agg@Wf + rowsum*bf + b1) @ W2 -> fp16 ----------------
// 256 threads = 4 waves, 32 nodes/block. Wave w: rows rh=w&1 (16 nodes), col base (w>>1)*64.
// mfma_f32_16x16x32_f16 layouts (m89-verified): A: m=lane&15,k=quad*8+j; B: n=lane&15,k=quad*8+j;
// D: col n=lane&15, row m=quad*4+reg.
#define NB 32
__global__ void dense_chain_mfma_kernel(const __half* __restrict__ agg16,
                                        const float* __restrict__ rowsum,
                                        const _Float16* __restrict__ Wf16t,  // [128][64] n-major
                                        const float* __restrict__ bf,
                                        const float* __restrict__ b1,
                                        const _Float16* __restrict__ W2t,    // [128][128] n-major
                                        __half* __restrict__ h2, int N) {
    __shared__ _Float16 sx1[32][136];  // +8 pad: row stride 272B (16B-aligned, bank-spread)
    __shared__ float srs[32];
    int t = threadIdx.x;
    int wv = t >> 6, lane = t & 63;
    int nb0 = blockIdx.x * NB;
    int rh = wv & 1;              // node half
    int ncb = (wv >> 1) * 64;     // col base
    int m16 = lane & 15;
    int q = lane >> 4;

    if (t < 32) srs[t] = (nb0 + t < N) ? rowsum[nb0 + t] : 0.f;

    // ---- GEMM1: [16x64] @ [64x128-half] ----
    f32x4 c0 = {}, c1 = {}, c2 = {}, c3 = {};
    int arow = nb0 + rh * 16 + m16;
    bool rowok = (arow < N);
    const _Float16* ag = (const _Float16*)agg16;
#pragma unroll
    for (int ks = 0; ks < 2; ks++) {
        int k0 = ks * 32 + q * 8;
        f16x8 afrag = {};
        if (rowok) afrag = *(const f16x8*)(ag + (size_t)arow * 64 + k0);
        f16x8 b0 = *(const f16x8*)(Wf16t + (size_t)(ncb + 0 * 16 + m16) * 64 + k0);
        f16x8 b1f = *(const f16x8*)(Wf16t + (size_t)(ncb + 1 * 16 + m16) * 64 + k0);
        f16x8 b2f = *(const f16x8*)(Wf16t + (size_t)(ncb + 2 * 16 + m16) * 64 + k0);
        f16x8 b3f = *(const f16x8*)(Wf16t + (size_t)(ncb + 3 * 16 + m16) * 64 + k0);
        c0 = __builtin_amdgcn_mfma_f32_16x16x32_f16(afrag, b0, c0, 0, 0, 0);
        c1 = __builtin_amdgcn_mfma_f32_16x16x32_f16(afrag, b1f, c1, 0, 0, 0);
        c2 = __builtin_amdgcn_mfma_f32_16x16x32_f16(afrag, b2f, c2, 0, 0, 0);
        c3 = __builtin_amdgcn_mfma_f32_16x16x32_f16(afrag, b3f, c3, 0, 0, 0);
    }
    __syncthreads();  // srs ready; sx1 about to be written
    // epilogue: z = c + rowsum*bf + b1, relu, -> sx1 fp16
    {
        f32x4 cc[4] = {c0, c1, c2, c3};
#pragma unroll
        for (int nt = 0; nt < 4; nt++) {
            int ncol = ncb + nt * 16 + m16;
            float bfj = bf[ncol], b1j = b1[ncol];
#pragma unroll
            for (int r = 0; r < 4; r++) {
                int mrow = q * 4 + r;
                float z = cc[nt][r] + srs[rh * 16 + mrow] * bfj + b1j;
                sx1[rh * 16 + mrow][ncol] = (_Float16)fmaxf(z, 0.f);
            }
        }
    }
    __syncthreads();

    // ---- GEMM2: [16x128] @ [128x128-half] ----
    f32x4 d0 = {}, d1 = {}, d2 = {}, d3 = {};
#pragma unroll
    for (int ks = 0; ks < 4; ks++) {
        int k0 = ks * 32 + q * 8;
        f16x8 afrag = *(const f16x8*)(&sx1[rh * 16 + m16][k0]);
        f16x8 b0 = *(const f16x8*)(W2t + (size_t)(ncb + 0 * 16 + m16) * 128 + k0);
        f16x8 b1f = *(const f16x8*)(W2t + (size_t)(ncb + 1 * 16 + m16) * 128 + k0);
        f16x8 b2f = *(const f16x8*)(W2t + (size_t)(ncb + 2 * 16 + m16) * 128 + k0);
        f16x8 b3f = *(const f16x8*)(W2t + (size_t)(ncb + 3 * 16 + m16) * 128 + k0);
        d0 = __builtin_amdgcn_mfma_f32_16x16x32_f16(afrag, b0, d0, 0, 0, 0);
        d1 = __builtin_amdgcn_mfma_f32_16x16x32_f16(afrag, b1f, d1, 0, 0, 0);
        d2 = __builtin_amdgcn_mfma_f32_16x16x32_f16(afrag, b2f, d2, 0, 0, 0);
        d3 = __builtin_amdgcn_mfma_f32_16x16x32_f16(afrag, b3f, d3, 0, 0, 0);
    }
    // write h2 fp16 (no bias/relu here; b2 applied in agg128)
    {
        f32x4 dd[4] = {d0, d1, d2, d3};
#pragma unroll
        for (int nt = 0; nt < 4; nt++) {
            int ncol = ncb + nt * 16 + m16;
#pragma unroll
            for (int r = 0; r < 4; r++) {
                int node = nb0 + rh * 16 + q * 4 + r;
                if (node < N) h2[(size_t)node * 128 + ncol] = __float2half(dd[nt][r]);
            }
        }
    }
}

// ---------------- layer 2: agg128 (fp16 rows, 4 rows per gather) + b2 + ReLU -> fp32 ----------------
__global__ __launch_bounds__(256, 5)
void gcn_agg128_kernel(const __half* __restrict__ hsrc,
                       const int* __restrict__ row_start,
                       const int2* __restrict__ csr,
                       const float* __restrict__ dis,
                       const float* __restrict__ b2,
                       float* __restrict__ outx, int N) {
    int t = threadIdx.x;
    int w = t >> 6, j = t & 63;
    int q = j >> 4, l = j & 15;
    int node = blockIdx.x * 4 + w;
    if (node >= N) return;
    const float4* h4 = (const float4*)hsrc;  // row = 16 float4 (128 halfs)
    int beg = row_start[node];
    int end = row_start[node + 1];
    float d = dis[node];
    float acc[8];
    {
        float4 raw = h4[(size_t)node * 16 + l];
        const __half2* hp = (const __half2*)&raw;
        float d2 = d * d * ((q == 0) ? 1.f : 0.f);
        float2 f0 = __half22float2(hp[0]);
        float2 f1 = __half22float2(hp[1]);
        float2 f2 = __half22float2(hp[2]);
        float2 f3 = __half22float2(hp[3]);
        acc[0] = f0.x * d2; acc[1] = f0.y * d2; acc[2] = f1.x * d2; acc[3] = f1.y * d2;
        acc[4] = f2.x * d2; acc[5] = f2.y * d2; acc[6] = f3.x * d2; acc[7] = f3.y * d2;
    }
    for (int k = beg; k < end; k += 32) {  // 8 gathers x 4 rows = 32 edges/iter
        int2 e[8];
        float4 v[8];
#pragma unroll
        for (int m = 0; m < 8; m++) {
            int kk = k + 4 * m + q;
            e[m] = (kk < end) ? csr[kk] : make_int2(0, 0);
        }
#pragma unroll
        for (int m = 0; m < 8; m++) v[m] = h4[(size_t)e[m].x * 16 + l];
#pragma unroll
        for (int m = 0; m < 8; m++) {
            float wm = __int_as_float(e[m].y);
            const __half2* hp = (const __half2*)&v[m];
            float2 f0 = __half22float2(hp[0]);
            float2 f1 = __half22float2(hp[1]);
            float2 f2 = __half22float2(hp[2]);
            float2 f3 = __half22float2(hp[3]);
            acc[0] += f0.x * wm; acc[1] += f0.y * wm;
            acc[2] += f1.x * wm; acc[3] += f1.y * wm;
            acc[4] += f2.x * wm; acc[5] += f2.y * wm;
            acc[6] += f3.x * wm; acc[7] += f3.y * wm;
        }
    }
#pragma unroll
    for (int i = 0; i < 8; i++) {
        acc[i] += __shfl_xor(acc[i], 16);
        acc[i] += __shfl_xor(acc[i], 32);
    }
    if (q == 0) {
        const float4* b4 = (const float4*)b2;
        float4 ba = b4[l * 2], bb = b4[l * 2 + 1];
        float4 o0, o1;
        o0.x = fmaxf(acc[0] + ba.x, 0.f);
        o0.y = fmaxf(acc[1] + ba.y, 0.f);
        o0.z = fmaxf(acc[2] + ba.z, 0.f);
        o0.w = fmaxf(acc[3] + ba.w, 0.f);
        o1.x = fmaxf(acc[4] + bb.x, 0.f);
        o1.y = fmaxf(acc[5] + bb.y, 0.f);
        o1.z = fmaxf(acc[6] + bb.z, 0.f);
        o1.w = fmaxf(acc[7] + bb.w, 0.f);
        ((float4*)outx)[(size_t)node * 32 + l * 2] = o0;
        ((float4*)outx)[(size_t)node * 32 + l * 2 + 1] = o1;
    }
}

// ---------------- atomic-free global mean pool (batch sorted), float2 ----------------
__device__ __forceinline__ int lower_bound_i(const int* __restrict__ a, int n, int val) {
    int lo = 0, hi = n;
    while (lo < hi) {
        int mid = (lo + hi) >> 1;
        if (a[mid] < val) lo = mid + 1; else hi = mid;
    }
    return lo;
}

__global__ void pool_mean_kernel(const float* __restrict__ x,
                                 const int* __restrict__ batch,
                                 float* __restrict__ g, int N) {
    int t = threadIdx.x;
    int w = t >> 6, j = t & 63;
    int gr = blockIdx.x * 4 + w;
    if (gr >= NUM_GRAPHS) return;
    int beg = lower_bound_i(batch, N, gr);
    int end = lower_bound_i(batch, N, gr + 1);
    const float2* x2 = (const float2*)x;
    float2 acc = make_float2(0.f, 0.f);
    int i = beg;
    for (; i + 4 <= end; i += 4) {
        float2 a0 = x2[(size_t)i * 64 + j];
        float2 a1 = x2[(size_t)(i + 1) * 64 + j];
        float2 a2 = x2[(size_t)(i + 2) * 64 + j];
        float2 a3 = x2[(size_t)(i + 3) * 64 + j];
        acc.x += a0.x + a1.x + a2.x + a3.x;
        acc.y += a0.y + a1.y + a2.y + a3.y;
    }
    for (; i < end; i++) {
        float2 a = x2[(size_t)i * 64 + j];
        acc.x += a.x; acc.y += a.y;
    }
    float inv = 1.0f / fmaxf((float)(end - beg), 1.0f);
    ((float2*)g)[(size_t)gr * 64 + j] = make_float2(acc.x * inv, acc.y * inv);
}

// ---------------- head ----------------
__global__ void head_kernel(const float* __restrict__ g,
                            const float* __restrict__ Wfc,
                            const float* __restrict__ bfc,
                            const float* __restrict__ Wout,
                            const float* __restrict__ bout,
                            float* __restrict__ out) {
    int gr = blockIdx.x;
    int j = threadIdx.x;  // 0..127
    __shared__ float sg[128];
    __shared__ float sred[128];
    sg[j] = g[gr * 128 + j];
    __syncthreads();
    float acc = bfc[j];
#pragma unroll
    for (int k = 0; k < 128; k++) acc += sg[k] * Wfc[k * 128 + j];
    float f = fmaxf(acc, 0.f);
    sred[j] = f * Wout[j];
    __syncthreads();
    if (j < 64) sred[j] += sred[j + 64];
    __syncthreads();
    if (j < 64) {
        float v = sred[j];
#pragma unroll
        for (int off = 32; off > 0; off >>= 1) v += __shfl_down(v, off);
        if (j == 0) {
            float logit = v + bout[0];
            out[gr] = 1.0f / (1.0f + expf(-logit));
            out[NUM_GRAPHS + gr] = logit;
        }
    }
}

extern "C" void kernel_launch(void* const* d_in, const int* in_sizes, int n_in,
                              void* d_out, int out_size, void* d_ws, size_t ws_size,
                              hipStream_t stream) {
    const int* tok   = (const int*)d_in[0];
    const int* eidx  = (const int*)d_in[1];
    const int* batch = (const int*)d_in[2];
    const float* emb = (const float*)d_in[3];
    const float* Wp  = (const float*)d_in[4];
    const float* bp  = (const float*)d_in[5];
    const float* W1  = (const float*)d_in[6];
    const float* b1  = (const float*)d_in[7];
    const float* W2  = (const float*)d_in[8];
    const float* b2  = (const float*)d_in[9];
    const float* Wfc = (const float*)d_in[10];
    const float* bfc = (const float*)d_in[11];
    const float* Wout= (const float*)d_in[12];
    const float* bout= (const float*)d_in[13];
    float* out = (float*)d_out;

    const int N = in_sizes[2];
    const int E = in_sizes[1] / 2;
    const int* src = eidx;
    const int* dst = eidx + E;
    const int nb_scan = (N + SCAN_B - 1) / SCAN_B;
    const int Np = (N + 3) & ~3;

    // workspace layout (float units)
    float* ws = (float*)d_ws;
    float* dis     = ws;                            // Np
    __half* mean16 = (__half*)(dis + Np);           // Np*64 halfs = Np*32 floats
    __half* agg16  = (__half*)(dis + Np + (size_t)Np * 32);  // Np*64 halfs = Np*32 floats
    float* rowsum  = dis + Np + (size_t)Np * 64;    // Np
    __half* h2buf  = (__half*)(rowsum + Np);        // Np*128 halfs = Np*64 floats
    float* xfin    = rowsum + Np + (size_t)Np * 64; // Np*128
    float* g       = xfin + (size_t)Np * 128;       // 1024*128
    _Float16* Wf16t = (_Float16*)(g + NUM_GRAPHS * 128);  // 128*64 halfs = 4096 floats
    _Float16* W2t   = (_Float16*)(g + NUM_GRAPHS * 128 + 4096);  // 128*128 halfs = 8192 floats
    float* bf      = g + NUM_GRAPHS * 128 + 4096 + 8192;  // 128
    int* row_start = (int*)(bf + 128);              // Np+4
    int* hist      = row_start + Np + 4;            // Np (doubles as cursor)
    int* bsums     = hist + Np;                     // 1028 (pad for csr 16B alignment)
    int2* csr      = (int2*)(bsums + 1028);         // E int2

    // --- fused/transposed fp16 weights (tiny) ---
    fuse_wt_kernel<<<128, 64, 0, stream>>>(Wp, W1, Wf16t);
    fuse_b_kernel<<<1, 128, 0, stream>>>(bp, W1, bf);
    convert_w2t_kernel<<<128, 128, 0, stream>>>(W2, W2t);

    // --- degree histogram ---
    hipMemsetAsync(hist, 0, N * sizeof(int), stream);
    hist_kernel<<<(E + 255) / 256, 256, 0, stream>>>(dst, hist, E);

    // --- scan (fused: dis + cursor reset) ---
    scan_local_kernel<<<nb_scan, SCAN_B, 0, stream>>>(hist, row_start, bsums, dis, N);
    scan_bsums_kernel<<<1, 512, 0, stream>>>(bsums, nb_scan);
    scan_add_kernel<<<(N + 1 + 255) / 256, 256, 0, stream>>>(row_start, bsums, N, nb_scan);

    // --- CSR fill ---
    fill_csr_kernel<<<(E + 255) / 256, 256, 0, stream>>>(src, dst, row_start, hist, dis,
                                                         csr, E);

    // --- embed + token-mean -> mean16 (fp16) ---
    embed_mean_kernel<<<(N + 3) / 4, 256, 0, stream>>>(tok, emb, mean16, N);

    // --- pure 64-dim aggregate -> agg16 (fp16) + rowsum ---
    agg64_kernel<<<(N + 3) / 4, 256, 0, stream>>>(mean16, row_start, csr, dis,
                                                  agg16, rowsum, N);

    // --- MFMA dense chain: h2 = relu(agg@Wf + rowsum*bf + b1) @ W2 -> fp16 ---
    dense_chain_mfma_kernel<<<(N + NB - 1) / NB, 256, 0, stream>>>(agg16, rowsum, Wf16t,
                                                                   bf, b1, W2t, h2buf, N);

    // --- layer 2 aggregate + b2 + ReLU -> xfin (fp32) ---
    gcn_agg128_kernel<<<(N + 3) / 4, 256, 0, stream>>>(h2buf, row_start, csr, dis, b2,
                                                       xfin, N);

    // --- global mean pool + head ---
    pool_mean_kernel<<<(NUM_GRAPHS + 3) / 4, 256, 0, stream>>>(xfin, batch, g, N);
    head_kernel<<<NUM_GRAPHS, 128, 0, stream>>>(g, Wfc, bfc, Wout, bout, out);
}

// Round 12
// 382.324 us; speedup vs baseline: 2.4377x; 1.2001x over previous
//
#include <hip/hip_runtime.h>
#include <hip/hip_bf16.h>
#include <hip/hip_fp16.h>
#include <math.h>

#define N_TOKENS 16
#define TOK_DIM 64
#define NODE_DIM 64
#define HID 128
#define FC 128
#define NUM_GRAPHS 1024
#define NBUCK_MAX 512
#define CHUNK 8192

typedef _Float16 f16x8 __attribute__((ext_vector_type(8)));
typedef float f32x4 __attribute__((ext_vector_type(4)));

// ---------------- fused fp16 transposed weights: Wf16t[n][k] = (Wp@W1)^T, bf = bp@W1 ----------------
__global__ void fuse_wt_kernel(const float* __restrict__ Wp, const float* __restrict__ W1,
                               _Float16* __restrict__ Wf16t) {
    int n = blockIdx.x;      // 0..127
    int m = threadIdx.x;     // 0..63
    float acc = 0.f;
#pragma unroll
    for (int d = 0; d < 64; d++) acc += Wp[m * 64 + d] * W1[d * 128 + n];
    Wf16t[(size_t)n * 64 + m] = (_Float16)acc;
}

__global__ void fuse_b_kernel(const float* __restrict__ bp, const float* __restrict__ W1,
                              float* __restrict__ bf) {
    int j = threadIdx.x;     // 0..127
    float acc = 0.f;
#pragma unroll
    for (int d = 0; d < 64; d++) acc += bp[d] * W1[d * 128 + j];
    bf[j] = acc;
}

__global__ void convert_w2t_kernel(const float* __restrict__ W2, _Float16* __restrict__ W2t) {
    int n = blockIdx.x;      // 0..127
    int k = threadIdx.x;     // 0..127
    W2t[(size_t)n * 128 + k] = (_Float16)W2[(size_t)k * 128 + n];
}

// ---------------- embed + token-mean -> mean16[N,64] (fp16 storage) ----------------
__global__ void embed_mean_kernel(const int* __restrict__ tok,
                                  const float* __restrict__ emb,
                                  __half* __restrict__ mean16, int N) {
    int t = threadIdx.x;
    int w = t >> 6, j = t & 63;
    int q = j >> 4, l = j & 15;
    int i = blockIdx.x * 4 + w;
    if (i >= N) return;
    const float4* e4 = (const float4*)emb;  // row = 16 float4
    int t0 = tok[i * 16 + q];
    int t1 = tok[i * 16 + q + 4];
    int t2 = tok[i * 16 + q + 8];
    int t3 = tok[i * 16 + q + 12];
    float4 v0 = e4[(size_t)t0 * 16 + l];
    float4 v1 = e4[(size_t)t1 * 16 + l];
    float4 v2 = e4[(size_t)t2 * 16 + l];
    float4 v3 = e4[(size_t)t3 * 16 + l];
    float4 s;
    s.x = v0.x + v1.x + v2.x + v3.x;
    s.y = v0.y + v1.y + v2.y + v3.y;
    s.z = v0.z + v1.z + v2.z + v3.z;
    s.w = v0.w + v1.w + v2.w + v3.w;
    s.x += __shfl_xor(s.x, 16); s.y += __shfl_xor(s.y, 16);
    s.z += __shfl_xor(s.z, 16); s.w += __shfl_xor(s.w, 16);
    s.x += __shfl_xor(s.x, 32); s.y += __shfl_xor(s.y, 32);
    s.z += __shfl_xor(s.z, 32); s.w += __shfl_xor(s.w, 32);
    if (q == 0) {
        const float inv = 1.0f / 16.0f;
        __half2 h0 = __floats2half2_rn(s.x * inv, s.y * inv);
        __half2 h1 = __floats2half2_rn(s.z * inv, s.w * inv);
        float2 packed;
        ((__half2*)&packed)[0] = h0;
        ((__half2*)&packed)[1] = h1;
        ((float2*)mean16)[(size_t)i * 16 + l] = packed;
    }
}

// ---------------- bucketed counting sort: dst buckets of 256 nodes ----------------
__global__ void bucket_hist_kernel(const int* __restrict__ dst, int* __restrict__ bucket_cnt,
                                   int E, int nbuck) {
    __shared__ int h[NBUCK_MAX];
    int t = threadIdx.x;
    for (int i = t; i < nbuck; i += 256) h[i] = 0;
    __syncthreads();
    int base = blockIdx.x * CHUNK;
    for (int i = t; i < CHUNK; i += 256) {
        int e = base + i;
        if (e < E) atomicAdd(&h[dst[e] >> 8], 1);
    }
    __syncthreads();
    for (int i = t; i < nbuck; i += 256)
        if (h[i]) atomicAdd(&bucket_cnt[i], h[i]);
}

// 1 block, 512 threads; nbuck <= 512
__global__ void bucket_scan_kernel(const int* __restrict__ bucket_cnt,
                                   int* __restrict__ bucket_base,
                                   int* __restrict__ bucket_cursor, int nbuck) {
    __shared__ int s[512];
    int tid = threadIdx.x;
    int v = (tid < nbuck) ? bucket_cnt[tid] : 0;
    s[tid] = v;
    __syncthreads();
    for (int off = 1; off < 512; off <<= 1) {
        int add = (tid >= off) ? s[tid - off] : 0;
        __syncthreads();
        s[tid] += add;
        __syncthreads();
    }
    if (tid < nbuck) { bucket_base[tid] = s[tid] - v; bucket_cursor[tid] = 0; }
    if (tid == 511) bucket_base[nbuck] = s[511];
}

// scatter edges into bucket-contiguous staging, packed val = src | (dst&255)<<17
__global__ void binscatter_kernel(const int* __restrict__ src, const int* __restrict__ dst,
                                  const int* __restrict__ bucket_base,
                                  int* __restrict__ bucket_cursor,
                                  int* __restrict__ staged, int E, int nbuck) {
    __shared__ int h[NBUCK_MAX];
    __shared__ int gw[NBUCK_MAX];
    int t = threadIdx.x;
    for (int i = t; i < nbuck; i += 256) h[i] = 0;
    __syncthreads();
    int base = blockIdx.x * CHUNK;
    for (int i = t; i < CHUNK; i += 256) {
        int e = base + i;
        if (e < E) atomicAdd(&h[dst[e] >> 8], 1);
    }
    __syncthreads();
    for (int i = t; i < nbuck; i += 256) {
        int c = h[i];
        gw[i] = (c > 0) ? bucket_base[i] + atomicAdd(&bucket_cursor[i], c) : 0;
        h[i] = 0;  // reuse as local rank cursor
    }
    __syncthreads();
    for (int i = t; i < CHUNK; i += 256) {
        int e = base + i;
        if (e < E) {
            int d = dst[e], s = src[e];
            int b = d >> 8;
            int r = atomicAdd(&h[b], 1);
            staged[gw[b] + r] = s | ((d & 255) << 17);
        }
    }
}

// per bucket: per-node degree -> row_start + dis (coalesced writes)
__global__ void bucket_count_kernel(const int* __restrict__ staged,
                                    const int* __restrict__ bucket_base,
                                    int* __restrict__ row_start, float* __restrict__ dis,
                                    int N, int E) {
    __shared__ int cnt[256];
    __shared__ int sc[256];
    int b = blockIdx.x;
    int t = threadIdx.x;
    cnt[t] = 0;
    __syncthreads();
    int rb0 = bucket_base[b], rb1 = bucket_base[b + 1];
    for (int i = rb0 + t; i < rb1; i += 256) atomicAdd(&cnt[staged[i] >> 17], 1);
    __syncthreads();
    int v = cnt[t];
    sc[t] = v;
    __syncthreads();
    for (int off = 1; off < 256; off <<= 1) {
        int add = (t >= off) ? sc[t - off] : 0;
        __syncthreads();
        sc[t] += add;
        __syncthreads();
    }
    int node = b * 256 + t;
    if (node < N) {
        row_start[node] = rb0 + sc[t] - v;  // exclusive
        dis[node] = rsqrtf(1.0f + (float)v);  // +1 self loop
    }
    if (b == 0 && t == 0) row_start[N] = E;
}

// per bucket: final CSR (src, w) — block-local contiguous region
__global__ void csr_write_kernel(const int* __restrict__ staged,
                                 const int* __restrict__ bucket_base,
                                 const int* __restrict__ row_start,
                                 const float* __restrict__ dis,
                                 int2* __restrict__ csr, int N) {
    __shared__ int cur[256];
    __shared__ float dl[256];
    int b = blockIdx.x;
    int t = threadIdx.x;
    int node = b * 256 + t;
    cur[t] = (node < N) ? row_start[node] : 0;
    dl[t] = (node < N) ? dis[node] : 0.f;
    __syncthreads();
    int rb0 = bucket_base[b], rb1 = bucket_base[b + 1];
    for (int i = rb0 + t; i < rb1; i += 256) {
        int v = staged[i];
        int s = v & 131071;
        int dloc = v >> 17;
        int pos = atomicAdd(&cur[dloc], 1);
        csr[pos] = make_int2(s, __float_as_int(dis[s] * dl[dloc]));
    }
}

// ---------------- pure agg64 (fp16 rows, 8 rows per gather instr) -> fp16 agg + rowsum ----------------
__global__ __launch_bounds__(256, 5)
void agg64_kernel(const __half* __restrict__ mean16,
                  const int* __restrict__ row_start,
                  const int2* __restrict__ csr,
                  const float* __restrict__ dis,
                  __half* __restrict__ agg16,
                  float* __restrict__ rowsum, int N) {
    int t = threadIdx.x;
    int w = t >> 6, j = t & 63;
    int q = j >> 3, l = j & 7;
    int node = blockIdx.x * 4 + w;
    if (node >= N) return;
    int beg = row_start[node];
    int end = row_start[node + 1];
    float d = dis[node];
    const float4* m4 = (const float4*)mean16;  // row = 8 float4 (64 halfs)
    float acc[8];
    {
        float4 raw = m4[(size_t)node * 8 + l];
        const __half2* hp = (const __half2*)&raw;
        float d2 = d * d * ((q == 0) ? 1.f : 0.f);
        float2 f0 = __half22float2(hp[0]);
        float2 f1 = __half22float2(hp[1]);
        float2 f2 = __half22float2(hp[2]);
        float2 f3 = __half22float2(hp[3]);
        acc[0] = f0.x * d2; acc[1] = f0.y * d2; acc[2] = f1.x * d2; acc[3] = f1.y * d2;
        acc[4] = f2.x * d2; acc[5] = f2.y * d2; acc[6] = f3.x * d2; acc[7] = f3.y * d2;
    }
    float rs = 0.f;
    for (int k = beg; k < end; k += 32) {  // 4 gathers x 8 rows = 32 edges/iter
        int2 e[4];
        float4 v[4];
#pragma unroll
        for (int m = 0; m < 4; m++) {
            int kk = k + 8 * m + q;
            e[m] = (kk < end) ? csr[kk] : make_int2(0, 0);
        }
#pragma unroll
        for (int m = 0; m < 4; m++) v[m] = m4[(size_t)e[m].x * 8 + l];
#pragma unroll
        for (int m = 0; m < 4; m++) {
            float wm = __int_as_float(e[m].y);
            const __half2* hp = (const __half2*)&v[m];
            float2 f0 = __half22float2(hp[0]);
            float2 f1 = __half22float2(hp[1]);
            float2 f2 = __half22float2(hp[2]);
            float2 f3 = __half22float2(hp[3]);
            acc[0] += f0.x * wm; acc[1] += f0.y * wm;
            acc[2] += f1.x * wm; acc[3] += f1.y * wm;
            acc[4] += f2.x * wm; acc[5] += f2.y * wm;
            acc[6] += f3.x * wm; acc[7] += f3.y * wm;
            rs += wm;
        }
    }
#pragma unroll
    for (int i = 0; i < 8; i++) {
        acc[i] += __shfl_xor(acc[i], 8);
        acc[i] += __shfl_xor(acc[i], 16);
        acc[i] += __shfl_xor(acc[i], 32);
    }
    rs += __shfl_xor(rs, 8);
    rs += __shfl_xor(rs, 16);
    rs += __shfl_xor(rs, 32);
    if (q == 0) {
        __half2 p0 = __floats2half2_rn(acc[0], acc[1]);
        __half2 p1 = __floats2half2_rn(acc[2], acc[3]);
        __half2 p2 = __floats2half2_rn(acc[4], acc[5]);
        __half2 p3 = __floats2half2_rn(acc[6], acc[7]);
        float4 packed;
        ((__half2*)&packed)[0] = p0;
        ((__half2*)&packed)[1] = p1;
        ((__half2*)&packed)[2] = p2;
        ((__half2*)&packed)[3] = p3;
        ((float4*)agg16)[(size_t)node * 8 + l] = packed;
    }
    if (j == 0) rowsum[node] = rs + d * d;
}

// ---------------- MFMA dense chain: h2 = relu(agg@Wf + rowsum*bf + b1) @ W2 -> fp16 ----------------
#define NB 32
__global__ void dense_chain_mfma_kernel(const __half* __restrict__ agg16,
                                        const float* __restrict__ rowsum,
                                        const _Float16* __restrict__ Wf16t,  // [128][64]
                                        const float* __restrict__ bf,
                                        const float* __restrict__ b1,
                                        const _Float16* __restrict__ W2t,    // [128][128]
                                        __half* __restrict__ h2, int N) {
    __shared__ _Float16 sx1[32][136];
    __shared__ float srs[32];
    int t = threadIdx.x;
    int wv = t >> 6, lane = t & 63;
    int nb0 = blockIdx.x * NB;
    int rh = wv & 1;
    int ncb = (wv >> 1) * 64;
    int m16 = lane & 15;
    int q = lane >> 4;

    if (t < 32) srs[t] = (nb0 + t < N) ? rowsum[nb0 + t] : 0.f;

    f32x4 c0 = {}, c1 = {}, c2 = {}, c3 = {};
    int arow = nb0 + rh * 16 + m16;
    bool rowok = (arow < N);
    const _Float16* ag = (const _Float16*)agg16;
#pragma unroll
    for (int ks = 0; ks < 2; ks++) {
        int k0 = ks * 32 + q * 8;
        f16x8 afrag = {};
        if (rowok) afrag = *(const f16x8*)(ag + (size_t)arow * 64 + k0);
        f16x8 b0 = *(const f16x8*)(Wf16t + (size_t)(ncb + 0 * 16 + m16) * 64 + k0);
        f16x8 b1f = *(const f16x8*)(Wf16t + (size_t)(ncb + 1 * 16 + m16) * 64 + k0);
        f16x8 b2f = *(const f16x8*)(Wf16t + (size_t)(ncb + 2 * 16 + m16) * 64 + k0);
        f16x8 b3f = *(const f16x8*)(Wf16t + (size_t)(ncb + 3 * 16 + m16) * 64 + k0);
        c0 = __builtin_amdgcn_mfma_f32_16x16x32_f16(afrag, b0, c0, 0, 0, 0);
        c1 = __builtin_amdgcn_mfma_f32_16x16x32_f16(afrag, b1f, c1, 0, 0, 0);
        c2 = __builtin_amdgcn_mfma_f32_16x16x32_f16(afrag, b2f, c2, 0, 0, 0);
        c3 = __builtin_amdgcn_mfma_f32_16x16x32_f16(afrag, b3f, c3, 0, 0, 0);
    }
    __syncthreads();
    {
        f32x4 cc[4] = {c0, c1, c2, c3};
#pragma unroll
        for (int nt = 0; nt < 4; nt++) {
            int ncol = ncb + nt * 16 + m16;
            float bfj = bf[ncol], b1j = b1[ncol];
#pragma unroll
            for (int r = 0; r < 4; r++) {
                int mrow = q * 4 + r;
                float z = cc[nt][r] + srs[rh * 16 + mrow] * bfj + b1j;
                sx1[rh * 16 + mrow][ncol] = (_Float16)fmaxf(z, 0.f);
            }
        }
    }
    __syncthreads();

    f32x4 d0 = {}, d1 = {}, d2 = {}, d3 = {};
#pragma unroll
    for (int ks = 0; ks < 4; ks++) {
        int k0 = ks * 32 + q * 8;
        f16x8 afrag = *(const f16x8*)(&sx1[rh * 16 + m16][k0]);
        f16x8 b0 = *(const f16x8*)(W2t + (size_t)(ncb + 0 * 16 + m16) * 128 + k0);
        f16x8 b1f = *(const f16x8*)(W2t + (size_t)(ncb + 1 * 16 + m16) * 128 + k0);
        f16x8 b2f = *(const f16x8*)(W2t + (size_t)(ncb + 2 * 16 + m16) * 128 + k0);
        f16x8 b3f = *(const f16x8*)(W2t + (size_t)(ncb + 3 * 16 + m16) * 128 + k0);
        d0 = __builtin_amdgcn_mfma_f32_16x16x32_f16(afrag, b0, d0, 0, 0, 0);
        d1 = __builtin_amdgcn_mfma_f32_16x16x32_f16(afrag, b1f, d1, 0, 0, 0);
        d2 = __builtin_amdgcn_mfma_f32_16x16x32_f16(afrag, b2f, d2, 0, 0, 0);
        d3 = __builtin_amdgcn_mfma_f32_16x16x32_f16(afrag, b3f, d3, 0, 0, 0);
    }
    {
        f32x4 dd[4] = {d0, d1, d2, d3};
#pragma unroll
        for (int nt = 0; nt < 4; nt++) {
            int ncol = ncb + nt * 16 + m16;
#pragma unroll
            for (int r = 0; r < 4; r++) {
                int node = nb0 + rh * 16 + q * 4 + r;
                if (node < N) h2[(size_t)node * 128 + ncol] = __float2half(dd[nt][r]);
            }
        }
    }
}

// ---------------- layer 2: agg128 (fp16 rows, 4 rows per gather) + b2 + ReLU -> fp32 ----------------
__global__ __launch_bounds__(256, 5)
void gcn_agg128_kernel(const __half* __restrict__ hsrc,
                       const int* __restrict__ row_start,
                       const int2* __restrict__ csr,
                       const float* __restrict__ dis,
                       const float* __restrict__ b2,
                       float* __restrict__ outx, int N) {
    int t = threadIdx.x;
    int w = t >> 6, j = t & 63;
    int q = j >> 4, l = j & 15;
    int node = blockIdx.x * 4 + w;
    if (node >= N) return;
    const float4* h4 = (const float4*)hsrc;  // row = 16 float4 (128 halfs)
    int beg = row_start[node];
    int end = row_start[node + 1];
    float d = dis[node];
    float acc[8];
    {
        float4 raw = h4[(size_t)node * 16 + l];
        const __half2* hp = (const __half2*)&raw;
        float d2 = d * d * ((q == 0) ? 1.f : 0.f);
        float2 f0 = __half22float2(hp[0]);
        float2 f1 = __half22float2(hp[1]);
        float2 f2 = __half22float2(hp[2]);
        float2 f3 = __half22float2(hp[3]);
        acc[0] = f0.x * d2; acc[1] = f0.y * d2; acc[2] = f1.x * d2; acc[3] = f1.y * d2;
        acc[4] = f2.x * d2; acc[5] = f2.y * d2; acc[6] = f3.x * d2; acc[7] = f3.y * d2;
    }
    for (int k = beg; k < end; k += 32) {
        int2 e[8];
        float4 v[8];
#pragma unroll
        for (int m = 0; m < 8; m++) {
            int kk = k + 4 * m + q;
            e[m] = (kk < end) ? csr[kk] : make_int2(0, 0);
        }
#pragma unroll
        for (int m = 0; m < 8; m++) v[m] = h4[(size_t)e[m].x * 16 + l];
#pragma unroll
        for (int m = 0; m < 8; m++) {
            float wm = __int_as_float(e[m].y);
            const __half2* hp = (const __half2*)&v[m];
            float2 f0 = __half22float2(hp[0]);
            float2 f1 = __half22float2(hp[1]);
            float2 f2 = __half22float2(hp[2]);
            float2 f3 = __half22float2(hp[3]);
            acc[0] += f0.x * wm; acc[1] += f0.y * wm;
            acc[2] += f1.x * wm; acc[3] += f1.y * wm;
            acc[4] += f2.x * wm; acc[5] += f2.y * wm;
            acc[6] += f3.x * wm; acc[7] += f3.y * wm;
        }
    }
#pragma unroll
    for (int i = 0; i < 8; i++) {
        acc[i] += __shfl_xor(acc[i], 16);
        acc[i] += __shfl_xor(acc[i], 32);
    }
    if (q == 0) {
        const float4* b4 = (const float4*)b2;
        float4 ba = b4[l * 2], bb = b4[l * 2 + 1];
        float4 o0, o1;
        o0.x = fmaxf(acc[0] + ba.x, 0.f);
        o0.y = fmaxf(acc[1] + ba.y, 0.f);
        o0.z = fmaxf(acc[2] + ba.z, 0.f);
        o0.w = fmaxf(acc[3] + ba.w, 0.f);
        o1.x = fmaxf(acc[4] + bb.x, 0.f);
        o1.y = fmaxf(acc[5] + bb.y, 0.f);
        o1.z = fmaxf(acc[6] + bb.z, 0.f);
        o1.w = fmaxf(acc[7] + bb.w, 0.f);
        ((float4*)outx)[(size_t)node * 32 + l * 2] = o0;
        ((float4*)outx)[(size_t)node * 32 + l * 2 + 1] = o1;
    }
}

// ---------------- atomic-free global mean pool (batch sorted), float2 ----------------
__device__ __forceinline__ int lower_bound_i(const int* __restrict__ a, int n, int val) {
    int lo = 0, hi = n;
    while (lo < hi) {
        int mid = (lo + hi) >> 1;
        if (a[mid] < val) lo = mid + 1; else hi = mid;
    }
    return lo;
}

__global__ void pool_mean_kernel(const float* __restrict__ x,
                                 const int* __restrict__ batch,
                                 float* __restrict__ g, int N) {
    int t = threadIdx.x;
    int w = t >> 6, j = t & 63;
    int gr = blockIdx.x * 4 + w;
    if (gr >= NUM_GRAPHS) return;
    int beg = lower_bound_i(batch, N, gr);
    int end = lower_bound_i(batch, N, gr + 1);
    const float2* x2 = (const float2*)x;
    float2 acc = make_float2(0.f, 0.f);
    int i = beg;
    for (; i + 4 <= end; i += 4) {
        float2 a0 = x2[(size_t)i * 64 + j];
        float2 a1 = x2[(size_t)(i + 1) * 64 + j];
        float2 a2 = x2[(size_t)(i + 2) * 64 + j];
        float2 a3 = x2[(size_t)(i + 3) * 64 + j];
        acc.x += a0.x + a1.x + a2.x + a3.x;
        acc.y += a0.y + a1.y + a2.y + a3.y;
    }
    for (; i < end; i++) {
        float2 a = x2[(size_t)i * 64 + j];
        acc.x += a.x; acc.y += a.y;
    }
    float inv = 1.0f / fmaxf((float)(end - beg), 1.0f);
    ((float2*)g)[(size_t)gr * 64 + j] = make_float2(acc.x * inv, acc.y * inv);
}

// ---------------- head ----------------
__global__ void head_kernel(const float* __restrict__ g,
                            const float* __restrict__ Wfc,
                            const float* __restrict__ bfc,
                            const float* __restrict__ Wout,
                            const float* __restrict__ bout,
                            float* __restrict__ out) {
    int gr = blockIdx.x;
    int j = threadIdx.x;  // 0..127
    __shared__ float sg[128];
    __shared__ float sred[128];
    sg[j] = g[gr * 128 + j];
    __syncthreads();
    float acc = bfc[j];
#pragma unroll
    for (int k = 0; k < 128; k++) acc += sg[k] * Wfc[k * 128 + j];
    float f = fmaxf(acc, 0.f);
    sred[j] = f * Wout[j];
    __syncthreads();
    if (j < 64) sred[j] += sred[j + 64];
    __syncthreads();
    if (j < 64) {
        float v = sred[j];
#pragma unroll
        for (int off = 32; off > 0; off >>= 1) v += __shfl_down(v, off);
        if (j == 0) {
            float logit = v + bout[0];
            out[gr] = 1.0f / (1.0f + expf(-logit));
            out[NUM_GRAPHS + gr] = logit;
        }
    }
}

extern "C" void kernel_launch(void* const* d_in, const int* in_sizes, int n_in,
                              void* d_out, int out_size, void* d_ws, size_t ws_size,
                              hipStream_t stream) {
    const int* tok   = (const int*)d_in[0];
    const int* eidx  = (const int*)d_in[1];
    const int* batch = (const int*)d_in[2];
    const float* emb = (const float*)d_in[3];
    const float* Wp  = (const float*)d_in[4];
    const float* bp  = (const float*)d_in[5];
    const float* W1  = (const float*)d_in[6];
    const float* b1  = (const float*)d_in[7];
    const float* W2  = (const float*)d_in[8];
    const float* b2  = (const float*)d_in[9];
    const float* Wfc = (const float*)d_in[10];
    const float* bfc = (const float*)d_in[11];
    const float* Wout= (const float*)d_in[12];
    const float* bout= (const float*)d_in[13];
    float* out = (float*)d_out;

    const int N = in_sizes[2];
    const int E = in_sizes[1] / 2;
    const int* src = eidx;
    const int* dst = eidx + E;
    const int Np = (N + 3) & ~3;
    const int nbuck = (N + 255) / 256;               // 391 for N=100k
    const int nchunk = (E + CHUNK - 1) / CHUNK;      // 196

    // workspace layout (float units)
    float* ws = (float*)d_ws;
    size_t off = 0;
    float* dis     = ws + off;            off += Np;
    __half* mean16 = (__half*)(ws + off); off += (size_t)Np * 32;
    __half* agg16  = (__half*)(ws + off); off += (size_t)Np * 32;
    float* rowsum  = ws + off;            off += Np;
    __half* h2buf  = (__half*)(ws + off); off += (size_t)Np * 64;
    float* xfin    = ws + off;            off += (size_t)Np * 128;
    float* g       = ws + off;            off += NUM_GRAPHS * 128;
    _Float16* Wf16t = (_Float16*)(ws + off); off += 4096;
    _Float16* W2t   = (_Float16*)(ws + off); off += 8192;
    float* bf      = ws + off;            off += 128;
    int* row_start = (int*)(ws + off);    off += Np + 4;
    int* staged    = (int*)(ws + off);    off += E;
    int* bucket_cnt    = (int*)(ws + off); off += NBUCK_MAX;
    int* bucket_base   = (int*)(ws + off); off += NBUCK_MAX + 8;
    int* bucket_cursor = (int*)(ws + off); off += NBUCK_MAX;
    int2* csr      = (int2*)(ws + off);   // E int2

    // --- fused/transposed fp16 weights (tiny) ---
    fuse_wt_kernel<<<128, 64, 0, stream>>>(Wp, W1, Wf16t);
    fuse_b_kernel<<<1, 128, 0, stream>>>(bp, W1, bf);
    convert_w2t_kernel<<<128, 128, 0, stream>>>(W2, W2t);

    // --- bucketed counting sort -> row_start, dis, csr ---
    hipMemsetAsync(bucket_cnt, 0, nbuck * sizeof(int), stream);
    bucket_hist_kernel<<<nchunk, 256, 0, stream>>>(dst, bucket_cnt, E, nbuck);
    bucket_scan_kernel<<<1, 512, 0, stream>>>(bucket_cnt, bucket_base, bucket_cursor, nbuck);
    binscatter_kernel<<<nchunk, 256, 0, stream>>>(src, dst, bucket_base, bucket_cursor,
                                                  staged, E, nbuck);
    bucket_count_kernel<<<nbuck, 256, 0, stream>>>(staged, bucket_base, row_start, dis, N, E);
    csr_write_kernel<<<nbuck, 256, 0, stream>>>(staged, bucket_base, row_start, dis, csr, N);

    // --- embed + token-mean -> mean16 (fp16) ---
    embed_mean_kernel<<<(N + 3) / 4, 256, 0, stream>>>(tok, emb, mean16, N);

    // --- pure 64-dim aggregate -> agg16 (fp16) + rowsum ---
    agg64_kernel<<<(N + 3) / 4, 256, 0, stream>>>(mean16, row_start, csr, dis,
                                                  agg16, rowsum, N);

    // --- MFMA dense chain: h2 = relu(agg@Wf + rowsum*bf + b1) @ W2 -> fp16 ---
    dense_chain_mfma_kernel<<<(N + NB - 1) / NB, 256, 0, stream>>>(agg16, rowsum, Wf16t,
                                                                   bf, b1, W2t, h2buf, N);

    // --- layer 2 aggregate + b2 + ReLU -> xfin (fp32) ---
    gcn_agg128_kernel<<<(N + 3) / 4, 256, 0, stream>>>(h2buf, row_start, csr, dis, b2,
                                                       xfin, N);

    // --- global mean pool + head ---
    pool_mean_kernel<<<(NUM_GRAPHS + 3) / 4, 256, 0, stream>>>(xfin, batch, g, N);
    head_kernel<<<NUM_GRAPHS, 128, 0, stream>>>(g, Wfc, bfc, Wout, bout, out);
}

// Round 13
// 369.457 us; speedup vs baseline: 2.5226x; 1.0348x over previous
//
#include <hip/hip_runtime.h>
#include <hip/hip_bf16.h>
#include <hip/hip_fp16.h>
#include <math.h>

#define N_TOKENS 16
#define TOK_DIM 64
#define NODE_DIM 64
#define HID 128
#define FC 128
#define NUM_GRAPHS 1024
#define NBUCK_MAX 512
#define CHUNK 8192

typedef _Float16 f16x8 __attribute__((ext_vector_type(8)));
typedef float f32x4 __attribute__((ext_vector_type(4)));

__device__ __forceinline__ __half2 shfl_xor_h2(__half2 v, int mask) {
    int i = *(int*)&v;
    i = __shfl_xor(i, mask);
    return *(__half2*)&i;
}

// ---------------- fused fp16 transposed weights: Wf16t[n][k] = (Wp@W1)^T, bf = bp@W1 ----------------
__global__ void fuse_wt_kernel(const float* __restrict__ Wp, const float* __restrict__ W1,
                               _Float16* __restrict__ Wf16t) {
    int n = blockIdx.x;      // 0..127
    int m = threadIdx.x;     // 0..63
    float acc = 0.f;
#pragma unroll
    for (int d = 0; d < 64; d++) acc += Wp[m * 64 + d] * W1[d * 128 + n];
    Wf16t[(size_t)n * 64 + m] = (_Float16)acc;
}

__global__ void fuse_b_kernel(const float* __restrict__ bp, const float* __restrict__ W1,
                              float* __restrict__ bf) {
    int j = threadIdx.x;     // 0..127
    float acc = 0.f;
#pragma unroll
    for (int d = 0; d < 64; d++) acc += bp[d] * W1[d * 128 + j];
    bf[j] = acc;
}

__global__ void convert_w2t_kernel(const float* __restrict__ W2, _Float16* __restrict__ W2t) {
    int n = blockIdx.x;      // 0..127
    int k = threadIdx.x;     // 0..127
    W2t[(size_t)n * 128 + k] = (_Float16)W2[(size_t)k * 128 + n];
}

// ---------------- embed + token-mean -> mean16[N,64] (fp16 storage) ----------------
__global__ void embed_mean_kernel(const int* __restrict__ tok,
                                  const float* __restrict__ emb,
                                  __half* __restrict__ mean16, int N) {
    int t = threadIdx.x;
    int w = t >> 6, j = t & 63;
    int q = j >> 4, l = j & 15;
    int i = blockIdx.x * 4 + w;
    if (i >= N) return;
    const float4* e4 = (const float4*)emb;  // row = 16 float4
    int t0 = tok[i * 16 + q];
    int t1 = tok[i * 16 + q + 4];
    int t2 = tok[i * 16 + q + 8];
    int t3 = tok[i * 16 + q + 12];
    float4 v0 = e4[(size_t)t0 * 16 + l];
    float4 v1 = e4[(size_t)t1 * 16 + l];
    float4 v2 = e4[(size_t)t2 * 16 + l];
    float4 v3 = e4[(size_t)t3 * 16 + l];
    float4 s;
    s.x = v0.x + v1.x + v2.x + v3.x;
    s.y = v0.y + v1.y + v2.y + v3.y;
    s.z = v0.z + v1.z + v2.z + v3.z;
    s.w = v0.w + v1.w + v2.w + v3.w;
    s.x += __shfl_xor(s.x, 16); s.y += __shfl_xor(s.y, 16);
    s.z += __shfl_xor(s.z, 16); s.w += __shfl_xor(s.w, 16);
    s.x += __shfl_xor(s.x, 32); s.y += __shfl_xor(s.y, 32);
    s.z += __shfl_xor(s.z, 32); s.w += __shfl_xor(s.w, 32);
    if (q == 0) {
        const float inv = 1.0f / 16.0f;
        __half2 h0 = __floats2half2_rn(s.x * inv, s.y * inv);
        __half2 h1 = __floats2half2_rn(s.z * inv, s.w * inv);
        float2 packed;
        ((__half2*)&packed)[0] = h0;
        ((__half2*)&packed)[1] = h1;
        ((float2*)mean16)[(size_t)i * 16 + l] = packed;
    }
}

// ---------------- bucketed counting sort: dst buckets of 256 nodes ----------------
__global__ void bucket_hist_kernel(const int* __restrict__ dst, int* __restrict__ bucket_cnt,
                                   int E, int nbuck) {
    __shared__ int h[NBUCK_MAX];
    int t = threadIdx.x;
    for (int i = t; i < nbuck; i += 256) h[i] = 0;
    __syncthreads();
    int base = blockIdx.x * CHUNK;
    for (int i = t; i < CHUNK; i += 256) {
        int e = base + i;
        if (e < E) atomicAdd(&h[dst[e] >> 8], 1);
    }
    __syncthreads();
    for (int i = t; i < nbuck; i += 256)
        if (h[i]) atomicAdd(&bucket_cnt[i], h[i]);
}

// 1 block, 512 threads; nbuck <= 512
__global__ void bucket_scan_kernel(const int* __restrict__ bucket_cnt,
                                   int* __restrict__ bucket_base,
                                   int* __restrict__ bucket_cursor, int nbuck) {
    __shared__ int s[512];
    int tid = threadIdx.x;
    int v = (tid < nbuck) ? bucket_cnt[tid] : 0;
    s[tid] = v;
    __syncthreads();
    for (int off = 1; off < 512; off <<= 1) {
        int add = (tid >= off) ? s[tid - off] : 0;
        __syncthreads();
        s[tid] += add;
        __syncthreads();
    }
    if (tid < nbuck) { bucket_base[tid] = s[tid] - v; bucket_cursor[tid] = 0; }
    if (tid == 511) bucket_base[nbuck] = s[511];
}

// scatter edges into bucket-contiguous staging, packed val = src | (dst&255)<<17
__global__ void binscatter_kernel(const int* __restrict__ src, const int* __restrict__ dst,
                                  const int* __restrict__ bucket_base,
                                  int* __restrict__ bucket_cursor,
                                  int* __restrict__ staged, int E, int nbuck) {
    __shared__ int h[NBUCK_MAX];
    __shared__ int gw[NBUCK_MAX];
    int t = threadIdx.x;
    for (int i = t; i < nbuck; i += 256) h[i] = 0;
    __syncthreads();
    int base = blockIdx.x * CHUNK;
    for (int i = t; i < CHUNK; i += 256) {
        int e = base + i;
        if (e < E) atomicAdd(&h[dst[e] >> 8], 1);
    }
    __syncthreads();
    for (int i = t; i < nbuck; i += 256) {
        int c = h[i];
        gw[i] = (c > 0) ? bucket_base[i] + atomicAdd(&bucket_cursor[i], c) : 0;
        h[i] = 0;  // reuse as local rank cursor
    }
    __syncthreads();
    for (int i = t; i < CHUNK; i += 256) {
        int e = base + i;
        if (e < E) {
            int d = dst[e], s = src[e];
            int b = d >> 8;
            int r = atomicAdd(&h[b], 1);
            staged[gw[b] + r] = s | ((d & 255) << 17);
        }
    }
}

// per bucket: per-node degree -> row_start + dis (coalesced writes)
__global__ void bucket_count_kernel(const int* __restrict__ staged,
                                    const int* __restrict__ bucket_base,
                                    int* __restrict__ row_start, float* __restrict__ dis,
                                    int N, int E) {
    __shared__ int cnt[256];
    __shared__ int sc[256];
    int b = blockIdx.x;
    int t = threadIdx.x;
    cnt[t] = 0;
    __syncthreads();
    int rb0 = bucket_base[b], rb1 = bucket_base[b + 1];
    for (int i = rb0 + t; i < rb1; i += 256) atomicAdd(&cnt[staged[i] >> 17], 1);
    __syncthreads();
    int v = cnt[t];
    sc[t] = v;
    __syncthreads();
    for (int off = 1; off < 256; off <<= 1) {
        int add = (t >= off) ? sc[t - off] : 0;
        __syncthreads();
        sc[t] += add;
        __syncthreads();
    }
    int node = b * 256 + t;
    if (node < N) {
        row_start[node] = rb0 + sc[t] - v;  // exclusive
        dis[node] = rsqrtf(1.0f + (float)v);  // +1 self loop
    }
    if (b == 0 && t == 0) row_start[N] = E;
}

// per bucket: final CSR (src, half2(w,w)) + rowsum — block-local contiguous region
__global__ void csr_write_kernel(const int* __restrict__ staged,
                                 const int* __restrict__ bucket_base,
                                 const int* __restrict__ row_start,
                                 const float* __restrict__ dis,
                                 int2* __restrict__ csr, float* __restrict__ rowsum, int N) {
    __shared__ int cur[256];
    __shared__ float dl[256];
    __shared__ float wsum[256];
    int b = blockIdx.x;
    int t = threadIdx.x;
    int node = b * 256 + t;
    cur[t] = (node < N) ? row_start[node] : 0;
    dl[t] = (node < N) ? dis[node] : 0.f;
    wsum[t] = 0.f;
    __syncthreads();
    int rb0 = bucket_base[b], rb1 = bucket_base[b + 1];
    for (int i = rb0 + t; i < rb1; i += 256) {
        int v = staged[i];
        int s = v & 131071;
        int dloc = v >> 17;
        float w = dis[s] * dl[dloc];
        int pos = atomicAdd(&cur[dloc], 1);
        __half2 wh = __floats2half2_rn(w, w);
        csr[pos] = make_int2(s, *(int*)&wh);
        atomicAdd(&wsum[dloc], w);
    }
    __syncthreads();
    if (node < N) rowsum[node] = wsum[t] + dl[t] * dl[t];
}

// ---------------- agg64: fp16 packed accumulate, 8 rows per gather -> fp16 agg ----------------
// lane (q,l): q=j>>3 edge slot (8), l=j&7 feature block (float4 = 4 half2)
__global__ __launch_bounds__(256, 5)
void agg64_kernel(const __half* __restrict__ mean16,
                  const int* __restrict__ row_start,
                  const int2* __restrict__ csr,
                  const float* __restrict__ dis,
                  __half* __restrict__ agg16, int N) {
    int t = threadIdx.x;
    int w = t >> 6, j = t & 63;
    int q = j >> 3, l = j & 7;
    int node = blockIdx.x * 4 + w;
    if (node >= N) return;
    int beg = row_start[node];
    int end = row_start[node + 1];
    float d = dis[node];
    const float4* m4 = (const float4*)mean16;  // row = 8 float4 (64 halfs)
    __half2 a0, a1, a2, a3;
    {
        float4 raw = m4[(size_t)node * 8 + l];
        const __half2* hp = (const __half2*)&raw;
        float d2f = d * d * ((q == 0) ? 1.f : 0.f);
        __half2 d2h = __floats2half2_rn(d2f, d2f);
        a0 = __hmul2(hp[0], d2h); a1 = __hmul2(hp[1], d2h);
        a2 = __hmul2(hp[2], d2h); a3 = __hmul2(hp[3], d2h);
    }
    for (int k = beg; k < end; k += 32) {  // 4 gathers x 8 rows = 32 edges/iter
        int2 e[4];
        float4 v[4];
#pragma unroll
        for (int m = 0; m < 4; m++) {
            int kk = k + 8 * m + q;
            e[m] = (kk < end) ? csr[kk] : make_int2(0, 0);  // wh=0 => no-op
        }
#pragma unroll
        for (int m = 0; m < 4; m++) v[m] = m4[(size_t)e[m].x * 8 + l];
#pragma unroll
        for (int m = 0; m < 4; m++) {
            __half2 wh = *(__half2*)&e[m].y;
            const __half2* hp = (const __half2*)&v[m];
            a0 = __hfma2(hp[0], wh, a0);
            a1 = __hfma2(hp[1], wh, a1);
            a2 = __hfma2(hp[2], wh, a2);
            a3 = __hfma2(hp[3], wh, a3);
        }
    }
    // fold across q (lane bits 3,4,5)
#pragma unroll
    for (int mask = 8; mask <= 32; mask <<= 1) {
        a0 = __hadd2(a0, shfl_xor_h2(a0, mask));
        a1 = __hadd2(a1, shfl_xor_h2(a1, mask));
        a2 = __hadd2(a2, shfl_xor_h2(a2, mask));
        a3 = __hadd2(a3, shfl_xor_h2(a3, mask));
    }
    if (q == 0) {
        float4 packed;
        __half2* pp = (__half2*)&packed;
        pp[0] = a0; pp[1] = a1; pp[2] = a2; pp[3] = a3;
        ((float4*)agg16)[(size_t)node * 8 + l] = packed;
    }
}

// ---------------- MFMA dense chain: h2 = relu(agg@Wf + rowsum*bf + b1) @ W2 -> fp16 ----------------
#define NB 32
__global__ void dense_chain_mfma_kernel(const __half* __restrict__ agg16,
                                        const float* __restrict__ rowsum,
                                        const _Float16* __restrict__ Wf16t,  // [128][64]
                                        const float* __restrict__ bf,
                                        const float* __restrict__ b1,
                                        const _Float16* __restrict__ W2t,    // [128][128]
                                        __half* __restrict__ h2, int N) {
    __shared__ _Float16 sx1[32][136];
    __shared__ float srs[32];
    int t = threadIdx.x;
    int wv = t >> 6, lane = t & 63;
    int nb0 = blockIdx.x * NB;
    int rh = wv & 1;
    int ncb = (wv >> 1) * 64;
    int m16 = lane & 15;
    int q = lane >> 4;

    if (t < 32) srs[t] = (nb0 + t < N) ? rowsum[nb0 + t] : 0.f;

    f32x4 c0 = {}, c1 = {}, c2 = {}, c3 = {};
    int arow = nb0 + rh * 16 + m16;
    bool rowok = (arow < N);
    const _Float16* ag = (const _Float16*)agg16;
#pragma unroll
    for (int ks = 0; ks < 2; ks++) {
        int k0 = ks * 32 + q * 8;
        f16x8 afrag = {};
        if (rowok) afrag = *(const f16x8*)(ag + (size_t)arow * 64 + k0);
        f16x8 b0 = *(const f16x8*)(Wf16t + (size_t)(ncb + 0 * 16 + m16) * 64 + k0);
        f16x8 b1f = *(const f16x8*)(Wf16t + (size_t)(ncb + 1 * 16 + m16) * 64 + k0);
        f16x8 b2f = *(const f16x8*)(Wf16t + (size_t)(ncb + 2 * 16 + m16) * 64 + k0);
        f16x8 b3f = *(const f16x8*)(Wf16t + (size_t)(ncb + 3 * 16 + m16) * 64 + k0);
        c0 = __builtin_amdgcn_mfma_f32_16x16x32_f16(afrag, b0, c0, 0, 0, 0);
        c1 = __builtin_amdgcn_mfma_f32_16x16x32_f16(afrag, b1f, c1, 0, 0, 0);
        c2 = __builtin_amdgcn_mfma_f32_16x16x32_f16(afrag, b2f, c2, 0, 0, 0);
        c3 = __builtin_amdgcn_mfma_f32_16x16x32_f16(afrag, b3f, c3, 0, 0, 0);
    }
    __syncthreads();
    {
        f32x4 cc[4] = {c0, c1, c2, c3};
#pragma unroll
        for (int nt = 0; nt < 4; nt++) {
            int ncol = ncb + nt * 16 + m16;
            float bfj = bf[ncol], b1j = b1[ncol];
#pragma unroll
            for (int r = 0; r < 4; r++) {
                int mrow = q * 4 + r;
                float z = cc[nt][r] + srs[rh * 16 + mrow] * bfj + b1j;
                sx1[rh * 16 + mrow][ncol] = (_Float16)fmaxf(z, 0.f);
            }
        }
    }
    __syncthreads();

    f32x4 d0 = {}, d1 = {}, d2 = {}, d3 = {};
#pragma unroll
    for (int ks = 0; ks < 4; ks++) {
        int k0 = ks * 32 + q * 8;
        f16x8 afrag = *(const f16x8*)(&sx1[rh * 16 + m16][k0]);
        f16x8 b0 = *(const f16x8*)(W2t + (size_t)(ncb + 0 * 16 + m16) * 128 + k0);
        f16x8 b1f = *(const f16x8*)(W2t + (size_t)(ncb + 1 * 16 + m16) * 128 + k0);
        f16x8 b2f = *(const f16x8*)(W2t + (size_t)(ncb + 2 * 16 + m16) * 128 + k0);
        f16x8 b3f = *(const f16x8*)(W2t + (size_t)(ncb + 3 * 16 + m16) * 128 + k0);
        d0 = __builtin_amdgcn_mfma_f32_16x16x32_f16(afrag, b0, d0, 0, 0, 0);
        d1 = __builtin_amdgcn_mfma_f32_16x16x32_f16(afrag, b1f, d1, 0, 0, 0);
        d2 = __builtin_amdgcn_mfma_f32_16x16x32_f16(afrag, b2f, d2, 0, 0, 0);
        d3 = __builtin_amdgcn_mfma_f32_16x16x32_f16(afrag, b3f, d3, 0, 0, 0);
    }
    {
        f32x4 dd[4] = {d0, d1, d2, d3};
#pragma unroll
        for (int nt = 0; nt < 4; nt++) {
            int ncol = ncb + nt * 16 + m16;
#pragma unroll
            for (int r = 0; r < 4; r++) {
                int node = nb0 + rh * 16 + q * 4 + r;
                if (node < N) h2[(size_t)node * 128 + ncol] = __float2half(dd[nt][r]);
            }
        }
    }
}

// ---------------- layer 2: agg128 fp16 packed accumulate, 4 rows per gather -> fp16 out ----------------
// lane (q,l): q=j>>4 edge slot (4), l=j&15 feature block (float4 = 4 half2)
__global__ __launch_bounds__(256, 5)
void gcn_agg128_kernel(const __half* __restrict__ hsrc,
                       const int* __restrict__ row_start,
                       const int2* __restrict__ csr,
                       const float* __restrict__ dis,
                       const float* __restrict__ b2,
                       __half* __restrict__ outx, int N) {
    int t = threadIdx.x;
    int w = t >> 6, j = t & 63;
    int q = j >> 4, l = j & 15;
    int node = blockIdx.x * 4 + w;
    if (node >= N) return;
    const float4* h4 = (const float4*)hsrc;  // row = 16 float4 (128 halfs)
    int beg = row_start[node];
    int end = row_start[node + 1];
    float d = dis[node];
    __half2 a0, a1, a2, a3;
    {
        float4 raw = h4[(size_t)node * 16 + l];
        const __half2* hp = (const __half2*)&raw;
        float d2f = d * d * ((q == 0) ? 1.f : 0.f);
        __half2 d2h = __floats2half2_rn(d2f, d2f);
        a0 = __hmul2(hp[0], d2h); a1 = __hmul2(hp[1], d2h);
        a2 = __hmul2(hp[2], d2h); a3 = __hmul2(hp[3], d2h);
    }
    for (int k = beg; k < end; k += 32) {  // 8 gathers x 4 rows = 32 edges/iter
        int2 e[8];
        float4 v[8];
#pragma unroll
        for (int m = 0; m < 8; m++) {
            int kk = k + 4 * m + q;
            e[m] = (kk < end) ? csr[kk] : make_int2(0, 0);
        }
#pragma unroll
        for (int m = 0; m < 8; m++) v[m] = h4[(size_t)e[m].x * 16 + l];
#pragma unroll
        for (int m = 0; m < 8; m++) {
            __half2 wh = *(__half2*)&e[m].y;
            const __half2* hp = (const __half2*)&v[m];
            a0 = __hfma2(hp[0], wh, a0);
            a1 = __hfma2(hp[1], wh, a1);
            a2 = __hfma2(hp[2], wh, a2);
            a3 = __hfma2(hp[3], wh, a3);
        }
    }
    // fold across q (lane bits 4,5)
#pragma unroll
    for (int mask = 16; mask <= 32; mask <<= 1) {
        a0 = __hadd2(a0, shfl_xor_h2(a0, mask));
        a1 = __hadd2(a1, shfl_xor_h2(a1, mask));
        a2 = __hadd2(a2, shfl_xor_h2(a2, mask));
        a3 = __hadd2(a3, shfl_xor_h2(a3, mask));
    }
    if (q == 0) {
        // fp32 epilogue: + b2, relu, pack fp16
        float2 f0 = __half22float2(a0), f1 = __half22float2(a1);
        float2 f2 = __half22float2(a2), f3 = __half22float2(a3);
        const float4* b4 = (const float4*)b2;
        float4 ba = b4[l * 2], bb = b4[l * 2 + 1];
        __half2 o0 = __floats2half2_rn(fmaxf(f0.x + ba.x, 0.f), fmaxf(f0.y + ba.y, 0.f));
        __half2 o1 = __floats2half2_rn(fmaxf(f1.x + ba.z, 0.f), fmaxf(f1.y + ba.w, 0.f));
        __half2 o2 = __floats2half2_rn(fmaxf(f2.x + bb.x, 0.f), fmaxf(f2.y + bb.y, 0.f));
        __half2 o3 = __floats2half2_rn(fmaxf(f3.x + bb.z, 0.f), fmaxf(f3.y + bb.w, 0.f));
        float4 packed;
        __half2* pp = (__half2*)&packed;
        pp[0] = o0; pp[1] = o1; pp[2] = o2; pp[3] = o3;
        ((float4*)outx)[(size_t)node * 16 + l] = packed;
    }
}

// ---------------- atomic-free global mean pool (batch sorted), fp16 in / fp32 out ----------------
__device__ __forceinline__ int lower_bound_i(const int* __restrict__ a, int n, int val) {
    int lo = 0, hi = n;
    while (lo < hi) {
        int mid = (lo + hi) >> 1;
        if (a[mid] < val) lo = mid + 1; else hi = mid;
    }
    return lo;
}

__global__ void pool_mean_kernel(const __half* __restrict__ x,
                                 const int* __restrict__ batch,
                                 float* __restrict__ g, int N) {
    int t = threadIdx.x;
    int w = t >> 6, j = t & 63;
    int gr = blockIdx.x * 4 + w;
    if (gr >= NUM_GRAPHS) return;
    int beg = lower_bound_i(batch, N, gr);
    int end = lower_bound_i(batch, N, gr + 1);
    const __half2* x2 = (const __half2*)x;  // row stride 64 half2
    float2 acc = make_float2(0.f, 0.f);
    int i = beg;
    for (; i + 4 <= end; i += 4) {
        float2 a0 = __half22float2(x2[(size_t)i * 64 + j]);
        float2 a1 = __half22float2(x2[(size_t)(i + 1) * 64 + j]);
        float2 a2 = __half22float2(x2[(size_t)(i + 2) * 64 + j]);
        float2 a3 = __half22float2(x2[(size_t)(i + 3) * 64 + j]);
        acc.x += a0.x + a1.x + a2.x + a3.x;
        acc.y += a0.y + a1.y + a2.y + a3.y;
    }
    for (; i < end; i++) {
        float2 a = __half22float2(x2[(size_t)i * 64 + j]);
        acc.x += a.x; acc.y += a.y;
    }
    float inv = 1.0f / fmaxf((float)(end - beg), 1.0f);
    ((float2*)g)[(size_t)gr * 64 + j] = make_float2(acc.x * inv, acc.y * inv);
}

// ---------------- head ----------------
__global__ void head_kernel(const float* __restrict__ g,
                            const float* __restrict__ Wfc,
                            const float* __restrict__ bfc,
                            const float* __restrict__ Wout,
                            const float* __restrict__ bout,
                            float* __restrict__ out) {
    int gr = blockIdx.x;
    int j = threadIdx.x;  // 0..127
    __shared__ float sg[128];
    __shared__ float sred[128];
    sg[j] = g[gr * 128 + j];
    __syncthreads();
    float acc = bfc[j];
#pragma unroll
    for (int k = 0; k < 128; k++) acc += sg[k] * Wfc[k * 128 + j];
    float f = fmaxf(acc, 0.f);
    sred[j] = f * Wout[j];
    __syncthreads();
    if (j < 64) sred[j] += sred[j + 64];
    __syncthreads();
    if (j < 64) {
        float v = sred[j];
#pragma unroll
        for (int off = 32; off > 0; off >>= 1) v += __shfl_down(v, off);
        if (j == 0) {
            float logit = v + bout[0];
            out[gr] = 1.0f / (1.0f + expf(-logit));
            out[NUM_GRAPHS + gr] = logit;
        }
    }
}

extern "C" void kernel_launch(void* const* d_in, const int* in_sizes, int n_in,
                              void* d_out, int out_size, void* d_ws, size_t ws_size,
                              hipStream_t stream) {
    const int* tok   = (const int*)d_in[0];
    const int* eidx  = (const int*)d_in[1];
    const int* batch = (const int*)d_in[2];
    const float* emb = (const float*)d_in[3];
    const float* Wp  = (const float*)d_in[4];
    const float* bp  = (const float*)d_in[5];
    const float* W1  = (const float*)d_in[6];
    const float* b1  = (const float*)d_in[7];
    const float* W2  = (const float*)d_in[8];
    const float* b2  = (const float*)d_in[9];
    const float* Wfc = (const float*)d_in[10];
    const float* bfc = (const float*)d_in[11];
    const float* Wout= (const float*)d_in[12];
    const float* bout= (const float*)d_in[13];
    float* out = (float*)d_out;

    const int N = in_sizes[2];
    const int E = in_sizes[1] / 2;
    const int* src = eidx;
    const int* dst = eidx + E;
    const int Np = (N + 3) & ~3;
    const int nbuck = (N + 255) / 256;               // 391 for N=100k
    const int nchunk = (E + CHUNK - 1) / CHUNK;      // 196

    // workspace layout (float units)
    float* ws = (float*)d_ws;
    size_t off = 0;
    float* dis     = ws + off;            off += Np;
    __half* mean16 = (__half*)(ws + off); off += (size_t)Np * 32;
    __half* agg16  = (__half*)(ws + off); off += (size_t)Np * 32;
    float* rowsum  = ws + off;            off += Np;
    __half* h2buf  = (__half*)(ws + off); off += (size_t)Np * 64;
    __half* xfin16 = (__half*)(ws + off); off += (size_t)Np * 64;
    float* g       = ws + off;            off += NUM_GRAPHS * 128;
    _Float16* Wf16t = (_Float16*)(ws + off); off += 4096;
    _Float16* W2t   = (_Float16*)(ws + off); off += 8192;
    float* bf      = ws + off;            off += 128;
    int* row_start = (int*)(ws + off);    off += Np + 4;
    int* staged    = (int*)(ws + off);    off += E;
    int* bucket_cnt    = (int*)(ws + off); off += NBUCK_MAX;
    int* bucket_base   = (int*)(ws + off); off += NBUCK_MAX + 8;
    int* bucket_cursor = (int*)(ws + off); off += NBUCK_MAX;
    int2* csr      = (int2*)(ws + off);   // E int2

    // --- fused/transposed fp16 weights (tiny) ---
    fuse_wt_kernel<<<128, 64, 0, stream>>>(Wp, W1, Wf16t);
    fuse_b_kernel<<<1, 128, 0, stream>>>(bp, W1, bf);
    convert_w2t_kernel<<<128, 128, 0, stream>>>(W2, W2t);

    // --- bucketed counting sort -> row_start, dis, csr(+rowsum) ---
    hipMemsetAsync(bucket_cnt, 0, nbuck * sizeof(int), stream);
    bucket_hist_kernel<<<nchunk, 256, 0, stream>>>(dst, bucket_cnt, E, nbuck);
    bucket_scan_kernel<<<1, 512, 0, stream>>>(bucket_cnt, bucket_base, bucket_cursor, nbuck);
    binscatter_kernel<<<nchunk, 256, 0, stream>>>(src, dst, bucket_base, bucket_cursor,
                                                  staged, E, nbuck);
    bucket_count_kernel<<<nbuck, 256, 0, stream>>>(staged, bucket_base, row_start, dis, N, E);
    csr_write_kernel<<<nbuck, 256, 0, stream>>>(staged, bucket_base, row_start, dis,
                                                csr, rowsum, N);

    // --- embed + token-mean -> mean16 (fp16) ---
    embed_mean_kernel<<<(N + 3) / 4, 256, 0, stream>>>(tok, emb, mean16, N);

    // --- 64-dim aggregate (fp16 packed) -> agg16 ---
    agg64_kernel<<<(N + 3) / 4, 256, 0, stream>>>(mean16, row_start, csr, dis, agg16, N);

    // --- MFMA dense chain: h2 = relu(agg@Wf + rowsum*bf + b1) @ W2 -> fp16 ---
    dense_chain_mfma_kernel<<<(N + NB - 1) / NB, 256, 0, stream>>>(agg16, rowsum, Wf16t,
                                                                   bf, b1, W2t, h2buf, N);

    // --- layer 2 aggregate (fp16 packed) + b2 + ReLU -> xfin16 ---
    gcn_agg128_kernel<<<(N + 3) / 4, 256, 0, stream>>>(h2buf, row_start, csr, dis, b2,
                                                       xfin16, N);

    // --- global mean pool + head ---
    pool_mean_kernel<<<(NUM_GRAPHS + 3) / 4, 256, 0, stream>>>(xfin16, batch, g, N);
    head_kernel<<<NUM_GRAPHS, 128, 0, stream>>>(g, Wfc, bfc, Wout, bout, out);
}

// Round 14
// 360.057 us; speedup vs baseline: 2.5885x; 1.0261x over previous
//
#include <hip/hip_runtime.h>
#include <hip/hip_bf16.h>
#include <hip/hip_fp16.h>
#include <math.h>

#define N_TOKENS 16
#define TOK_DIM 64
#define NODE_DIM 64
#define HID 128
#define FC 128
#define NUM_GRAPHS 1024
#define NBUCK_MAX 512
#define CHUNK 8192

typedef _Float16 f16x8 __attribute__((ext_vector_type(8)));
typedef float f32x4 __attribute__((ext_vector_type(4)));

__device__ __forceinline__ __half2 shfl_xor_h2(__half2 v, int mask) {
    int i = *(int*)&v;
    i = __shfl_xor(i, mask);
    return *(__half2*)&i;
}

// ---------------- fused weight prep: Wf16t = (Wp@W1)^T fp16, W2t = W2^T fp16, bf = bp@W1 ----------------
// 128 blocks (n) x 128 threads
__global__ void prep_weights_kernel(const float* __restrict__ Wp, const float* __restrict__ W1,
                                    const float* __restrict__ W2, const float* __restrict__ bp,
                                    _Float16* __restrict__ Wf16t, _Float16* __restrict__ W2t,
                                    float* __restrict__ bf) {
    int n = blockIdx.x;   // 0..127
    int t = threadIdx.x;  // 0..127
    if (t < 64) {
        float acc = 0.f;
#pragma unroll
        for (int d = 0; d < 64; d++) acc += Wp[t * 64 + d] * W1[d * 128 + n];
        Wf16t[(size_t)n * 64 + t] = (_Float16)acc;
    } else {
        int d = t - 64;  // lane of wave 1
        float v = bp[d] * W1[d * 128 + n];
#pragma unroll
        for (int off = 32; off > 0; off >>= 1) v += __shfl_down(v, off);
        if (d == 0) bf[n] = v;
    }
    W2t[(size_t)n * 128 + t] = (_Float16)W2[(size_t)t * 128 + n];
}

// ---------------- embed + token-mean -> mean16[N,64] (fp16 storage) ----------------
__global__ void embed_mean_kernel(const int* __restrict__ tok,
                                  const float* __restrict__ emb,
                                  __half* __restrict__ mean16, int N) {
    int t = threadIdx.x;
    int w = t >> 6, j = t & 63;
    int q = j >> 4, l = j & 15;
    int i = blockIdx.x * 4 + w;
    if (i >= N) return;
    const float4* e4 = (const float4*)emb;  // row = 16 float4
    int t0 = tok[i * 16 + q];
    int t1 = tok[i * 16 + q + 4];
    int t2 = tok[i * 16 + q + 8];
    int t3 = tok[i * 16 + q + 12];
    float4 v0 = e4[(size_t)t0 * 16 + l];
    float4 v1 = e4[(size_t)t1 * 16 + l];
    float4 v2 = e4[(size_t)t2 * 16 + l];
    float4 v3 = e4[(size_t)t3 * 16 + l];
    float4 s;
    s.x = v0.x + v1.x + v2.x + v3.x;
    s.y = v0.y + v1.y + v2.y + v3.y;
    s.z = v0.z + v1.z + v2.z + v3.z;
    s.w = v0.w + v1.w + v2.w + v3.w;
    s.x += __shfl_xor(s.x, 16); s.y += __shfl_xor(s.y, 16);
    s.z += __shfl_xor(s.z, 16); s.w += __shfl_xor(s.w, 16);
    s.x += __shfl_xor(s.x, 32); s.y += __shfl_xor(s.y, 32);
    s.z += __shfl_xor(s.z, 32); s.w += __shfl_xor(s.w, 32);
    if (q == 0) {
        const float inv = 1.0f / 16.0f;
        __half2 h0 = __floats2half2_rn(s.x * inv, s.y * inv);
        __half2 h1 = __floats2half2_rn(s.z * inv, s.w * inv);
        float2 packed;
        ((__half2*)&packed)[0] = h0;
        ((__half2*)&packed)[1] = h1;
        ((float2*)mean16)[(size_t)i * 16 + l] = packed;
    }
}

// ---------------- bucketed counting sort: dst buckets of 256 nodes ----------------
__global__ void bucket_hist_kernel(const int* __restrict__ dst, int* __restrict__ bucket_cnt,
                                   int E, int nbuck) {
    __shared__ int h[NBUCK_MAX];
    int t = threadIdx.x;
    for (int i = t; i < nbuck; i += 256) h[i] = 0;
    __syncthreads();
    int base = blockIdx.x * CHUNK;
    for (int i = t; i < CHUNK; i += 256) {
        int e = base + i;
        if (e < E) atomicAdd(&h[dst[e] >> 8], 1);
    }
    __syncthreads();
    for (int i = t; i < nbuck; i += 256)
        if (h[i]) atomicAdd(&bucket_cnt[i], h[i]);
}

// 1 block, 512 threads; nbuck <= 512
__global__ void bucket_scan_kernel(const int* __restrict__ bucket_cnt,
                                   int* __restrict__ bucket_base,
                                   int* __restrict__ bucket_cursor, int nbuck) {
    __shared__ int s[512];
    int tid = threadIdx.x;
    int v = (tid < nbuck) ? bucket_cnt[tid] : 0;
    s[tid] = v;
    __syncthreads();
    for (int off = 1; off < 512; off <<= 1) {
        int add = (tid >= off) ? s[tid - off] : 0;
        __syncthreads();
        s[tid] += add;
        __syncthreads();
    }
    if (tid < nbuck) { bucket_base[tid] = s[tid] - v; bucket_cursor[tid] = 0; }
    if (tid == 511) bucket_base[nbuck] = s[511];
}

// scatter edges into bucket-contiguous staging, packed val = src | (dst&255)<<17
__global__ void binscatter_kernel(const int* __restrict__ src, const int* __restrict__ dst,
                                  const int* __restrict__ bucket_base,
                                  int* __restrict__ bucket_cursor,
                                  int* __restrict__ staged, int E, int nbuck) {
    __shared__ int h[NBUCK_MAX];
    __shared__ int gw[NBUCK_MAX];
    int t = threadIdx.x;
    for (int i = t; i < nbuck; i += 256) h[i] = 0;
    __syncthreads();
    int base = blockIdx.x * CHUNK;
    for (int i = t; i < CHUNK; i += 256) {
        int e = base + i;
        if (e < E) atomicAdd(&h[dst[e] >> 8], 1);
    }
    __syncthreads();
    for (int i = t; i < nbuck; i += 256) {
        int c = h[i];
        gw[i] = (c > 0) ? bucket_base[i] + atomicAdd(&bucket_cursor[i], c) : 0;
        h[i] = 0;  // reuse as local rank cursor
    }
    __syncthreads();
    for (int i = t; i < CHUNK; i += 256) {
        int e = base + i;
        if (e < E) {
            int d = dst[e], s = src[e];
            int b = d >> 8;
            int r = atomicAdd(&h[b], 1);
            staged[gw[b] + r] = s | ((d & 255) << 17);
        }
    }
}

// per bucket: per-node degree -> row_start + dis (coalesced writes)
__global__ void bucket_count_kernel(const int* __restrict__ staged,
                                    const int* __restrict__ bucket_base,
                                    int* __restrict__ row_start, float* __restrict__ dis,
                                    int N, int E) {
    __shared__ int cnt[256];
    __shared__ int sc[256];
    int b = blockIdx.x;
    int t = threadIdx.x;
    cnt[t] = 0;
    __syncthreads();
    int rb0 = bucket_base[b], rb1 = bucket_base[b + 1];
    for (int i = rb0 + t; i < rb1; i += 256) atomicAdd(&cnt[staged[i] >> 17], 1);
    __syncthreads();
    int v = cnt[t];
    sc[t] = v;
    __syncthreads();
    for (int off = 1; off < 256; off <<= 1) {
        int add = (t >= off) ? sc[t - off] : 0;
        __syncthreads();
        sc[t] += add;
        __syncthreads();
    }
    int node = b * 256 + t;
    if (node < N) {
        row_start[node] = rb0 + sc[t] - v;  // exclusive
        dis[node] = rsqrtf(1.0f + (float)v);  // +1 self loop
    }
    if (b == 0 && t == 0) row_start[N] = E;
}

// per bucket: final CSR (src, half2(w,w)) + rowsum — block-local contiguous region
__global__ void csr_write_kernel(const int* __restrict__ staged,
                                 const int* __restrict__ bucket_base,
                                 const int* __restrict__ row_start,
                                 const float* __restrict__ dis,
                                 int2* __restrict__ csr, float* __restrict__ rowsum, int N) {
    __shared__ int cur[256];
    __shared__ float dl[256];
    __shared__ float wsum[256];
    int b = blockIdx.x;
    int t = threadIdx.x;
    int node = b * 256 + t;
    cur[t] = (node < N) ? row_start[node] : 0;
    dl[t] = (node < N) ? dis[node] : 0.f;
    wsum[t] = 0.f;
    __syncthreads();
    int rb0 = bucket_base[b], rb1 = bucket_base[b + 1];
    for (int i = rb0 + t; i < rb1; i += 256) {
        int v = staged[i];
        int s = v & 131071;
        int dloc = v >> 17;
        float w = dis[s] * dl[dloc];
        int pos = atomicAdd(&cur[dloc], 1);
        __half2 wh = __floats2half2_rn(w, w);
        csr[pos] = make_int2(s, *(int*)&wh);
        atomicAdd(&wsum[dloc], w);
    }
    __syncthreads();
    if (node < N) rowsum[node] = wsum[t] + dl[t] * dl[t];
}

// ---------------- agg64: fp16 packed accumulate, 8 rows per gather -> fp16 agg ----------------
// lane (q,l): q=j>>3 edge slot (8), l=j&7 feature block (float4 = 4 half2)
__global__ __launch_bounds__(256, 8)
void agg64_kernel(const __half* __restrict__ mean16,
                  const int* __restrict__ row_start,
                  const int2* __restrict__ csr,
                  const float* __restrict__ dis,
                  __half* __restrict__ agg16, int N) {
    int t = threadIdx.x;
    int w = t >> 6, j = t & 63;
    int q = j >> 3, l = j & 7;
    int node = blockIdx.x * 4 + w;
    if (node >= N) return;
    int beg = row_start[node];
    int end = row_start[node + 1];
    float d = dis[node];
    const float4* m4 = (const float4*)mean16;  // row = 8 float4 (64 halfs)
    __half2 a0, a1, a2, a3;
    {
        float4 raw = m4[(size_t)node * 8 + l];
        const __half2* hp = (const __half2*)&raw;
        float d2f = d * d * ((q == 0) ? 1.f : 0.f);
        __half2 d2h = __floats2half2_rn(d2f, d2f);
        a0 = __hmul2(hp[0], d2h); a1 = __hmul2(hp[1], d2h);
        a2 = __hmul2(hp[2], d2h); a3 = __hmul2(hp[3], d2h);
    }
    int k = beg;
    int kfull = beg + ((end - beg) & ~31);
    for (; k < kfull; k += 32) {  // unguarded: 4 batches x 8 slots
        int2 e[4];
        float4 v[4];
#pragma unroll
        for (int m = 0; m < 4; m++) e[m] = csr[k + 8 * m + q];
#pragma unroll
        for (int m = 0; m < 4; m++) v[m] = m4[(size_t)e[m].x * 8 + l];
#pragma unroll
        for (int m = 0; m < 4; m++) {
            __half2 wh = *(__half2*)&e[m].y;
            const __half2* hp = (const __half2*)&v[m];
            a0 = __hfma2(hp[0], wh, a0);
            a1 = __hfma2(hp[1], wh, a1);
            a2 = __hfma2(hp[2], wh, a2);
            a3 = __hfma2(hp[3], wh, a3);
        }
    }
    for (; k < end; k += 16) {  // guarded tail: 2 batches x 8 slots
        int2 e[2];
        float4 v[2];
#pragma unroll
        for (int m = 0; m < 2; m++) {
            int kk = k + 8 * m + q;
            e[m] = (kk < end) ? csr[kk] : make_int2(0, 0);  // wh=0 => no-op
        }
#pragma unroll
        for (int m = 0; m < 2; m++) v[m] = m4[(size_t)e[m].x * 8 + l];
#pragma unroll
        for (int m = 0; m < 2; m++) {
            __half2 wh = *(__half2*)&e[m].y;
            const __half2* hp = (const __half2*)&v[m];
            a0 = __hfma2(hp[0], wh, a0);
            a1 = __hfma2(hp[1], wh, a1);
            a2 = __hfma2(hp[2], wh, a2);
            a3 = __hfma2(hp[3], wh, a3);
        }
    }
    // fold across q (lane bits 3,4,5)
#pragma unroll
    for (int mask = 8; mask <= 32; mask <<= 1) {
        a0 = __hadd2(a0, shfl_xor_h2(a0, mask));
        a1 = __hadd2(a1, shfl_xor_h2(a1, mask));
        a2 = __hadd2(a2, shfl_xor_h2(a2, mask));
        a3 = __hadd2(a3, shfl_xor_h2(a3, mask));
    }
    if (q == 0) {
        float4 packed;
        __half2* pp = (__half2*)&packed;
        pp[0] = a0; pp[1] = a1; pp[2] = a2; pp[3] = a3;
        ((float4*)agg16)[(size_t)node * 8 + l] = packed;
    }
}

// ---------------- MFMA dense chain: h2 = relu(agg@Wf + rowsum*bf + b1) @ W2 -> fp16 ----------------
#define NB 32
__global__ void dense_chain_mfma_kernel(const __half* __restrict__ agg16,
                                        const float* __restrict__ rowsum,
                                        const _Float16* __restrict__ Wf16t,  // [128][64]
                                        const float* __restrict__ bf,
                                        const float* __restrict__ b1,
                                        const _Float16* __restrict__ W2t,    // [128][128]
                                        __half* __restrict__ h2, int N) {
    __shared__ _Float16 sx1[32][136];
    __shared__ float srs[32];
    int t = threadIdx.x;
    int wv = t >> 6, lane = t & 63;
    int nb0 = blockIdx.x * NB;
    int rh = wv & 1;
    int ncb = (wv >> 1) * 64;
    int m16 = lane & 15;
    int q = lane >> 4;

    if (t < 32) srs[t] = (nb0 + t < N) ? rowsum[nb0 + t] : 0.f;

    f32x4 c0 = {}, c1 = {}, c2 = {}, c3 = {};
    int arow = nb0 + rh * 16 + m16;
    bool rowok = (arow < N);
    const _Float16* ag = (const _Float16*)agg16;
#pragma unroll
    for (int ks = 0; ks < 2; ks++) {
        int k0 = ks * 32 + q * 8;
        f16x8 afrag = {};
        if (rowok) afrag = *(const f16x8*)(ag + (size_t)arow * 64 + k0);
        f16x8 b0 = *(const f16x8*)(Wf16t + (size_t)(ncb + 0 * 16 + m16) * 64 + k0);
        f16x8 b1f = *(const f16x8*)(Wf16t + (size_t)(ncb + 1 * 16 + m16) * 64 + k0);
        f16x8 b2f = *(const f16x8*)(Wf16t + (size_t)(ncb + 2 * 16 + m16) * 64 + k0);
        f16x8 b3f = *(const f16x8*)(Wf16t + (size_t)(ncb + 3 * 16 + m16) * 64 + k0);
        c0 = __builtin_amdgcn_mfma_f32_16x16x32_f16(afrag, b0, c0, 0, 0, 0);
        c1 = __builtin_amdgcn_mfma_f32_16x16x32_f16(afrag, b1f, c1, 0, 0, 0);
        c2 = __builtin_amdgcn_mfma_f32_16x16x32_f16(afrag, b2f, c2, 0, 0, 0);
        c3 = __builtin_amdgcn_mfma_f32_16x16x32_f16(afrag, b3f, c3, 0, 0, 0);
    }
    __syncthreads();
    {
        f32x4 cc[4] = {c0, c1, c2, c3};
#pragma unroll
        for (int nt = 0; nt < 4; nt++) {
            int ncol = ncb + nt * 16 + m16;
            float bfj = bf[ncol], b1j = b1[ncol];
#pragma unroll
            for (int r = 0; r < 4; r++) {
                int mrow = q * 4 + r;
                float z = cc[nt][r] + srs[rh * 16 + mrow] * bfj + b1j;
                sx1[rh * 16 + mrow][ncol] = (_Float16)fmaxf(z, 0.f);
            }
        }
    }
    __syncthreads();

    f32x4 d0 = {}, d1 = {}, d2 = {}, d3 = {};
#pragma unroll
    for (int ks = 0; ks < 4; ks++) {
        int k0 = ks * 32 + q * 8;
        f16x8 afrag = *(const f16x8*)(&sx1[rh * 16 + m16][k0]);
        f16x8 b0 = *(const f16x8*)(W2t + (size_t)(ncb + 0 * 16 + m16) * 128 + k0);
        f16x8 b1f = *(const f16x8*)(W2t + (size_t)(ncb + 1 * 16 + m16) * 128 + k0);
        f16x8 b2f = *(const f16x8*)(W2t + (size_t)(ncb + 2 * 16 + m16) * 128 + k0);
        f16x8 b3f = *(const f16x8*)(W2t + (size_t)(ncb + 3 * 16 + m16) * 128 + k0);
        d0 = __builtin_amdgcn_mfma_f32_16x16x32_f16(afrag, b0, d0, 0, 0, 0);
        d1 = __builtin_amdgcn_mfma_f32_16x16x32_f16(afrag, b1f, d1, 0, 0, 0);
        d2 = __builtin_amdgcn_mfma_f32_16x16x32_f16(afrag, b2f, d2, 0, 0, 0);
        d3 = __builtin_amdgcn_mfma_f32_16x16x32_f16(afrag, b3f, d3, 0, 0, 0);
    }
    {
        f32x4 dd[4] = {d0, d1, d2, d3};
#pragma unroll
        for (int nt = 0; nt < 4; nt++) {
            int ncol = ncb + nt * 16 + m16;
#pragma unroll
            for (int r = 0; r < 4; r++) {
                int node = nb0 + rh * 16 + q * 4 + r;
                if (node < N) h2[(size_t)node * 128 + ncol] = __float2half(dd[nt][r]);
            }
        }
    }
}

// ---------------- layer 2: agg128 fp16 packed accumulate, 4 rows per gather -> fp16 out ----------------
// lane (q,l): q=j>>4 edge slot (4), l=j&15 feature block (float4 = 4 half2)
__global__ __launch_bounds__(256, 8)
void gcn_agg128_kernel(const __half* __restrict__ hsrc,
                       const int* __restrict__ row_start,
                       const int2* __restrict__ csr,
                       const float* __restrict__ dis,
                       const float* __restrict__ b2,
                       __half* __restrict__ outx, int N) {
    int t = threadIdx.x;
    int w = t >> 6, j = t & 63;
    int q = j >> 4, l = j & 15;
    int node = blockIdx.x * 4 + w;
    if (node >= N) return;
    const float4* h4 = (const float4*)hsrc;  // row = 16 float4 (128 halfs)
    int beg = row_start[node];
    int end = row_start[node + 1];
    float d = dis[node];
    __half2 a0, a1, a2, a3;
    {
        float4 raw = h4[(size_t)node * 16 + l];
        const __half2* hp = (const __half2*)&raw;
        float d2f = d * d * ((q == 0) ? 1.f : 0.f);
        __half2 d2h = __floats2half2_rn(d2f, d2f);
        a0 = __hmul2(hp[0], d2h); a1 = __hmul2(hp[1], d2h);
        a2 = __hmul2(hp[2], d2h); a3 = __hmul2(hp[3], d2h);
    }
    int k = beg;
    int kfull = beg + ((end - beg) & ~31);
    for (; k < kfull; k += 32) {  // unguarded: 8 batches x 4 slots
        int2 e[8];
        float4 v[8];
#pragma unroll
        for (int m = 0; m < 8; m++) e[m] = csr[k + 4 * m + q];
#pragma unroll
        for (int m = 0; m < 8; m++) v[m] = h4[(size_t)e[m].x * 16 + l];
#pragma unroll
        for (int m = 0; m < 8; m++) {
            __half2 wh = *(__half2*)&e[m].y;
            const __half2* hp = (const __half2*)&v[m];
            a0 = __hfma2(hp[0], wh, a0);
            a1 = __hfma2(hp[1], wh, a1);
            a2 = __hfma2(hp[2], wh, a2);
            a3 = __hfma2(hp[3], wh, a3);
        }
    }
    for (; k < end; k += 16) {  // guarded tail: 4 batches x 4 slots
        int2 e[4];
        float4 v[4];
#pragma unroll
        for (int m = 0; m < 4; m++) {
            int kk = k + 4 * m + q;
            e[m] = (kk < end) ? csr[kk] : make_int2(0, 0);
        }
#pragma unroll
        for (int m = 0; m < 4; m++) v[m] = h4[(size_t)e[m].x * 16 + l];
#pragma unroll
        for (int m = 0; m < 4; m++) {
            __half2 wh = *(__half2*)&e[m].y;
            const __half2* hp = (const __half2*)&v[m];
            a0 = __hfma2(hp[0], wh, a0);
            a1 = __hfma2(hp[1], wh, a1);
            a2 = __hfma2(hp[2], wh, a2);
            a3 = __hfma2(hp[3], wh, a3);
        }
    }
    // fold across q (lane bits 4,5)
#pragma unroll
    for (int mask = 16; mask <= 32; mask <<= 1) {
        a0 = __hadd2(a0, shfl_xor_h2(a0, mask));
        a1 = __hadd2(a1, shfl_xor_h2(a1, mask));
        a2 = __hadd2(a2, shfl_xor_h2(a2, mask));
        a3 = __hadd2(a3, shfl_xor_h2(a3, mask));
    }
    if (q == 0) {
        // fp32 epilogue: + b2, relu, pack fp16
        float2 f0 = __half22float2(a0), f1 = __half22float2(a1);
        float2 f2 = __half22float2(a2), f3 = __half22float2(a3);
        const float4* b4 = (const float4*)b2;
        float4 ba = b4[l * 2], bb = b4[l * 2 + 1];
        __half2 o0 = __floats2half2_rn(fmaxf(f0.x + ba.x, 0.f), fmaxf(f0.y + ba.y, 0.f));
        __half2 o1 = __floats2half2_rn(fmaxf(f1.x + ba.z, 0.f), fmaxf(f1.y + ba.w, 0.f));
        __half2 o2 = __floats2half2_rn(fmaxf(f2.x + bb.x, 0.f), fmaxf(f2.y + bb.y, 0.f));
        __half2 o3 = __floats2half2_rn(fmaxf(f3.x + bb.z, 0.f), fmaxf(f3.y + bb.w, 0.f));
        float4 packed;
        __half2* pp = (__half2*)&packed;
        pp[0] = o0; pp[1] = o1; pp[2] = o2; pp[3] = o3;
        ((float4*)outx)[(size_t)node * 16 + l] = packed;
    }
}

// ---------------- fused pool + head: one block (128 threads) per graph ----------------
__device__ __forceinline__ int lower_bound_i(const int* __restrict__ a, int n, int val) {
    int lo = 0, hi = n;
    while (lo < hi) {
        int mid = (lo + hi) >> 1;
        if (a[mid] < val) lo = mid + 1; else hi = mid;
    }
    return lo;
}

__global__ void pool_head_kernel(const __half* __restrict__ x,
                                 const int* __restrict__ batch,
                                 const float* __restrict__ Wfc,
                                 const float* __restrict__ bfc,
                                 const float* __restrict__ Wout,
                                 const float* __restrict__ bout,
                                 float* __restrict__ out, int N) {
    int gr = blockIdx.x;
    int j = threadIdx.x;  // 0..127
    __shared__ float sg[128];
    __shared__ float sred[128];
    int beg = lower_bound_i(batch, N, gr);
    int end = lower_bound_i(batch, N, gr + 1);
    float acc = 0.f;
    int i = beg;
    for (; i + 4 <= end; i += 4) {
        float v0 = __half2float(x[(size_t)i * 128 + j]);
        float v1 = __half2float(x[(size_t)(i + 1) * 128 + j]);
        float v2 = __half2float(x[(size_t)(i + 2) * 128 + j]);
        float v3 = __half2float(x[(size_t)(i + 3) * 128 + j]);
        acc += v0 + v1 + v2 + v3;
    }
    for (; i < end; i++) acc += __half2float(x[(size_t)i * 128 + j]);
    float cnt = fmaxf((float)(end - beg), 1.0f);
    sg[j] = acc / cnt;
    __syncthreads();
    float a = bfc[j];
#pragma unroll
    for (int k = 0; k < 128; k++) a += sg[k] * Wfc[k * 128 + j];
    float f = fmaxf(a, 0.f);
    sred[j] = f * Wout[j];
    __syncthreads();
    if (j < 64) sred[j] += sred[j + 64];
    __syncthreads();
    if (j < 64) {
        float v = sred[j];
#pragma unroll
        for (int off = 32; off > 0; off >>= 1) v += __shfl_down(v, off);
        if (j == 0) {
            float logit = v + bout[0];
            out[gr] = 1.0f / (1.0f + expf(-logit));
            out[NUM_GRAPHS + gr] = logit;
        }
    }
}

extern "C" void kernel_launch(void* const* d_in, const int* in_sizes, int n_in,
                              void* d_out, int out_size, void* d_ws, size_t ws_size,
                              hipStream_t stream) {
    const int* tok   = (const int*)d_in[0];
    const int* eidx  = (const int*)d_in[1];
    const int* batch = (const int*)d_in[2];
    const float* emb = (const float*)d_in[3];
    const float* Wp  = (const float*)d_in[4];
    const float* bp  = (const float*)d_in[5];
    const float* W1  = (const float*)d_in[6];
    const float* b1  = (const float*)d_in[7];
    const float* W2  = (const float*)d_in[8];
    const float* b2  = (const float*)d_in[9];
    const float* Wfc = (const float*)d_in[10];
    const float* bfc = (const float*)d_in[11];
    const float* Wout= (const float*)d_in[12];
    const float* bout= (const float*)d_in[13];
    float* out = (float*)d_out;

    const int N = in_sizes[2];
    const int E = in_sizes[1] / 2;
    const int* src = eidx;
    const int* dst = eidx + E;
    const int Np = (N + 3) & ~3;
    const int nbuck = (N + 255) / 256;               // 391 for N=100k
    const int nchunk = (E + CHUNK - 1) / CHUNK;      // 196

    // workspace layout (float units)
    float* ws = (float*)d_ws;
    size_t off = 0;
    float* dis     = ws + off;            off += Np;
    __half* mean16 = (__half*)(ws + off); off += (size_t)Np * 32;
    __half* agg16  = (__half*)(ws + off); off += (size_t)Np * 32;
    float* rowsum  = ws + off;            off += Np;
    __half* h2buf  = (__half*)(ws + off); off += (size_t)Np * 64;
    __half* xfin16 = (__half*)(ws + off); off += (size_t)Np * 64;
    _Float16* Wf16t = (_Float16*)(ws + off); off += 4096;
    _Float16* W2t   = (_Float16*)(ws + off); off += 8192;
    float* bf      = ws + off;            off += 128;
    int* row_start = (int*)(ws + off);    off += Np + 4;
    int* staged    = (int*)(ws + off);    off += E;
    int* bucket_cnt    = (int*)(ws + off); off += NBUCK_MAX;
    int* bucket_base   = (int*)(ws + off); off += NBUCK_MAX + 8;
    int* bucket_cursor = (int*)(ws + off); off += NBUCK_MAX;
    int2* csr      = (int2*)(ws + off);   // E int2

    // --- fused weight prep ---
    prep_weights_kernel<<<128, 128, 0, stream>>>(Wp, W1, W2, bp, Wf16t, W2t, bf);

    // --- bucketed counting sort -> row_start, dis, csr(+rowsum) ---
    hipMemsetAsync(bucket_cnt, 0, nbuck * sizeof(int), stream);
    bucket_hist_kernel<<<nchunk, 256, 0, stream>>>(dst, bucket_cnt, E, nbuck);
    bucket_scan_kernel<<<1, 512, 0, stream>>>(bucket_cnt, bucket_base, bucket_cursor, nbuck);
    binscatter_kernel<<<nchunk, 256, 0, stream>>>(src, dst, bucket_base, bucket_cursor,
                                                  staged, E, nbuck);
    bucket_count_kernel<<<nbuck, 256, 0, stream>>>(staged, bucket_base, row_start, dis, N, E);
    csr_write_kernel<<<nbuck, 256, 0, stream>>>(staged, bucket_base, row_start, dis,
                                                csr, rowsum, N);

    // --- embed + token-mean -> mean16 (fp16) ---
    embed_mean_kernel<<<(N + 3) / 4, 256, 0, stream>>>(tok, emb, mean16, N);

    // --- 64-dim aggregate (fp16 packed) -> agg16 ---
    agg64_kernel<<<(N + 3) / 4, 256, 0, stream>>>(mean16, row_start, csr, dis, agg16, N);

    // --- MFMA dense chain: h2 = relu(agg@Wf + rowsum*bf + b1) @ W2 -> fp16 ---
    dense_chain_mfma_kernel<<<(N + NB - 1) / NB, 256, 0, stream>>>(agg16, rowsum, Wf16t,
                                                                   bf, b1, W2t, h2buf, N);

    // --- layer 2 aggregate (fp16 packed) + b2 + ReLU -> xfin16 ---
    gcn_agg128_kernel<<<(N + 3) / 4, 256, 0, stream>>>(h2buf, row_start, csr, dis, b2,
                                                       xfin16, N);

    // --- fused global mean pool + head ---
    pool_head_kernel<<<NUM_GRAPHS, 128, 0, stream>>>(xfin16, batch, Wfc, bfc, Wout, bout,
                                                     out, N);
}

// Round 15
// 345.700 us; speedup vs baseline: 2.6959x; 1.0415x over previous
//
#include <hip/hip_runtime.h>
#include <hip/hip_bf16.h>
#include <hip/hip_fp16.h>
#include <math.h>

#define N_TOKENS 16
#define TOK_DIM 64
#define NODE_DIM 64
#define HID 128
#define FC 128
#define NUM_GRAPHS 1024
#define NBUCK_MAX 512
#define CHUNK 8192

typedef _Float16 f16x8 __attribute__((ext_vector_type(8)));
typedef float f32x4 __attribute__((ext_vector_type(4)));

__device__ __forceinline__ __half2 shfl_xor_h2(__half2 v, int mask) {
    int i = *(int*)&v;
    i = __shfl_xor(i, mask);
    return *(__half2*)&i;
}

// ---------------- fused weight prep: Wf16t = (Wp@W1)^T fp16, W2t = W2^T fp16, bf = bp@W1 ----------------
__global__ void prep_weights_kernel(const float* __restrict__ Wp, const float* __restrict__ W1,
                                    const float* __restrict__ W2, const float* __restrict__ bp,
                                    _Float16* __restrict__ Wf16t, _Float16* __restrict__ W2t,
                                    float* __restrict__ bf) {
    int n = blockIdx.x;   // 0..127
    int t = threadIdx.x;  // 0..127
    if (t < 64) {
        float acc = 0.f;
#pragma unroll
        for (int d = 0; d < 64; d++) acc += Wp[t * 64 + d] * W1[d * 128 + n];
        Wf16t[(size_t)n * 64 + t] = (_Float16)acc;
    } else {
        int d = t - 64;  // lane of wave 1
        float v = bp[d] * W1[d * 128 + n];
#pragma unroll
        for (int off = 32; off > 0; off >>= 1) v += __shfl_down(v, off);
        if (d == 0) bf[n] = v;
    }
    W2t[(size_t)n * 128 + t] = (_Float16)W2[(size_t)t * 128 + n];
}

// ---------------- emb fp32 -> fp16 table ----------------
__global__ void convert_emb_kernel(const float* __restrict__ emb, __half* __restrict__ emb16,
                                   int n4) {
    int i = blockIdx.x * 256 + threadIdx.x;
    if (i < n4) {
        float4 v = ((const float4*)emb)[i];
        __half2 h0 = __floats2half2_rn(v.x, v.y);
        __half2 h1 = __floats2half2_rn(v.z, v.w);
        float2 p;
        ((__half2*)&p)[0] = h0;
        ((__half2*)&p)[1] = h1;
        ((float2*)emb16)[i] = p;
    }
}

// ---------------- embed + token-mean (fp16 table, 8 rows/gather) -> mean16[N,64] ----------------
// lane (q,l): q=j>>3 token slot (8), l=j&7 feature block (float4 = 8 halfs)
__global__ void embed_mean_kernel(const int* __restrict__ tok,
                                  const __half* __restrict__ emb16,
                                  __half* __restrict__ mean16, int N) {
    int t = threadIdx.x;
    int w = t >> 6, j = t & 63;
    int q = j >> 3, l = j & 7;
    int i = blockIdx.x * 4 + w;
    if (i >= N) return;
    const float4* e4 = (const float4*)emb16;  // row = 8 float4 (64 halfs)
    int t0 = tok[i * 16 + q];
    int t1 = tok[i * 16 + q + 8];
    float4 v0 = e4[(size_t)t0 * 8 + l];
    float4 v1 = e4[(size_t)t1 * 8 + l];
    const __half2* p0 = (const __half2*)&v0;
    const __half2* p1 = (const __half2*)&v1;
    __half2 a0 = __hadd2(p0[0], p1[0]);
    __half2 a1 = __hadd2(p0[1], p1[1]);
    __half2 a2 = __hadd2(p0[2], p1[2]);
    __half2 a3 = __hadd2(p0[3], p1[3]);
#pragma unroll
    for (int mask = 8; mask <= 32; mask <<= 1) {
        a0 = __hadd2(a0, shfl_xor_h2(a0, mask));
        a1 = __hadd2(a1, shfl_xor_h2(a1, mask));
        a2 = __hadd2(a2, shfl_xor_h2(a2, mask));
        a3 = __hadd2(a3, shfl_xor_h2(a3, mask));
    }
    if (q == 0) {
        __half2 inv = __floats2half2_rn(1.0f / 16.0f, 1.0f / 16.0f);
        float4 packed;
        __half2* pp = (__half2*)&packed;
        pp[0] = __hmul2(a0, inv);
        pp[1] = __hmul2(a1, inv);
        pp[2] = __hmul2(a2, inv);
        pp[3] = __hmul2(a3, inv);
        ((float4*)mean16)[(size_t)i * 8 + l] = packed;
    }
}

// ---------------- bucketed counting sort: dst buckets of 256 nodes (512-thread blocks) ----------------
__global__ void bucket_hist_kernel(const int* __restrict__ dst, int* __restrict__ bucket_cnt,
                                   int E, int nbuck) {
    __shared__ int h[NBUCK_MAX];
    int t = threadIdx.x;
    for (int i = t; i < nbuck; i += 512) h[i] = 0;
    __syncthreads();
    int base = blockIdx.x * CHUNK;
    for (int i = t; i < CHUNK; i += 512) {
        int e = base + i;
        if (e < E) atomicAdd(&h[dst[e] >> 8], 1);
    }
    __syncthreads();
    for (int i = t; i < nbuck; i += 512)
        if (h[i]) atomicAdd(&bucket_cnt[i], h[i]);
}

// 1 block, 512 threads; nbuck <= 512
__global__ void bucket_scan_kernel(const int* __restrict__ bucket_cnt,
                                   int* __restrict__ bucket_base,
                                   int* __restrict__ bucket_cursor, int nbuck) {
    __shared__ int s[512];
    int tid = threadIdx.x;
    int v = (tid < nbuck) ? bucket_cnt[tid] : 0;
    s[tid] = v;
    __syncthreads();
    for (int off = 1; off < 512; off <<= 1) {
        int add = (tid >= off) ? s[tid - off] : 0;
        __syncthreads();
        s[tid] += add;
        __syncthreads();
    }
    if (tid < nbuck) { bucket_base[tid] = s[tid] - v; bucket_cursor[tid] = 0; }
    if (tid == 511) bucket_base[nbuck] = s[511];
}

// scatter edges into bucket-contiguous staging, packed val = src | (dst&255)<<17
__global__ void binscatter_kernel(const int* __restrict__ src, const int* __restrict__ dst,
                                  const int* __restrict__ bucket_base,
                                  int* __restrict__ bucket_cursor,
                                  int* __restrict__ staged, int E, int nbuck) {
    __shared__ int h[NBUCK_MAX];
    __shared__ int gw[NBUCK_MAX];
    int t = threadIdx.x;
    for (int i = t; i < nbuck; i += 512) h[i] = 0;
    __syncthreads();
    int base = blockIdx.x * CHUNK;
    for (int i = t; i < CHUNK; i += 512) {
        int e = base + i;
        if (e < E) atomicAdd(&h[dst[e] >> 8], 1);
    }
    __syncthreads();
    for (int i = t; i < nbuck; i += 512) {
        int c = h[i];
        gw[i] = (c > 0) ? bucket_base[i] + atomicAdd(&bucket_cursor[i], c) : 0;
        h[i] = 0;  // reuse as local rank cursor
    }
    __syncthreads();
    for (int i = t; i < CHUNK; i += 512) {
        int e = base + i;
        if (e < E) {
            int d = dst[e], s = src[e];
            int b = d >> 8;
            int r = atomicAdd(&h[b], 1);
            staged[gw[b] + r] = s | ((d & 255) << 17);
        }
    }
}

// per bucket: per-node degree -> row_start + dis (coalesced writes)
__global__ void bucket_count_kernel(const int* __restrict__ staged,
                                    const int* __restrict__ bucket_base,
                                    int* __restrict__ row_start, float* __restrict__ dis,
                                    int N, int E) {
    __shared__ int cnt[256];
    __shared__ int sc[256];
    int b = blockIdx.x;
    int t = threadIdx.x;
    cnt[t] = 0;
    __syncthreads();
    int rb0 = bucket_base[b], rb1 = bucket_base[b + 1];
    for (int i = rb0 + t; i < rb1; i += 256) atomicAdd(&cnt[staged[i] >> 17], 1);
    __syncthreads();
    int v = cnt[t];
    sc[t] = v;
    __syncthreads();
    for (int off = 1; off < 256; off <<= 1) {
        int add = (t >= off) ? sc[t - off] : 0;
        __syncthreads();
        sc[t] += add;
        __syncthreads();
    }
    int node = b * 256 + t;
    if (node < N) {
        row_start[node] = rb0 + sc[t] - v;  // exclusive
        dis[node] = rsqrtf(1.0f + (float)v);  // +1 self loop
    }
    if (b == 0 && t == 0) row_start[N] = E;
}

// per bucket: final CSR (src, half2(w,w)) + rowsum — block-local contiguous region
__global__ void csr_write_kernel(const int* __restrict__ staged,
                                 const int* __restrict__ bucket_base,
                                 const int* __restrict__ row_start,
                                 const float* __restrict__ dis,
                                 int2* __restrict__ csr, float* __restrict__ rowsum, int N) {
    __shared__ int cur[256];
    __shared__ float dl[256];
    __shared__ float wsum[256];
    int b = blockIdx.x;
    int t = threadIdx.x;
    int node = b * 256 + t;
    cur[t] = (node < N) ? row_start[node] : 0;
    dl[t] = (node < N) ? dis[node] : 0.f;
    wsum[t] = 0.f;
    __syncthreads();
    int rb0 = bucket_base[b], rb1 = bucket_base[b + 1];
    for (int i = rb0 + t; i < rb1; i += 256) {
        int v = staged[i];
        int s = v & 131071;
        int dloc = v >> 17;
        float w = dis[s] * dl[dloc];
        int pos = atomicAdd(&cur[dloc], 1);
        __half2 wh = __floats2half2_rn(w, w);
        csr[pos] = make_int2(s, *(int*)&wh);
        atomicAdd(&wsum[dloc], w);
    }
    __syncthreads();
    if (node < N) rowsum[node] = wsum[t] + dl[t] * dl[t];
}

// ---------------- agg64: fp16 packed accumulate, 8 rows per gather -> fp16 agg ----------------
// lane (q,l): q=j>>3 edge slot (8), l=j&7 feature block (float4 = 4 half2)
__global__ __launch_bounds__(256, 8)
void agg64_kernel(const __half* __restrict__ mean16,
                  const int* __restrict__ row_start,
                  const int2* __restrict__ csr,
                  const float* __restrict__ dis,
                  __half* __restrict__ agg16, int N) {
    int t = threadIdx.x;
    int w = t >> 6, j = t & 63;
    int q = j >> 3, l = j & 7;
    int node = blockIdx.x * 4 + w;
    if (node >= N) return;
    int beg = row_start[node];
    int end = row_start[node + 1];
    float d = dis[node];
    const float4* m4 = (const float4*)mean16;  // row = 8 float4 (64 halfs)
    __half2 a0, a1, a2, a3;
    {
        float4 raw = m4[(size_t)node * 8 + l];
        const __half2* hp = (const __half2*)&raw;
        float d2f = d * d * ((q == 0) ? 1.f : 0.f);
        __half2 d2h = __floats2half2_rn(d2f, d2f);
        a0 = __hmul2(hp[0], d2h); a1 = __hmul2(hp[1], d2h);
        a2 = __hmul2(hp[2], d2h); a3 = __hmul2(hp[3], d2h);
    }
    int k = beg;
    int kfull = beg + ((end - beg) & ~31);
    for (; k < kfull; k += 32) {  // unguarded: 4 batches x 8 slots
        int2 e[4];
        float4 v[4];
#pragma unroll
        for (int m = 0; m < 4; m++) e[m] = csr[k + 8 * m + q];
#pragma unroll
        for (int m = 0; m < 4; m++) v[m] = m4[(size_t)e[m].x * 8 + l];
#pragma unroll
        for (int m = 0; m < 4; m++) {
            __half2 wh = *(__half2*)&e[m].y;
            const __half2* hp = (const __half2*)&v[m];
            a0 = __hfma2(hp[0], wh, a0);
            a1 = __hfma2(hp[1], wh, a1);
            a2 = __hfma2(hp[2], wh, a2);
            a3 = __hfma2(hp[3], wh, a3);
        }
    }
    for (; k < end; k += 16) {  // guarded tail: 2 batches x 8 slots
        int2 e[2];
        float4 v[2];
#pragma unroll
        for (int m = 0; m < 2; m++) {
            int kk = k + 8 * m + q;
            e[m] = (kk < end) ? csr[kk] : make_int2(0, 0);  // wh=0 => no-op
        }
#pragma unroll
        for (int m = 0; m < 2; m++) v[m] = m4[(size_t)e[m].x * 8 + l];
#pragma unroll
        for (int m = 0; m < 2; m++) {
            __half2 wh = *(__half2*)&e[m].y;
            const __half2* hp = (const __half2*)&v[m];
            a0 = __hfma2(hp[0], wh, a0);
            a1 = __hfma2(hp[1], wh, a1);
            a2 = __hfma2(hp[2], wh, a2);
            a3 = __hfma2(hp[3], wh, a3);
        }
    }
    // fold across q (lane bits 3,4,5)
#pragma unroll
    for (int mask = 8; mask <= 32; mask <<= 1) {
        a0 = __hadd2(a0, shfl_xor_h2(a0, mask));
        a1 = __hadd2(a1, shfl_xor_h2(a1, mask));
        a2 = __hadd2(a2, shfl_xor_h2(a2, mask));
        a3 = __hadd2(a3, shfl_xor_h2(a3, mask));
    }
    if (q == 0) {
        float4 packed;
        __half2* pp = (__half2*)&packed;
        pp[0] = a0; pp[1] = a1; pp[2] = a2; pp[3] = a3;
        ((float4*)agg16)[(size_t)node * 8 + l] = packed;
    }
}

// ---------------- MFMA dense chain: h2 = relu(agg@Wf + rowsum*bf + b1) @ W2 -> fp16 ----------------
#define NB 32
__global__ void dense_chain_mfma_kernel(const __half* __restrict__ agg16,
                                        const float* __restrict__ rowsum,
                                        const _Float16* __restrict__ Wf16t,  // [128][64]
                                        const float* __restrict__ bf,
                                        const float* __restrict__ b1,
                                        const _Float16* __restrict__ W2t,    // [128][128]
                                        __half* __restrict__ h2, int N) {
    __shared__ _Float16 sx1[32][136];
    __shared__ float srs[32];
    int t = threadIdx.x;
    int wv = t >> 6, lane = t & 63;
    int nb0 = blockIdx.x * NB;
    int rh = wv & 1;
    int ncb = (wv >> 1) * 64;
    int m16 = lane & 15;
    int q = lane >> 4;

    if (t < 32) srs[t] = (nb0 + t < N) ? rowsum[nb0 + t] : 0.f;

    f32x4 c0 = {}, c1 = {}, c2 = {}, c3 = {};
    int arow = nb0 + rh * 16 + m16;
    bool rowok = (arow < N);
    const _Float16* ag = (const _Float16*)agg16;
#pragma unroll
    for (int ks = 0; ks < 2; ks++) {
        int k0 = ks * 32 + q * 8;
        f16x8 afrag = {};
        if (rowok) afrag = *(const f16x8*)(ag + (size_t)arow * 64 + k0);
        f16x8 b0 = *(const f16x8*)(Wf16t + (size_t)(ncb + 0 * 16 + m16) * 64 + k0);
        f16x8 b1f = *(const f16x8*)(Wf16t + (size_t)(ncb + 1 * 16 + m16) * 64 + k0);
        f16x8 b2f = *(const f16x8*)(Wf16t + (size_t)(ncb + 2 * 16 + m16) * 64 + k0);
        f16x8 b3f = *(const f16x8*)(Wf16t + (size_t)(ncb + 3 * 16 + m16) * 64 + k0);
        c0 = __builtin_amdgcn_mfma_f32_16x16x32_f16(afrag, b0, c0, 0, 0, 0);
        c1 = __builtin_amdgcn_mfma_f32_16x16x32_f16(afrag, b1f, c1, 0, 0, 0);
        c2 = __builtin_amdgcn_mfma_f32_16x16x32_f16(afrag, b2f, c2, 0, 0, 0);
        c3 = __builtin_amdgcn_mfma_f32_16x16x32_f16(afrag, b3f, c3, 0, 0, 0);
    }
    __syncthreads();
    {
        f32x4 cc[4] = {c0, c1, c2, c3};
#pragma unroll
        for (int nt = 0; nt < 4; nt++) {
            int ncol = ncb + nt * 16 + m16;
            float bfj = bf[ncol], b1j = b1[ncol];
#pragma unroll
            for (int r = 0; r < 4; r++) {
                int mrow = q * 4 + r;
                float z = cc[nt][r] + srs[rh * 16 + mrow] * bfj + b1j;
                sx1[rh * 16 + mrow][ncol] = (_Float16)fmaxf(z, 0.f);
            }
        }
    }
    __syncthreads();

    f32x4 d0 = {}, d1 = {}, d2 = {}, d3 = {};
#pragma unroll
    for (int ks = 0; ks < 4; ks++) {
        int k0 = ks * 32 + q * 8;
        f16x8 afrag = *(const f16x8*)(&sx1[rh * 16 + m16][k0]);
        f16x8 b0 = *(const f16x8*)(W2t + (size_t)(ncb + 0 * 16 + m16) * 128 + k0);
        f16x8 b1f = *(const f16x8*)(W2t + (size_t)(ncb + 1 * 16 + m16) * 128 + k0);
        f16x8 b2f = *(const f16x8*)(W2t + (size_t)(ncb + 2 * 16 + m16) * 128 + k0);
        f16x8 b3f = *(const f16x8*)(W2t + (size_t)(ncb + 3 * 16 + m16) * 128 + k0);
        d0 = __builtin_amdgcn_mfma_f32_16x16x32_f16(afrag, b0, d0, 0, 0, 0);
        d1 = __builtin_amdgcn_mfma_f32_16x16x32_f16(afrag, b1f, d1, 0, 0, 0);
        d2 = __builtin_amdgcn_mfma_f32_16x16x32_f16(afrag, b2f, d2, 0, 0, 0);
        d3 = __builtin_amdgcn_mfma_f32_16x16x32_f16(afrag, b3f, d3, 0, 0, 0);
    }
    {
        f32x4 dd[4] = {d0, d1, d2, d3};
#pragma unroll
        for (int nt = 0; nt < 4; nt++) {
            int ncol = ncb + nt * 16 + m16;
#pragma unroll
            for (int r = 0; r < 4; r++) {
                int node = nb0 + rh * 16 + q * 4 + r;
                if (node < N) h2[(size_t)node * 128 + ncol] = __float2half(dd[nt][r]);
            }
        }
    }
}

// ---------------- layer 2: agg128 fp16 packed accumulate, 4 rows per gather -> fp16 out ----------------
// lane (q,l): q=j>>4 edge slot (4), l=j&15 feature block (float4 = 4 half2)
__global__ __launch_bounds__(256, 8)
void gcn_agg128_kernel(const __half* __restrict__ hsrc,
                       const int* __restrict__ row_start,
                       const int2* __restrict__ csr,
                       const float* __restrict__ dis,
                       const float* __restrict__ b2,
                       __half* __restrict__ outx, int N) {
    int t = threadIdx.x;
    int w = t >> 6, j = t & 63;
    int q = j >> 4, l = j & 15;
    int node = blockIdx.x * 4 + w;
    if (node >= N) return;
    const float4* h4 = (const float4*)hsrc;  // row = 16 float4 (128 halfs)
    int beg = row_start[node];
    int end = row_start[node + 1];
    float d = dis[node];
    __half2 a0, a1, a2, a3;
    {
        float4 raw = h4[(size_t)node * 16 + l];
        const __half2* hp = (const __half2*)&raw;
        float d2f = d * d * ((q == 0) ? 1.f : 0.f);
        __half2 d2h = __floats2half2_rn(d2f, d2f);
        a0 = __hmul2(hp[0], d2h); a1 = __hmul2(hp[1], d2h);
        a2 = __hmul2(hp[2], d2h); a3 = __hmul2(hp[3], d2h);
    }
    int k = beg;
    int kfull = beg + ((end - beg) & ~31);
    for (; k < kfull; k += 32) {  // unguarded: 8 batches x 4 slots
        int2 e[8];
        float4 v[8];
#pragma unroll
        for (int m = 0; m < 8; m++) e[m] = csr[k + 4 * m + q];
#pragma unroll
        for (int m = 0; m < 8; m++) v[m] = h4[(size_t)e[m].x * 16 + l];
#pragma unroll
        for (int m = 0; m < 8; m++) {
            __half2 wh = *(__half2*)&e[m].y;
            const __half2* hp = (const __half2*)&v[m];
            a0 = __hfma2(hp[0], wh, a0);
            a1 = __hfma2(hp[1], wh, a1);
            a2 = __hfma2(hp[2], wh, a2);
            a3 = __hfma2(hp[3], wh, a3);
        }
    }
    for (; k < end; k += 16) {  // guarded tail: 4 batches x 4 slots
        int2 e[4];
        float4 v[4];
#pragma unroll
        for (int m = 0; m < 4; m++) {
            int kk = k + 4 * m + q;
            e[m] = (kk < end) ? csr[kk] : make_int2(0, 0);
        }
#pragma unroll
        for (int m = 0; m < 4; m++) v[m] = h4[(size_t)e[m].x * 16 + l];
#pragma unroll
        for (int m = 0; m < 4; m++) {
            __half2 wh = *(__half2*)&e[m].y;
            const __half2* hp = (const __half2*)&v[m];
            a0 = __hfma2(hp[0], wh, a0);
            a1 = __hfma2(hp[1], wh, a1);
            a2 = __hfma2(hp[2], wh, a2);
            a3 = __hfma2(hp[3], wh, a3);
        }
    }
    // fold across q (lane bits 4,5)
#pragma unroll
    for (int mask = 16; mask <= 32; mask <<= 1) {
        a0 = __hadd2(a0, shfl_xor_h2(a0, mask));
        a1 = __hadd2(a1, shfl_xor_h2(a1, mask));
        a2 = __hadd2(a2, shfl_xor_h2(a2, mask));
        a3 = __hadd2(a3, shfl_xor_h2(a3, mask));
    }
    if (q == 0) {
        // fp32 epilogue: + b2, relu, pack fp16
        float2 f0 = __half22float2(a0), f1 = __half22float2(a1);
        float2 f2 = __half22float2(a2), f3 = __half22float2(a3);
        const float4* b4 = (const float4*)b2;
        float4 ba = b4[l * 2], bb = b4[l * 2 + 1];
        __half2 o0 = __floats2half2_rn(fmaxf(f0.x + ba.x, 0.f), fmaxf(f0.y + ba.y, 0.f));
        __half2 o1 = __floats2half2_rn(fmaxf(f1.x + ba.z, 0.f), fmaxf(f1.y + ba.w, 0.f));
        __half2 o2 = __floats2half2_rn(fmaxf(f2.x + bb.x, 0.f), fmaxf(f2.y + bb.y, 0.f));
        __half2 o3 = __floats2half2_rn(fmaxf(f3.x + bb.z, 0.f), fmaxf(f3.y + bb.w, 0.f));
        float4 packed;
        __half2* pp = (__half2*)&packed;
        pp[0] = o0; pp[1] = o1; pp[2] = o2; pp[3] = o3;
        ((float4*)outx)[(size_t)node * 16 + l] = packed;
    }
}

// ---------------- fused pool + head: one block (128 threads) per graph ----------------
__device__ __forceinline__ int lower_bound_i(const int* __restrict__ a, int n, int val) {
    int lo = 0, hi = n;
    while (lo < hi) {
        int mid = (lo + hi) >> 1;
        if (a[mid] < val) lo = mid + 1; else hi = mid;
    }
    return lo;
}

__global__ void pool_head_kernel(const __half* __restrict__ x,
                                 const int* __restrict__ batch,
                                 const float* __restrict__ Wfc,
                                 const float* __restrict__ bfc,
                                 const float* __restrict__ Wout,
                                 const float* __restrict__ bout,
                                 float* __restrict__ out, int N) {
    int gr = blockIdx.x;
    int t = threadIdx.x;  // 0..127
    int j2 = t & 63, w = t >> 6;
    __shared__ float2 spart[2][64];
    __shared__ float sg[128];
    __shared__ float sred[128];
    int beg = lower_bound_i(batch, N, gr);
    int end = lower_bound_i(batch, N, gr + 1);
    const __half2* x2 = (const __half2*)x;  // row stride 64 half2
    float2 acc = make_float2(0.f, 0.f);
    for (int i = beg + w; i < end; i += 2) {
        float2 a = __half22float2(x2[(size_t)i * 64 + j2]);
        acc.x += a.x; acc.y += a.y;
    }
    spart[w][j2] = acc;
    __syncthreads();
    if (t < 64) {
        float inv = 1.0f / fmaxf((float)(end - beg), 1.0f);
        float2 s0 = spart[0][t], s1 = spart[1][t];
        sg[2 * t] = (s0.x + s1.x) * inv;
        sg[2 * t + 1] = (s0.y + s1.y) * inv;
    }
    __syncthreads();
    int j = t;
    float a = bfc[j];
#pragma unroll
    for (int k = 0; k < 128; k++) a += sg[k] * Wfc[k * 128 + j];
    float f = fmaxf(a, 0.f);
    sred[j] = f * Wout[j];
    __syncthreads();
    if (j < 64) sred[j] += sred[j + 64];
    __syncthreads();
    if (j < 64) {
        float v = sred[j];
#pragma unroll
        for (int off = 32; off > 0; off >>= 1) v += __shfl_down(v, off);
        if (j == 0) {
            float logit = v + bout[0];
            out[gr] = 1.0f / (1.0f + expf(-logit));
            out[NUM_GRAPHS + gr] = logit;
        }
    }
}

extern "C" void kernel_launch(void* const* d_in, const int* in_sizes, int n_in,
                              void* d_out, int out_size, void* d_ws, size_t ws_size,
                              hipStream_t stream) {
    const int* tok   = (const int*)d_in[0];
    const int* eidx  = (const int*)d_in[1];
    const int* batch = (const int*)d_in[2];
    const float* emb = (const float*)d_in[3];
    const float* Wp  = (const float*)d_in[4];
    const float* bp  = (const float*)d_in[5];
    const float* W1  = (const float*)d_in[6];
    const float* b1  = (const float*)d_in[7];
    const float* W2  = (const float*)d_in[8];
    const float* b2  = (const float*)d_in[9];
    const float* Wfc = (const float*)d_in[10];
    const float* bfc = (const float*)d_in[11];
    const float* Wout= (const float*)d_in[12];
    const float* bout= (const float*)d_in[13];
    float* out = (float*)d_out;

    const int N = in_sizes[2];
    const int E = in_sizes[1] / 2;
    const int* src = eidx;
    const int* dst = eidx + E;
    const int Np = (N + 3) & ~3;
    const int nbuck = (N + 255) / 256;               // 391 for N=100k
    const int nchunk = (E + CHUNK - 1) / CHUNK;      // 196
    const int emb_n4 = in_sizes[3] / 4;              // float4 count of emb

    // workspace layout (float units)
    float* ws = (float*)d_ws;
    size_t off = 0;
    float* dis     = ws + off;            off += Np;
    __half* mean16 = (__half*)(ws + off); off += (size_t)Np * 32;
    __half* agg16  = (__half*)(ws + off); off += (size_t)Np * 32;
    float* rowsum  = ws + off;            off += Np;
    __half* h2buf  = (__half*)(ws + off); off += (size_t)Np * 64;
    __half* xfin16 = (__half*)(ws + off); off += (size_t)Np * 64;
    __half* emb16  = (__half*)(ws + off); off += (size_t)(in_sizes[3] / 2 + 4);
    _Float16* Wf16t = (_Float16*)(ws + off); off += 4096;
    _Float16* W2t   = (_Float16*)(ws + off); off += 8192;
    float* bf      = ws + off;            off += 128;
    int* row_start = (int*)(ws + off);    off += Np + 4;
    int* staged    = (int*)(ws + off);    off += E;
    int* bucket_cnt    = (int*)(ws + off); off += NBUCK_MAX;
    int* bucket_base   = (int*)(ws + off); off += NBUCK_MAX + 8;
    int* bucket_cursor = (int*)(ws + off); off += NBUCK_MAX;
    int2* csr      = (int2*)(ws + off);   // E int2

    // --- fused weight prep + emb fp16 conversion ---
    prep_weights_kernel<<<128, 128, 0, stream>>>(Wp, W1, W2, bp, Wf16t, W2t, bf);
    convert_emb_kernel<<<(emb_n4 + 255) / 256, 256, 0, stream>>>(emb, emb16, emb_n4);

    // --- bucketed counting sort -> row_start, dis, csr(+rowsum) ---
    hipMemsetAsync(bucket_cnt, 0, nbuck * sizeof(int), stream);
    bucket_hist_kernel<<<nchunk, 512, 0, stream>>>(dst, bucket_cnt, E, nbuck);
    bucket_scan_kernel<<<1, 512, 0, stream>>>(bucket_cnt, bucket_base, bucket_cursor, nbuck);
    binscatter_kernel<<<nchunk, 512, 0, stream>>>(src, dst, bucket_base, bucket_cursor,
                                                  staged, E, nbuck);
    bucket_count_kernel<<<nbuck, 256, 0, stream>>>(staged, bucket_base, row_start, dis, N, E);
    csr_write_kernel<<<nbuck, 256, 0, stream>>>(staged, bucket_base, row_start, dis,
                                                csr, rowsum, N);

    // --- embed + token-mean (fp16 table) -> mean16 ---
    embed_mean_kernel<<<(N + 3) / 4, 256, 0, stream>>>(tok, emb16, mean16, N);

    // --- 64-dim aggregate (fp16 packed) -> agg16 ---
    agg64_kernel<<<(N + 3) / 4, 256, 0, stream>>>(mean16, row_start, csr, dis, agg16, N);

    // --- MFMA dense chain: h2 = relu(agg@Wf + rowsum*bf + b1) @ W2 -> fp16 ---
    dense_chain_mfma_kernel<<<(N + NB - 1) / NB, 256, 0, stream>>>(agg16, rowsum, Wf16t,
                                                                   bf, b1, W2t, h2buf, N);

    // --- layer 2 aggregate (fp16 packed) + b2 + ReLU -> xfin16 ---
    gcn_agg128_kernel<<<(N + 3) / 4, 256, 0, stream>>>(h2buf, row_start, csr, dis, b2,
                                                       xfin16, N);

    // --- fused global mean pool + head ---
    pool_head_kernel<<<NUM_GRAPHS, 128, 0, stream>>>(xfin16, batch, Wfc, bfc, Wout, bout,
                                                     out, N);
}